// Round 1
// baseline (4127.906 us; speedup 1.0000x reference)
//
#include <hip/hip_runtime.h>
#include <math.h>

#define NEGV -1000000000.0f

__device__ __forceinline__ unsigned f2mono(float f){
  unsigned u = __float_as_uint(f);
  return (u & 0x80000000u) ? ~u : (u | 0x80000000u);
}
__device__ __forceinline__ float mono2f(unsigned u){
  return __uint_as_float((u & 0x80000000u) ? (u & 0x7fffffffu) : ~u);
}
__device__ __forceinline__ float sigm(float x){ return 1.0f/(1.0f+expf(-x)); }
__device__ __forceinline__ void edge_sd(int e,const int* src,const int* dst,int E,int& s,int& d){
  if(e<E){ s=src[e]; d=dst[e]; } else { s=e-E; d=s; }
}

// ---------------- generic tiled fp32 GEMM ----------------
// C[M,N] = sum_k opA * opB.
// ADIR: A stored K x M (row-major, lda = row stride). else A stored M x K.
// BDIR: B stored K x N. else B stored N x K.
// MAXM: acc = max(acc, a!=0 ? b : NEG)   (masked segment-max)
// kchunk>0 with gridDim.z>1: K-split; FMA -> atomicAdd into prezeroed C,
//   MAXM -> atomicMax into mono-encoded C (pre-filled with f2mono(-3e38)).
// epi (only when gridDim.z==1): 0 none, 1 mask+leakyrelu (NEG where mask==0), 2 zero diagonal.
template<bool ADIR, bool BDIR, bool MAXM>
__global__ __launch_bounds__(256) void k_gemm(
    const float* __restrict__ A, int lda,
    const float* __restrict__ B, int ldb,
    float* __restrict__ C, int ldc,
    int M, int N, int K, int kchunk,
    const float* __restrict__ mask, int ldm, int epi)
{
  __shared__ float As[16][68];
  __shared__ float Bs[16][68];
  const int tid = threadIdx.x;
  const int m0 = blockIdx.y * 64, n0 = blockIdx.x * 64;
  const int tmb = (tid & 15) * 4, tnb = (tid >> 4) * 4;
  float acc[4][4];
#pragma unroll
  for (int i=0;i<4;i++)
#pragma unroll
    for (int j=0;j<4;j++) acc[i][j] = MAXM ? NEGV : 0.0f;

  int kstart = 0, kend = K;
  if (kchunk > 0) { kstart = blockIdx.z * kchunk; kend = kstart + kchunk; if (kend > K) kend = K; }

  for (int k0 = kstart; k0 < kend; k0 += 16) {
    if (ADIR) {
      const int m = m0 + (tid & 63);
      const int tb = tid >> 6;
#pragma unroll
      for (int s=0;s<4;s++) {
        const int tk = tb + s*4;
        float v = 0.0f;
        if (m < M && (k0+tk) < K) v = A[(size_t)(k0+tk)*lda + m];
        As[tk][tid & 63] = v;
      }
    } else {
      const int tm = tid >> 2, tb = (tid & 3) * 4;
#pragma unroll
      for (int s=0;s<4;s++) {
        const int tk = tb + s;
        float v = 0.0f;
        if ((m0+tm) < M && (k0+tk) < K) v = A[(size_t)(m0+tm)*lda + (k0+tk)];
        As[tk][tm] = v;
      }
    }
    if (BDIR) {
      const int nn = n0 + (tid & 63);
      const int tb = tid >> 6;
#pragma unroll
      for (int s=0;s<4;s++) {
        const int tk = tb + s*4;
        float v = 0.0f;
        if (nn < N && (k0+tk) < K) v = B[(size_t)(k0+tk)*ldb + nn];
        Bs[tk][tid & 63] = v;
      }
    } else {
      const int tn = tid >> 2, tb = (tid & 3) * 4;
#pragma unroll
      for (int s=0;s<4;s++) {
        const int tk = tb + s;
        float v = 0.0f;
        if ((n0+tn) < N && (k0+tk) < K) v = B[(size_t)(n0+tn)*ldb + (k0+tk)];
        Bs[tk][tn] = v;
      }
    }
    __syncthreads();
#pragma unroll
    for (int kk=0; kk<16; kk++) {
      const float4 a4 = *(const float4*)&As[kk][tmb];
      const float4 b4 = *(const float4*)&Bs[kk][tnb];
      const float av[4] = {a4.x,a4.y,a4.z,a4.w};
      const float bv[4] = {b4.x,b4.y,b4.z,b4.w};
#pragma unroll
      for (int i=0;i<4;i++)
#pragma unroll
        for (int j=0;j<4;j++) {
          if (MAXM) acc[i][j] = fmaxf(acc[i][j], av[i] != 0.0f ? bv[j] : NEGV);
          else      acc[i][j] = fmaf(av[i], bv[j], acc[i][j]);
        }
    }
    __syncthreads();
  }

  const bool split = (gridDim.z > 1);
#pragma unroll
  for (int i=0;i<4;i++)
#pragma unroll
    for (int j=0;j<4;j++) {
      const int m = m0 + tmb + i, nn = n0 + tnb + j;
      if (m < M && nn < N) {
        float v = acc[i][j];
        if (split) {
          if (MAXM) atomicMax((unsigned*)&C[(size_t)m*ldc + nn], f2mono(v));
          else atomicAdd(&C[(size_t)m*ldc + nn], v);
        } else {
          if (epi == 1) { v = (mask[(size_t)m*ldm + nn] != 0.0f) ? (v > 0.0f ? v : 0.2f*v) : NEGV; }
          else if (epi == 2) { if (m == nn) v = 0.0f; }
          C[(size_t)m*ldc + nn] = v;
        }
      }
    }
}

// ---------------- small kernels ----------------
__global__ void k_deg(const int* __restrict__ src,const int* __restrict__ dst,int* indeg,int* outdeg,int E){
  int e = blockIdx.x*256+threadIdx.x; if(e>=E) return;
  atomicAdd(&indeg[dst[e]],1); atomicAdd(&outdeg[src[e]],1);
}

__global__ void k_mm_small(const float* __restrict__ A,const float* __restrict__ W,
                           const float* __restrict__ b,float* __restrict__ C,
                           int M,int K,int Np,int act){
  int idx = blockIdx.x*256+threadIdx.x; if(idx>=M*Np) return;
  int m = idx/Np, j = idx - m*Np;
  float s = b ? b[j] : 0.0f;
  const float* a = A + (size_t)m*K;
  for(int q=0;q<K;q++) s = fmaf(a[q], W[(size_t)q*Np + j], s);
  if(act==1) s = fmaxf(s, 0.0f);
  C[idx] = s;
}

__global__ void k_copy(float* d,const float* s,int n){ int i=blockIdx.x*256+threadIdx.x; if(i<n) d[i]=s[i]; }
__global__ void k_copy_int(int* d,const int* s,int n){ int i=blockIdx.x*256+threadIdx.x; if(i<n) d[i]=s[i]; }

__global__ void k_scatter_add(const int* __restrict__ src,const int* __restrict__ dst,
                              const float* __restrict__ Y,float* SEG,int E,int H){
  int idx = blockIdx.x*256+threadIdx.x; if(idx>=E*H) return;
  int e = idx/H, h = idx - e*H;
  atomicAdd(&SEG[(size_t)dst[e]*H + h], Y[(size_t)src[e]*H + h]);
}

__global__ void k_feast_fin(const float* __restrict__ SEG,const int* __restrict__ indeg,
                            const float* __restrict__ b,float* X,int n,int H){
  int idx = blockIdx.x*256+threadIdx.x; if(idx>=n*H) return;
  int i = idx/H, h = idx - i*H;
  float v = SEG[idx]/(float)(indeg[i]+1) + b[h];
  X[idx] = v > 0.0f ? v : (expf(v)-1.0f);
}

__global__ void k_cnt_sparse(const int* indeg,float* cntf,int n){
  int i = blockIdx.x*256+threadIdx.x; if(i>=n) return;
  cntf[i] = (float)(indeg[i] > 1 ? indeg[i] : 1);
}

__global__ void k_gconv_fin(const float* __restrict__ AGG,const float* __restrict__ cnt,
                            const float* __restrict__ Wrel,const float* __restrict__ brel,
                            const float* __restrict__ X,const float* __restrict__ Wroot,
                            float* XN,int n){
  int idx = blockIdx.x*256+threadIdx.x; if(idx>=n*64) return;
  int i = idx >> 6, j = idx & 63;
  const float* ag = AGG + (size_t)i*64;
  const float* xr = X + (size_t)i*64;
  float a = 0.0f, r = 0.0f;
  for(int q=0;q<64;q++){ a = fmaf(ag[q], Wrel[q*64+j], a); r = fmaf(xr[q], Wroot[q*64+j], r); }
  float v = a/cnt[i] + brel[j] + r;
  XN[idx] = fmaxf(v, 0.0f);
}

__global__ void k_mean(const float* __restrict__ X,int n,float* o){
  __shared__ float sh[256];
  int t = threadIdx.x; int h = t & 63, p = t >> 6;
  float s = 0.0f;
  for(int i=p;i<n;i+=4) s += X[(size_t)i*64 + h];
  sh[t] = s; __syncthreads();
  if(t < 64) o[t] = (sh[t]+sh[t+64]+sh[t+128]+sh[t+192])/(float)n;
}

__global__ void k_mono_init_from(unsigned* M,const float* X,int n){
  int i = blockIdx.x*256+threadIdx.x; if(i<n) M[i] = f2mono(X[i]);
}
__global__ void k_fill_mono(unsigned* M,int n,float v){
  int i = blockIdx.x*256+threadIdx.x; if(i<n) M[i] = f2mono(v);
}
__global__ void k_mono_fin(float* out,const unsigned* M,int n){
  int i = blockIdx.x*256+threadIdx.x; if(i<n){ unsigned u = M[i]; out[i] = mono2f(u); }
}
__global__ void k_scatter_max(const int* __restrict__ src,const int* __restrict__ dst,
                              const float* __restrict__ X,unsigned* M,int E,int H){
  int idx = blockIdx.x*256+threadIdx.x; if(idx>=E*H) return;
  int e = idx/H, h = idx - e*H;
  atomicMax(&M[(size_t)dst[e]*H + h], f2mono(X[(size_t)src[e]*H + h]));
}

__global__ void k_edge_score(const int* __restrict__ src,const int* __restrict__ dst,
                             const float* __restrict__ XQ2,const float* __restrict__ X,
                             float* sE,int E,int n){
  int e = blockIdx.x*256+threadIdx.x; if(e>=E+n) return;
  int s,d; edge_sd(e,src,dst,E,s,d);
  const float* q = XQ2 + (size_t)d*64;
  const float* x = X + (size_t)s*64;
  float acc = 0.0f;
  for(int h=0;h<64;h++) acc = fmaf(q[h], x[h], acc);
  sE[e] = acc > 0.0f ? acc : 0.2f*acc;
}
__global__ void k_segmax_edge(const int* src,const int* dst,const float* sE,unsigned* M,int E,int n){
  int e = blockIdx.x*256+threadIdx.x; if(e>=E+n) return;
  int s,d; edge_sd(e,src,dst,E,s,d);
  atomicMax(&M[d], f2mono(sE[e]));
}
__global__ void k_exp_edge(const int* src,const int* dst,const float* sE,const float* m,
                           float* eE,float* denom,int E,int n){
  int e = blockIdx.x*256+threadIdx.x; if(e>=E+n) return;
  int s,d; edge_sd(e,src,dst,E,s,d);
  float v = expf(sE[e]-m[d]); eE[e]=v; atomicAdd(&denom[d],v);
}
__global__ void k_score_edge(const int* src,const int* dst,const float* eE,const float* denom,
                             float* scE,int E,int n){
  int e = blockIdx.x*256+threadIdx.x; if(e>=E+n) return;
  int s,d; edge_sd(e,src,dst,E,s,d);
  scE[e] = eE[e]/denom[d];
}
__global__ void k_xc_scatter(const int* __restrict__ src,const int* __restrict__ dst,
                             const float* __restrict__ scE,const float* __restrict__ X,
                             float* XC,int E,int n){
  int idx = blockIdx.x*256+threadIdx.x; if(idx>=(E+n)*64) return;
  int e = idx >> 6, h = idx & 63;
  int s,d; edge_sd(e,src,dst,E,s,d);
  atomicAdd(&XC[(size_t)d*64 + h], scE[e]*X[(size_t)s*64 + h]);
}
__global__ void k_abc(const float* __restrict__ XC,const float* __restrict__ w1,const float* bb1,
                      const float* __restrict__ w2,const float* __restrict__ w3,const float* bb3,
                      float* aN,float* bN,float* cN,int n){
  int v = blockIdx.x*256+threadIdx.x; if(v>=n) return;
  const float* xc = XC + (size_t)v*64;
  float a = bb1[0], b = 0.0f, c = bb3[0];
  for(int h=0;h<64;h++){ a=fmaf(xc[h],w1[h],a); b=fmaf(xc[h],w2[h],b); c=fmaf(xc[h],w3[h],c); }
  aN[v]=a; bN[v]=b; cN[v]=c;
}
__global__ void k_agg_edge(const int* src,const int* dst,const float* aN,float* agg,int E,int n){
  int e = blockIdx.x*256+threadIdx.x; if(e>=E+n) return;
  int s,d; edge_sd(e,src,dst,E,s,d);
  atomicAdd(&agg[d], aN[s]);
}
__global__ void k_fit_sparse(const float* agg,const int* indeg,const float* bN,const float* cN,
                             float* fit,int n){
  int v = blockIdx.x*256+threadIdx.x; if(v>=n) return;
  fit[v] = sigm(agg[v] - (float)(indeg[v]+1)*bN[v] + cN[v]);
}
__global__ void k_fit_dense(const float* agg,const float* cntP,const float* bN,const float* cN,
                            float* fit,int n){
  int v = blockIdx.x*256+threadIdx.x; if(v>=n) return;
  fit[v] = sigm(agg[v] - cntP[v]*bN[v] + cN[v]);
}

__global__ void k_rank(const float* __restrict__ fit,int n,int k,int* sel){
  int v = blockIdx.x*256+threadIdx.x; if(v>=n) return;
  float fv = fit[v]; int r = 0;
  for(int u=0;u<n;u++){ float fu = fit[u]; if(fu > fv || (fu == fv && u < v)) r++; }
  sel[v] = (r < k) ? 1 : 0;
}
__global__ void k_compact(const int* __restrict__ sel,int n,int* perm){
  int v = blockIdx.x*256+threadIdx.x; if(v>=n || !sel[v]) return;
  int p = 0;
  for(int u=0;u<v;u++) p += sel[u];
  perm[p] = v;
}
__global__ void k_xnew(const float* __restrict__ XC,const float* __restrict__ fit,
                       const int* __restrict__ perm,float* XN,int k){
  int idx = blockIdx.x*256+threadIdx.x; if(idx>=k*64) return;
  int u = idx >> 6, h = idx & 63; int v = perm[u];
  XN[idx] = XC[(size_t)v*64 + h]*fit[v];
}

__global__ void k_prefix(const int* __restrict__ deg,int* off,int n){
  int t = blockIdx.x*256+threadIdx.x; if(t>n) return;
  int s = 0;
  for(int u=0;u<t;u++) s += deg[u]+1;
  off[t] = s;
}
__global__ void k_csr_fill(const int* src,const int* dst,const float* scE,
                           int* curS,int* colS,float* valS,
                           int* curD,int* rowD,float* valD,int E,int n){
  int e = blockIdx.x*256+threadIdx.x; if(e>=E+n) return;
  int s,d; edge_sd(e,src,dst,E,s,d);
  float sc = scE[e];
  int p = atomicAdd(&curS[s],1); colS[p]=d; valS[p]=sc;
  int q = atomicAdd(&curD[d],1); rowD[q]=s; valD[q]=sc;
}
__global__ void k_stage1(const int* src,const int* dst,const int* __restrict__ offS,
                         const int* __restrict__ colS,const float* __restrict__ valS,
                         float* R,int E,int n){
  int e = blockIdx.x*256+threadIdx.x; if(e>=E+n) return;
  int i,j; edge_sd(e,src,dst,E,i,j);
  int p0 = offS[j], p1 = offS[j+1];
  float* Ri = R + (size_t)i*n;
  for(int p=p0;p<p1;p++) atomicAdd(&Ri[colS[p]], valS[p]);
}
__global__ void k_gather_cols(const float* __restrict__ S,int ldS,const int* __restrict__ perm,
                              float* out,int k,int rows){
  int idx = blockIdx.x*256+threadIdx.x; if(idx>=rows*k) return;
  int i = idx/k, u = idx - i*k;
  out[idx] = S[(size_t)i*ldS + perm[u]];
}
__global__ void k_stage2(const int* __restrict__ perm,const int* __restrict__ offD,
                         const int* __restrict__ rowD,const float* __restrict__ valD,
                         const float* __restrict__ Rp,float* A,int k){
  int idx = blockIdx.x*256+threadIdx.x; if(idx>=k*k) return;
  int u = idx/k, v = idx - u*k; int d = perm[u];
  float acc = 0.0f;
  int p0 = offD[d], p1 = offD[d+1];
  for(int p=p0;p<p1;p++) acc = fmaf(valD[p], Rp[(size_t)rowD[p]*k + v], acc);
  A[idx] = (u==v) ? 0.0f : acc;
}

__global__ void k_diagfix(float* A,int n){
  int i = blockIdx.x*256+threadIdx.x; if(i>=n) return;
  size_t d = (size_t)i*n + i;
  if(A[d]==0.0f) A[d]=1.0f;
}
__global__ void k_colcount_part(const float* __restrict__ A,int n,int* cnt){
  int idx = blockIdx.x*256+threadIdx.x; if(idx>=n*16) return;
  int j = idx % n, c = idx / n;
  int i0 = (int)(((long long)n*c)/16), i1 = (int)(((long long)n*(c+1))/16);
  int s = 0;
  for(int i=i0;i<i1;i++) s += (A[(size_t)i*n + j] != 0.0f) ? 1 : 0;
  if(s) atomicAdd(&cnt[j], s);
}
__global__ void k_cnt_fin(const int* cnt,float* out,int n,int clampMin){
  int j = blockIdx.x*256+threadIdx.x; if(j>=n) return;
  int c = cnt[j]; if(c < clampMin) c = clampMin;
  out[j] = (float)c;
}
__global__ void k_colmax_part(const float* __restrict__ S,int n,unsigned* M){
  int idx = blockIdx.x*256+threadIdx.x; if(idx>=n*16) return;
  int j = idx % n, c = idx / n;
  int i0 = (int)(((long long)n*c)/16), i1 = (int)(((long long)n*(c+1))/16);
  float lm = -3.0e38f;
  for(int i=i0;i<i1;i++) lm = fmaxf(lm, S[(size_t)i*n + j]);
  atomicMax(&M[j], f2mono(lm));
}
__global__ void k_exp_colsum(float* S,const float* __restrict__ A,const float* __restrict__ m,
                             float* denom,int n){
  int idx = blockIdx.x*256+threadIdx.x; if(idx>=n*16) return;
  int j = idx % n, c = idx / n;
  int i0 = (int)(((long long)n*c)/16), i1 = (int)(((long long)n*(c+1))/16);
  float mj = m[j], ls = 0.0f;
  for(int i=i0;i<i1;i++){
    size_t o = (size_t)i*n + j;
    float v = (A[o] != 0.0f) ? expf(S[o]-mj) : 0.0f;
    S[o] = v; ls += v;
  }
  if(ls != 0.0f) atomicAdd(&denom[j], ls);
}
__global__ void k_scale_cols(float* S,const float* __restrict__ denom,int n){
  int idx = blockIdx.x*256+threadIdx.x; if(idx>=n*n) return;
  int j = idx % n;
  S[idx] /= denom[j];
}
__global__ void k_aggcol_part(const float* __restrict__ A,const float* __restrict__ aN,
                              float* agg,int n){
  int idx = blockIdx.x*256+threadIdx.x; if(idx>=n*16) return;
  int j = idx % n, c = idx / n;
  int i0 = (int)(((long long)n*c)/16), i1 = (int)(((long long)n*(c+1))/16);
  float s = 0.0f;
  for(int i=i0;i<i1;i++) if(A[(size_t)i*n + j] != 0.0f) s += aN[i];
  if(s != 0.0f) atomicAdd(&agg[j], s);
}

__global__ void k_head(const float* __restrict__ h2,const float* __restrict__ W,
                       const float* __restrict__ b,float* out){
  __shared__ float lg[10];
  int t = threadIdx.x;
  if(t < 10){
    float s = b[t];
    for(int k=0;k<64;k++) s = fmaf(h2[k], W[k*10+t], s);
    lg[t] = s;
  }
  __syncthreads();
  if(t == 0){
    float mx = lg[0];
    for(int i=1;i<10;i++) mx = fmaxf(mx, lg[i]);
    float se = 0.0f;
    for(int i=0;i<10;i++) se += expf(lg[i]-mx);
    float lse = mx + logf(se);
    for(int i=0;i<10;i++) out[i] = lg[i]-lse;
  }
}

// ---------------- host orchestration ----------------
extern "C" void kernel_launch(void* const* d_in, const int* in_sizes, int n_in,
                              void* d_out, int out_size, void* d_ws, size_t ws_size,
                              hipStream_t stream) {
  const int N0 = 1500, E = 24000;
  const float* x0   = (const float*)d_in[0];
  const int* esrc   = (const int*)d_in[1];
  const int* edst   = (const int*)d_in[2];
  const float* W1   = (const float*)d_in[3];  const float* b1   = (const float*)d_in[4];
  const float* W2   = (const float*)d_in[5];  const float* b2   = (const float*)d_in[6];
  const float* W3   = (const float*)d_in[7];  const float* b3   = (const float*)d_in[8];
  const float* Wrel = (const float*)d_in[9];  const float* brel = (const float*)d_in[10];
  const float* Wroot= (const float*)d_in[11];
  const float* pW   = (const float*)d_in[12]; const float* pb   = (const float*)d_in[13];
  const float* leW1 = (const float*)d_in[14]; const float* leb1 = (const float*)d_in[15];
  const float* leW2 = (const float*)d_in[16]; const float* leW3 = (const float*)d_in[17];
  const float* leb3 = (const float*)d_in[18];
  const float* linW1= (const float*)d_in[19]; const float* linb1= (const float*)d_in[20];
  const float* linW2= (const float*)d_in[21]; const float* linb2= (const float*)d_in[22];
  float* out = (float*)d_out;

  float* ws = (float*)d_ws;
  size_t cur = 0;
  auto allocF = [&](size_t nf)->float*{ float* p = ws + cur; cur += (nf + 15) & ~(size_t)15; return p; };
  float* Xa  = allocF(96000); float* Xb  = allocF(96000); float* Y   = allocF(96000);
  float* XQ2 = allocF(96000); float* XC  = allocF(96000); float* SEG = allocF(96000);
  float* xs  = allocF(640);
  float* mcol = allocF(1500); float* denom = allocF(1500);
  float* aN = allocF(1500); float* bN = allocF(1500); float* cN = allocF(1500);
  float* fit = allocF(1500); float* agg1 = allocF(1500); float* cntf = allocF(1500); float* cntP = allocF(1500);
  int* indeg = (int*)allocF(1500); int* outdeg = (int*)allocF(1500); int* cnti = (int*)allocF(1500);
  int* sel = (int*)allocF(1500); int* perm = (int*)allocF(1500);
  int* offS = (int*)allocF(1504); int* offD = (int*)allocF(1504);
  int* curS = (int*)allocF(1504); int* curD = (int*)allocF(1504);
  int* colS = (int*)allocF(25504); int* rowD = (int*)allocF(25504);
  unsigned* mmono = (unsigned*)allocF(1504);
  float* valS = allocF(25504); float* valD = allocF(25504);
  float* sE = allocF(25504); float* eE = allocF(25504); float* scE = allocF(25504);
  float* R   = allocF((size_t)1500*1500);
  float* TB  = allocF((size_t)1500*1350);
  float* SPD = allocF((size_t)1350*1215 + 16);
  float* SCb = allocF((size_t)1350*1350);
  float* A0  = allocF((size_t)1350*1350);
  float* A1s = allocF((size_t)1350*1350);

  dim3 B256(256);
  auto G1 = [&](size_t n){ return dim3((unsigned)((n + 255) / 256)); };
  auto MS = [&](void* p, size_t bytes){ hipMemsetAsync(p, 0, bytes, stream); };
  auto kchunk_for = [&](int K, int Z){ return (int)(((K + Z*16 - 1) / (Z*16)) * 16); };

  // degrees
  MS(indeg, 1500*4); MS(outdeg, 1500*4);
  k_deg<<<G1(E),B256,0,stream>>>(esrc, edst, indeg, outdeg, E);

  // ---- FEAST x3 ----
  auto feast = [&](const float* xin,int cin,const float* W,const float* bb,int hh,float* xout){
    k_mm_small<<<G1((size_t)N0*hh),B256,0,stream>>>(xin, W, nullptr, Y, N0, cin, hh, 0);
    k_copy<<<G1((size_t)N0*hh),B256,0,stream>>>(SEG, Y, N0*hh);           // self-loop init
    k_scatter_add<<<G1((size_t)E*hh),B256,0,stream>>>(esrc, edst, Y, SEG, E, hh);
    k_feast_fin<<<G1((size_t)N0*hh),B256,0,stream>>>(SEG, indeg, bb, xout, N0, hh);
  };
  feast(x0, 16, W1, b1, 32, Xa);
  feast(Xa, 32, W2, b2, 64, Xb);
  feast(Xb, 64, W3, b3, 64, Xa);
  float* X = Xa; float* XN = Xb;
  k_mean<<<1,B256,0,stream>>>(X, N0, xs + 0);

  // ---- i=0 gconv_sparse ----
  MS(SEG, (size_t)N0*64*4);
  k_scatter_add<<<G1((size_t)E*64),B256,0,stream>>>(esrc, edst, X, SEG, E, 64);
  k_cnt_sparse<<<G1(N0),B256,0,stream>>>(indeg, cntf, N0);
  k_gconv_fin<<<G1((size_t)N0*64),B256,0,stream>>>(SEG, cntf, Wrel, brel, X, Wroot, XN, N0);
  { float* t = X; X = XN; XN = t; }
  k_mean<<<1,B256,0,stream>>>(X, N0, xs + 64);

  // ---- pool 0 (sparse ASAP), n=1500 -> k=1350 ----
  {
    const int n = 1500, kk = 1350, L = E + n;
    unsigned* xqm = (unsigned*)Y;
    k_mono_init_from<<<G1((size_t)n*64),B256,0,stream>>>(xqm, X, n*64);
    k_scatter_max<<<G1((size_t)E*64),B256,0,stream>>>(esrc, edst, X, xqm, E, 64);
    k_mono_fin<<<G1((size_t)n*64),B256,0,stream>>>(Y, xqm, n*64);
    k_mm_small<<<G1((size_t)n*64),B256,0,stream>>>(Y, pW, pb, XQ2, n, 64, 64, 0);
    k_edge_score<<<G1(L),B256,0,stream>>>(esrc, edst, XQ2, X, sE, E, n);
    k_fill_mono<<<G1(n),B256,0,stream>>>(mmono, n, -3.0e38f);
    k_segmax_edge<<<G1(L),B256,0,stream>>>(esrc, edst, sE, mmono, E, n);
    k_mono_fin<<<G1(n),B256,0,stream>>>(mcol, mmono, n);
    MS(denom, n*4);
    k_exp_edge<<<G1(L),B256,0,stream>>>(esrc, edst, sE, mcol, eE, denom, E, n);
    k_score_edge<<<G1(L),B256,0,stream>>>(esrc, edst, eE, denom, scE, E, n);
    MS(XC, (size_t)n*64*4);
    k_xc_scatter<<<G1((size_t)L*64),B256,0,stream>>>(esrc, edst, scE, X, XC, E, n);
    k_abc<<<G1(n),B256,0,stream>>>(XC, leW1, leb1, leW2, leW3, leb3, aN, bN, cN, n);
    MS(agg1, n*4);
    k_agg_edge<<<G1(L),B256,0,stream>>>(esrc, edst, aN, agg1, E, n);
    k_fit_sparse<<<G1(n),B256,0,stream>>>(agg1, indeg, bN, cN, fit, n);
    k_rank<<<G1(n),B256,0,stream>>>(fit, n, kk, sel);
    k_compact<<<G1(n),B256,0,stream>>>(sel, n, perm);
    k_xnew<<<G1((size_t)kk*64),B256,0,stream>>>(XC, fit, perm, XN, kk);
    // sparse A_new = Sp^T A Sp
    k_prefix<<<G1(n+1),B256,0,stream>>>(outdeg, offS, n);
    k_prefix<<<G1(n+1),B256,0,stream>>>(indeg, offD, n);
    k_copy_int<<<G1(n),B256,0,stream>>>(curS, offS, n);
    k_copy_int<<<G1(n),B256,0,stream>>>(curD, offD, n);
    k_csr_fill<<<G1(L),B256,0,stream>>>(esrc, edst, scE, curS, colS, valS, curD, rowD, valD, E, n);
    MS(R, (size_t)n*n*4);
    k_stage1<<<G1(L),B256,0,stream>>>(esrc, edst, offS, colS, valS, R, E, n);
    k_gather_cols<<<G1((size_t)n*kk),B256,0,stream>>>(R, n, perm, TB, kk, n);
    k_stage2<<<G1((size_t)kk*kk),B256,0,stream>>>(perm, offD, rowD, valD, TB, A0, kk);
    { float* t = X; X = XN; XN = t; }
  }

  float* Acur = A0; float* Aoth = A1s;
  int nn = 1350;

  // ---- dense gconv ----
  auto gconv_dense = [&](int layer){
    MS(cnti, nn*4);
    k_colcount_part<<<G1((size_t)nn*16),B256,0,stream>>>(Acur, nn, cnti);
    k_cnt_fin<<<G1(nn),B256,0,stream>>>(cnti, cntf, nn, 1);
    MS(SEG, (size_t)nn*64*4);
    int kc = kchunk_for(nn, 16);
    dim3 g(1, (nn+63)/64, 16);
    k_gemm<true,true,false><<<g,B256,0,stream>>>(Acur, nn, X, 64, SEG, 64, nn, 64, nn, kc, nullptr, 0, 0);
    k_gconv_fin<<<G1((size_t)nn*64),B256,0,stream>>>(SEG, cntf, Wrel + (size_t)layer*4096, brel + layer*64,
                                                    X, Wroot + (size_t)layer*4096, XN, nn);
    { float* t = X; X = XN; XN = t; }
  };

  // ---- dense ASAP pool ----
  auto asap_dense = [&](int kk, int p){
    k_diagfix<<<G1(nn),B256,0,stream>>>(Acur, nn);
    MS(cnti, nn*4);
    k_colcount_part<<<G1((size_t)nn*16),B256,0,stream>>>(Acur, nn, cnti);
    k_cnt_fin<<<G1(nn),B256,0,stream>>>(cnti, cntP, nn, 0);
    // xq = masked column-max of x, then @ pW + pb
    k_fill_mono<<<G1((size_t)nn*64),B256,0,stream>>>((unsigned*)Y, nn*64, -3.0e38f);
    {
      int kc = kchunk_for(nn, 16);
      dim3 g(1, (nn+63)/64, 16);
      k_gemm<true,true,true><<<g,B256,0,stream>>>(Acur, nn, X, 64, Y, 64, nn, 64, nn, kc, nullptr, 0, 0);
    }
    k_mono_fin<<<G1((size_t)nn*64),B256,0,stream>>>(Y, (unsigned*)Y, nn*64);
    k_mm_small<<<G1((size_t)nn*64),B256,0,stream>>>(Y, pW + (size_t)p*4096, pb + p*64, XQ2, nn, 64, 64, 0);
    // Sc = mask ? lrelu(x @ xq^T) : NEG
    {
      dim3 g((nn+63)/64, (nn+63)/64);
      k_gemm<false,false,false><<<g,B256,0,stream>>>(X, 64, XQ2, 64, SCb, nn, nn, nn, 64, 0, Acur, nn, 1);
    }
    // column softmax (masked)
    k_fill_mono<<<G1(nn),B256,0,stream>>>(mmono, nn, -3.0e38f);
    k_colmax_part<<<G1((size_t)nn*16),B256,0,stream>>>(SCb, nn, mmono);
    k_mono_fin<<<G1(nn),B256,0,stream>>>(mcol, mmono, nn);
    MS(denom, nn*4);
    k_exp_colsum<<<G1((size_t)nn*16),B256,0,stream>>>(SCb, Acur, mcol, denom, nn);
    k_scale_cols<<<G1((size_t)nn*nn),B256,0,stream>>>(SCb, denom, nn);
    // xc = score^T @ x
    MS(XC, (size_t)nn*64*4);
    {
      int kc = kchunk_for(nn, 16);
      dim3 g(1, (nn+63)/64, 16);
      k_gemm<true,true,false><<<g,B256,0,stream>>>(SCb, nn, X, 64, XC, 64, nn, 64, nn, kc, nullptr, 0, 0);
    }
    k_abc<<<G1(nn),B256,0,stream>>>(XC, leW1 + p*64, leb1 + p, leW2 + p*64, leW3 + p*64, leb3 + p, aN, bN, cN, nn);
    MS(agg1, nn*4);
    k_aggcol_part<<<G1((size_t)nn*16),B256,0,stream>>>(Acur, aN, agg1, nn);
    k_fit_dense<<<G1(nn),B256,0,stream>>>(agg1, cntP, bN, cN, fit, nn);
    k_rank<<<G1(nn),B256,0,stream>>>(fit, nn, kk, sel);
    k_compact<<<G1(nn),B256,0,stream>>>(sel, nn, perm);
    k_xnew<<<G1((size_t)kk*64),B256,0,stream>>>(XC, fit, perm, XN, kk);
    // A_new = Sp^T @ (A' @ Sp), diag zeroed
    k_gather_cols<<<G1((size_t)nn*kk),B256,0,stream>>>(SCb, nn, perm, SPD, kk, nn);
    {
      dim3 g((kk+63)/64, (nn+63)/64);
      k_gemm<false,true,false><<<g,B256,0,stream>>>(Acur, nn, SPD, kk, TB, kk, nn, kk, nn, 0, nullptr, 0, 0);
    }
    {
      dim3 g((kk+63)/64, (kk+63)/64);
      k_gemm<true,true,false><<<g,B256,0,stream>>>(SPD, kk, TB, kk, Aoth, kk, kk, kk, nn, 0, nullptr, 0, 2);
    }
    { float* t = X; X = XN; XN = t; }
    { float* t = Acur; Acur = Aoth; Aoth = t; }
    nn = kk;
  };

  // i=1
  gconv_dense(1); k_mean<<<1,B256,0,stream>>>(X, nn, xs + 2*64);
  // i=2 + pool 1
  gconv_dense(2); k_mean<<<1,B256,0,stream>>>(X, nn, xs + 3*64);
  asap_dense(1215, 1);
  // i=3
  gconv_dense(3); k_mean<<<1,B256,0,stream>>>(X, nn, xs + 4*64);
  // i=4 + pool 2
  gconv_dense(4); k_mean<<<1,B256,0,stream>>>(X, nn, xs + 5*64);
  asap_dense(1094, 2);
  // i=5
  gconv_dense(5); k_mean<<<1,B256,0,stream>>>(X, nn, xs + 6*64);
  // i=6 + pool 3
  gconv_dense(6); k_mean<<<1,B256,0,stream>>>(X, nn, xs + 7*64);
  asap_dense(985, 3);
  // i=7
  gconv_dense(7); k_mean<<<1,B256,0,stream>>>(X, nn, xs + 8*64);
  // i=8
  gconv_dense(8); k_mean<<<1,B256,0,stream>>>(X, nn, xs + 9*64);

  // ---- head ----
  k_mm_small<<<G1(64),B256,0,stream>>>(xs, linW1, linb1, Y, 1, 640, 64, 1);
  k_head<<<1,64,0,stream>>>(Y, linW2, linb2, out);
}

// Round 2
// 3462.524 us; speedup vs baseline: 1.1922x; 1.1922x over previous
//
#include <hip/hip_runtime.h>
#include <math.h>

#define NEGV -1000000000.0f

typedef short short8 __attribute__((ext_vector_type(8)));
typedef float floatx4 __attribute__((ext_vector_type(4)));

__device__ __forceinline__ unsigned f2mono(float f){
  unsigned u = __float_as_uint(f);
  return (u & 0x80000000u) ? ~u : (u | 0x80000000u);
}
__device__ __forceinline__ float mono2f(unsigned u){
  return __uint_as_float((u & 0x80000000u) ? (u & 0x7fffffffu) : ~u);
}
__device__ __forceinline__ float sigm(float x){ return 1.0f/(1.0f+expf(-x)); }
__device__ __forceinline__ void edge_sd(int e,const int* src,const int* dst,int E,int& s,int& d){
  if(e<E){ s=src[e]; d=dst[e]; } else { s=e-E; d=s; }
}
__device__ __forceinline__ ushort bf16rn(float x){
  unsigned u = __float_as_uint(x);
  unsigned r = (u + 0x7fffu + ((u>>16)&1u)) >> 16;
  return (ushort)r;
}
__device__ __forceinline__ float bf16f(ushort h){ return __uint_as_float(((unsigned)h)<<16); }

// ---------------- bf16x3 split conversions ----------------
// dst is R x 3*Cp bf16, K-innermost. bmode 0 (A role): [h,h,l]; bmode 1 (B role): [h,l,h].
__global__ void k_split3(const float* __restrict__ src,int R,int Cs,int ld,
                         ushort* __restrict__ dst,int Cp,int bmode){
  int idx = blockIdx.x*256+threadIdx.x;
  if (idx >= R*Cp) return;
  int r = idx / Cp, c = idx - r*Cp;
  float x = (c < Cs) ? src[(size_t)r*ld + c] : 0.0f;
  ushort h = bf16rn(x);
  ushort l = bf16rn(x - bf16f(h));
  size_t base = (size_t)r*(3*Cp) + c;
  dst[base]        = h;
  dst[base + Cp]   = bmode ? l : h;
  dst[base + 2*Cp] = bmode ? h : l;
}
// transpose variant: src stored Rs(K) x Cs(X) (ld), dst is Cs x 3*Kp bf16.
__global__ void k_split3_T(const float* __restrict__ src,int Rs,int Cs,int ld,
                           ushort* __restrict__ dst,int Kp,int bmode){
  __shared__ float t[32][33];
  int tx = threadIdx.x & 31, ty = threadIdx.x >> 5;
  int kb = blockIdx.y*32, xb = blockIdx.x*32;
#pragma unroll
  for (int i=0;i<4;i++){
    int k = kb + ty + i*8, x = xb + tx;
    t[ty+i*8][tx] = (k < Rs && x < Cs) ? src[(size_t)k*ld + x] : 0.0f;
  }
  __syncthreads();
  const int K3 = 3*Kp;
#pragma unroll
  for (int i=0;i<4;i++){
    int xo = xb + ty + i*8, ko = kb + tx;
    if (xo < Cs){
      float v = t[tx][ty+i*8];
      ushort h = bf16rn(v);
      ushort l = bf16rn(v - bf16f(h));
      size_t base = (size_t)xo*K3 + ko;
      dst[base]        = h;
      dst[base + Kp]   = bmode ? l : h;
      dst[base + 2*Kp] = bmode ? h : l;
    }
  }
}

// ---------------- MFMA bf16 GEMM (64x64 tile, 4 waves, 16x16x32) ----------------
// A: M x K3 bf16 (K-innermost), B: N x K3 bf16 (K-innermost), C: fp32 M x N (ldc).
// K3 must be a multiple of 32. EPI: 0 none, 1 mask+leakyrelu(NEG where mask==0), 2 zero diagonal.
template<int EPI>
__global__ __launch_bounds__(256) void k_gemm_mfma(
    const ushort* __restrict__ A, const ushort* __restrict__ B,
    float* __restrict__ C, int ldc, int M, int N, int K3,
    const float* __restrict__ mask, int ldm)
{
  __shared__ ushort As[64][40];
  __shared__ ushort Bs[64][40];
  const int tid = threadIdx.x;
  const int m0 = blockIdx.y*64, n0 = blockIdx.x*64;
  const int w = tid>>6, lane = tid&63;
  const int lo4 = lane&15, quad = lane>>4;
  const int sr = tid>>2, sseg = tid&3;

  floatx4 acc[4];
#pragma unroll
  for(int c=0;c<4;c++){ acc[c][0]=0.f; acc[c][1]=0.f; acc[c][2]=0.f; acc[c][3]=0.f; }

  const size_t arow = (size_t)(m0+sr)*K3;
  const size_t brow = (size_t)(n0+sr)*K3;
  const bool aval = (m0+sr) < M;
  const bool bval = (n0+sr) < N;

  for (int k0 = 0; k0 < K3; k0 += 32) {
    uint4 av = make_uint4(0,0,0,0), bv = make_uint4(0,0,0,0);
    if (aval) av = *(const uint4*)(A + arow + k0 + sseg*8);
    if (bval) bv = *(const uint4*)(B + brow + k0 + sseg*8);
    __syncthreads();
    *(uint4*)&As[sr][sseg*8] = av;
    *(uint4*)&Bs[sr][sseg*8] = bv;
    __syncthreads();
    short8 af = *(const short8*)&As[16*w + lo4][quad*8];
#pragma unroll
    for (int c=0;c<4;c++){
      short8 bf = *(const short8*)&Bs[16*c + lo4][quad*8];
      acc[c] = __builtin_amdgcn_mfma_f32_16x16x32_bf16(af, bf, acc[c], 0, 0, 0);
    }
  }

#pragma unroll
  for (int c=0;c<4;c++){
    const int gn = n0 + 16*c + lo4;
#pragma unroll
    for (int r=0;r<4;r++){
      const int gm = m0 + 16*w + quad*4 + r;
      if (gm < M && gn < N){
        float v = acc[c][r];
        if (EPI==1) v = (mask[(size_t)gm*ldm+gn] != 0.0f) ? (v > 0.0f ? v : 0.2f*v) : NEGV;
        if (EPI==2 && gm==gn) v = 0.0f;
        C[(size_t)gm*ldc+gn] = v;
      }
    }
  }
}

// ---------------- generic tiled fp32 GEMM (kept for skinny / masked-max) ----------------
template<bool ADIR, bool BDIR, bool MAXM>
__global__ __launch_bounds__(256) void k_gemm(
    const float* __restrict__ A, int lda,
    const float* __restrict__ B, int ldb,
    float* __restrict__ C, int ldc,
    int M, int N, int K, int kchunk,
    const float* __restrict__ mask, int ldm, int epi)
{
  __shared__ float Asm[16][68];
  __shared__ float Bsm[16][68];
  const int tid = threadIdx.x;
  const int m0 = blockIdx.y * 64, n0 = blockIdx.x * 64;
  const int tmb = (tid & 15) * 4, tnb = (tid >> 4) * 4;
  float acc[4][4];
#pragma unroll
  for (int i=0;i<4;i++)
#pragma unroll
    for (int j=0;j<4;j++) acc[i][j] = MAXM ? NEGV : 0.0f;

  int kstart = 0, kend = K;
  if (kchunk > 0) { kstart = blockIdx.z * kchunk; kend = kstart + kchunk; if (kend > K) kend = K; }

  for (int k0 = kstart; k0 < kend; k0 += 16) {
    if (ADIR) {
      const int m = m0 + (tid & 63);
      const int tb = tid >> 6;
#pragma unroll
      for (int s=0;s<4;s++) {
        const int tk = tb + s*4;
        float v = 0.0f;
        if (m < M && (k0+tk) < K) v = A[(size_t)(k0+tk)*lda + m];
        Asm[tk][tid & 63] = v;
      }
    } else {
      const int tm = tid >> 2, tb = (tid & 3) * 4;
#pragma unroll
      for (int s=0;s<4;s++) {
        const int tk = tb + s;
        float v = 0.0f;
        if ((m0+tm) < M && (k0+tk) < K) v = A[(size_t)(m0+tm)*lda + (k0+tk)];
        Asm[tk][tm] = v;
      }
    }
    if (BDIR) {
      const int nn = n0 + (tid & 63);
      const int tb = tid >> 6;
#pragma unroll
      for (int s=0;s<4;s++) {
        const int tk = tb + s*4;
        float v = 0.0f;
        if (nn < N && (k0+tk) < K) v = B[(size_t)(k0+tk)*ldb + nn];
        Bsm[tk][tid & 63] = v;
      }
    } else {
      const int tn = tid >> 2, tb = (tid & 3) * 4;
#pragma unroll
      for (int s=0;s<4;s++) {
        const int tk = tb + s;
        float v = 0.0f;
        if ((n0+tn) < N && (k0+tk) < K) v = B[(size_t)(n0+tn)*ldb + (k0+tk)];
        Bsm[tk][tn] = v;
      }
    }
    __syncthreads();
#pragma unroll
    for (int kk=0; kk<16; kk++) {
      const float4 a4 = *(const float4*)&Asm[kk][tmb];
      const float4 b4 = *(const float4*)&Bsm[kk][tnb];
      const float av[4] = {a4.x,a4.y,a4.z,a4.w};
      const float bv[4] = {b4.x,b4.y,b4.z,b4.w};
#pragma unroll
      for (int i=0;i<4;i++)
#pragma unroll
        for (int j=0;j<4;j++) {
          if (MAXM) acc[i][j] = fmaxf(acc[i][j], av[i] != 0.0f ? bv[j] : NEGV);
          else      acc[i][j] = fmaf(av[i], bv[j], acc[i][j]);
        }
    }
    __syncthreads();
  }

  const bool split = (gridDim.z > 1);
#pragma unroll
  for (int i=0;i<4;i++)
#pragma unroll
    for (int j=0;j<4;j++) {
      const int m = m0 + tmb + i, nn = n0 + tnb + j;
      if (m < M && nn < N) {
        float v = acc[i][j];
        if (split) {
          if (MAXM) atomicMax((unsigned*)&C[(size_t)m*ldc + nn], f2mono(v));
          else atomicAdd(&C[(size_t)m*ldc + nn], v);
        } else {
          if (epi == 1) { v = (mask[(size_t)m*ldm + nn] != 0.0f) ? (v > 0.0f ? v : 0.2f*v) : NEGV; }
          else if (epi == 2) { if (m == nn) v = 0.0f; }
          C[(size_t)m*ldc + nn] = v;
        }
      }
    }
}

// ---------------- small kernels ----------------
__global__ void k_deg(const int* __restrict__ src,const int* __restrict__ dst,int* indeg,int* outdeg,int E){
  int e = blockIdx.x*256+threadIdx.x; if(e>=E) return;
  atomicAdd(&indeg[dst[e]],1); atomicAdd(&outdeg[src[e]],1);
}

__global__ void k_mm_small(const float* __restrict__ A,const float* __restrict__ W,
                           const float* __restrict__ b,float* __restrict__ C,
                           int M,int K,int Np,int act){
  int idx = blockIdx.x*256+threadIdx.x; if(idx>=M*Np) return;
  int m = idx/Np, j = idx - m*Np;
  float s = b ? b[j] : 0.0f;
  const float* a = A + (size_t)m*K;
  for(int q=0;q<K;q++) s = fmaf(a[q], W[(size_t)q*Np + j], s);
  if(act==1) s = fmaxf(s, 0.0f);
  C[idx] = s;
}

__global__ void k_copy(float* d,const float* s,int n){ int i=blockIdx.x*256+threadIdx.x; if(i<n) d[i]=s[i]; }
__global__ void k_copy_int(int* d,const int* s,int n){ int i=blockIdx.x*256+threadIdx.x; if(i<n) d[i]=s[i]; }

__global__ void k_scatter_add(const int* __restrict__ src,const int* __restrict__ dst,
                              const float* __restrict__ Y,float* SEG,int E,int H){
  int idx = blockIdx.x*256+threadIdx.x; if(idx>=E*H) return;
  int e = idx/H, h = idx - e*H;
  atomicAdd(&SEG[(size_t)dst[e]*H + h], Y[(size_t)src[e]*H + h]);
}

__global__ void k_feast_fin(const float* __restrict__ SEG,const int* __restrict__ indeg,
                            const float* __restrict__ b,float* X,int n,int H){
  int idx = blockIdx.x*256+threadIdx.x; if(idx>=n*H) return;
  int i = idx/H, h = idx - i*H;
  float v = SEG[idx]/(float)(indeg[i]+1) + b[h];
  X[idx] = v > 0.0f ? v : (expf(v)-1.0f);
}

__global__ void k_cnt_sparse(const int* indeg,float* cntf,int n){
  int i = blockIdx.x*256+threadIdx.x; if(i>=n) return;
  cntf[i] = (float)(indeg[i] > 1 ? indeg[i] : 1);
}

__global__ void k_gconv_fin(const float* __restrict__ AGG,const float* __restrict__ cnt,
                            const float* __restrict__ Wrel,const float* __restrict__ brel,
                            const float* __restrict__ X,const float* __restrict__ Wroot,
                            float* XN,int n){
  int idx = blockIdx.x*256+threadIdx.x; if(idx>=n*64) return;
  int i = idx >> 6, j = idx & 63;
  const float* ag = AGG + (size_t)i*64;
  const float* xr = X + (size_t)i*64;
  float a = 0.0f, r = 0.0f;
  for(int q=0;q<64;q++){ a = fmaf(ag[q], Wrel[q*64+j], a); r = fmaf(xr[q], Wroot[q*64+j], r); }
  float v = a/cnt[i] + brel[j] + r;
  XN[idx] = fmaxf(v, 0.0f);
}

__global__ void k_mean(const float* __restrict__ X,int n,float* o){
  __shared__ float sh[256];
  int t = threadIdx.x; int h = t & 63, p = t >> 6;
  float s = 0.0f;
  for(int i=p;i<n;i+=4) s += X[(size_t)i*64 + h];
  sh[t] = s; __syncthreads();
  if(t < 64) o[t] = (sh[t]+sh[t+64]+sh[t+128]+sh[t+192])/(float)n;
}

__global__ void k_mono_init_from(unsigned* M,const float* X,int n){
  int i = blockIdx.x*256+threadIdx.x; if(i<n) M[i] = f2mono(X[i]);
}
__global__ void k_fill_mono(unsigned* M,int n,float v){
  int i = blockIdx.x*256+threadIdx.x; if(i<n) M[i] = f2mono(v);
}
__global__ void k_mono_fin(float* out,const unsigned* M,int n){
  int i = blockIdx.x*256+threadIdx.x; if(i<n){ unsigned u = M[i]; out[i] = mono2f(u); }
}
__global__ void k_scatter_max(const int* __restrict__ src,const int* __restrict__ dst,
                              const float* __restrict__ X,unsigned* M,int E,int H){
  int idx = blockIdx.x*256+threadIdx.x; if(idx>=E*H) return;
  int e = idx/H, h = idx - e*H;
  atomicMax(&M[(size_t)dst[e]*H + h], f2mono(X[(size_t)src[e]*H + h]));
}

__global__ void k_edge_score(const int* __restrict__ src,const int* __restrict__ dst,
                             const float* __restrict__ XQ2,const float* __restrict__ X,
                             float* sE,int E,int n){
  int e = blockIdx.x*256+threadIdx.x; if(e>=E+n) return;
  int s,d; edge_sd(e,src,dst,E,s,d);
  const float* q = XQ2 + (size_t)d*64;
  const float* x = X + (size_t)s*64;
  float acc = 0.0f;
  for(int h=0;h<64;h++) acc = fmaf(q[h], x[h], acc);
  sE[e] = acc > 0.0f ? acc : 0.2f*acc;
}
__global__ void k_segmax_edge(const int* src,const int* dst,const float* sE,unsigned* M,int E,int n){
  int e = blockIdx.x*256+threadIdx.x; if(e>=E+n) return;
  int s,d; edge_sd(e,src,dst,E,s,d);
  atomicMax(&M[d], f2mono(sE[e]));
}
__global__ void k_exp_edge(const int* src,const int* dst,const float* sE,const float* m,
                           float* eE,float* denom,int E,int n){
  int e = blockIdx.x*256+threadIdx.x; if(e>=E+n) return;
  int s,d; edge_sd(e,src,dst,E,s,d);
  float v = expf(sE[e]-m[d]); eE[e]=v; atomicAdd(&denom[d],v);
}
__global__ void k_score_edge(const int* src,const int* dst,const float* eE,const float* denom,
                             float* scE,int E,int n){
  int e = blockIdx.x*256+threadIdx.x; if(e>=E+n) return;
  int s,d; edge_sd(e,src,dst,E,s,d);
  scE[e] = eE[e]/denom[d];
}
__global__ void k_xc_scatter(const int* __restrict__ src,const int* __restrict__ dst,
                             const float* __restrict__ scE,const float* __restrict__ X,
                             float* XC,int E,int n){
  int idx = blockIdx.x*256+threadIdx.x; if(idx>=(E+n)*64) return;
  int e = idx >> 6, h = idx & 63;
  int s,d; edge_sd(e,src,dst,E,s,d);
  atomicAdd(&XC[(size_t)d*64 + h], scE[e]*X[(size_t)s*64 + h]);
}
__global__ void k_abc(const float* __restrict__ XC,const float* __restrict__ w1,const float* bb1,
                      const float* __restrict__ w2,const float* __restrict__ w3,const float* bb3,
                      float* aN,float* bN,float* cN,int n){
  int v = blockIdx.x*256+threadIdx.x; if(v>=n) return;
  const float* xc = XC + (size_t)v*64;
  float a = bb1[0], b = 0.0f, c = bb3[0];
  for(int h=0;h<64;h++){ a=fmaf(xc[h],w1[h],a); b=fmaf(xc[h],w2[h],b); c=fmaf(xc[h],w3[h],c); }
  aN[v]=a; bN[v]=b; cN[v]=c;
}
__global__ void k_agg_edge(const int* src,const int* dst,const float* aN,float* agg,int E,int n){
  int e = blockIdx.x*256+threadIdx.x; if(e>=E+n) return;
  int s,d; edge_sd(e,src,dst,E,s,d);
  atomicAdd(&agg[d], aN[s]);
}
__global__ void k_fit_sparse(const float* agg,const int* indeg,const float* bN,const float* cN,
                             float* fit,int n){
  int v = blockIdx.x*256+threadIdx.x; if(v>=n) return;
  fit[v] = sigm(agg[v] - (float)(indeg[v]+1)*bN[v] + cN[v]);
}
__global__ void k_fit_dense(const float* agg,const float* cntP,const float* bN,const float* cN,
                            float* fit,int n){
  int v = blockIdx.x*256+threadIdx.x; if(v>=n) return;
  fit[v] = sigm(agg[v] - cntP[v]*bN[v] + cN[v]);
}

__global__ void k_rank(const float* __restrict__ fit,int n,int k,int* sel){
  int v = blockIdx.x*256+threadIdx.x; if(v>=n) return;
  float fv = fit[v]; int r = 0;
  for(int u=0;u<n;u++){ float fu = fit[u]; if(fu > fv || (fu == fv && u < v)) r++; }
  sel[v] = (r < k) ? 1 : 0;
}
__global__ void k_compact(const int* __restrict__ sel,int n,int* perm){
  int v = blockIdx.x*256+threadIdx.x; if(v>=n || !sel[v]) return;
  int p = 0;
  for(int u=0;u<v;u++) p += sel[u];
  perm[p] = v;
}
__global__ void k_xnew(const float* __restrict__ XC,const float* __restrict__ fit,
                       const int* __restrict__ perm,float* XN,int k){
  int idx = blockIdx.x*256+threadIdx.x; if(idx>=k*64) return;
  int u = idx >> 6, h = idx & 63; int v = perm[u];
  XN[idx] = XC[(size_t)v*64 + h]*fit[v];
}

__global__ void k_prefix(const int* __restrict__ deg,int* off,int n){
  int t = blockIdx.x*256+threadIdx.x; if(t>n) return;
  int s = 0;
  for(int u=0;u<t;u++) s += deg[u]+1;
  off[t] = s;
}
__global__ void k_csr_fill(const int* src,const int* dst,const float* scE,
                           int* curS,int* colS,float* valS,
                           int* curD,int* rowD,float* valD,int E,int n){
  int e = blockIdx.x*256+threadIdx.x; if(e>=E+n) return;
  int s,d; edge_sd(e,src,dst,E,s,d);
  float sc = scE[e];
  int p = atomicAdd(&curS[s],1); colS[p]=d; valS[p]=sc;
  int q = atomicAdd(&curD[d],1); rowD[q]=s; valD[q]=sc;
}
__global__ void k_stage1(const int* src,const int* dst,const int* __restrict__ offS,
                         const int* __restrict__ colS,const float* __restrict__ valS,
                         float* R,int E,int n){
  int e = blockIdx.x*256+threadIdx.x; if(e>=E+n) return;
  int i,j; edge_sd(e,src,dst,E,i,j);
  int p0 = offS[j], p1 = offS[j+1];
  float* Ri = R + (size_t)i*n;
  for(int p=p0;p<p1;p++) atomicAdd(&Ri[colS[p]], valS[p]);
}
__global__ void k_gather_cols(const float* __restrict__ S,int ldS,const int* __restrict__ perm,
                              float* out,int k,int rows){
  int idx = blockIdx.x*256+threadIdx.x; if(idx>=rows*k) return;
  int i = idx/k, u = idx - i*k;
  out[idx] = S[(size_t)i*ldS + perm[u]];
}
__global__ void k_stage2(const int* __restrict__ perm,const int* __restrict__ offD,
                         const int* __restrict__ rowD,const float* __restrict__ valD,
                         const float* __restrict__ Rp,float* A,int k){
  int idx = blockIdx.x*256+threadIdx.x; if(idx>=k*k) return;
  int u = idx/k, v = idx - u*k; int d = perm[u];
  float acc = 0.0f;
  int p0 = offD[d], p1 = offD[d+1];
  for(int p=p0;p<p1;p++) acc = fmaf(valD[p], Rp[(size_t)rowD[p]*k + v], acc);
  A[idx] = (u==v) ? 0.0f : acc;
}

__global__ void k_diagfix(float* A,int n){
  int i = blockIdx.x*256+threadIdx.x; if(i>=n) return;
  size_t d = (size_t)i*n + i;
  if(A[d]==0.0f) A[d]=1.0f;
}
__global__ void k_colcount_part(const float* __restrict__ A,int n,int* cnt){
  int idx = blockIdx.x*256+threadIdx.x; if(idx>=n*16) return;
  int j = idx % n, c = idx / n;
  int i0 = (int)(((long long)n*c)/16), i1 = (int)(((long long)n*(c+1))/16);
  int s = 0;
  for(int i=i0;i<i1;i++) s += (A[(size_t)i*n + j] != 0.0f) ? 1 : 0;
  if(s) atomicAdd(&cnt[j], s);
}
__global__ void k_cnt_fin(const int* cnt,float* out,int n,int clampMin){
  int j = blockIdx.x*256+threadIdx.x; if(j>=n) return;
  int c = cnt[j]; if(c < clampMin) c = clampMin;
  out[j] = (float)c;
}
__global__ void k_colmax_part(const float* __restrict__ S,int n,unsigned* M){
  int idx = blockIdx.x*256+threadIdx.x; if(idx>=n*16) return;
  int j = idx % n, c = idx / n;
  int i0 = (int)(((long long)n*c)/16), i1 = (int)(((long long)n*(c+1))/16);
  float lm = -3.0e38f;
  for(int i=i0;i<i1;i++) lm = fmaxf(lm, S[(size_t)i*n + j]);
  atomicMax(&M[j], f2mono(lm));
}
__global__ void k_exp_colsum(float* S,const float* __restrict__ A,const float* __restrict__ m,
                             float* denom,int n){
  int idx = blockIdx.x*256+threadIdx.x; if(idx>=n*16) return;
  int j = idx % n, c = idx / n;
  int i0 = (int)(((long long)n*c)/16), i1 = (int)(((long long)n*(c+1))/16);
  float mj = m[j], ls = 0.0f;
  for(int i=i0;i<i1;i++){
    size_t o = (size_t)i*n + j;
    float v = (A[o] != 0.0f) ? expf(S[o]-mj) : 0.0f;
    S[o] = v; ls += v;
  }
  if(ls != 0.0f) atomicAdd(&denom[j], ls);
}
__global__ void k_scale_cols(float* S,const float* __restrict__ denom,int n){
  int idx = blockIdx.x*256+threadIdx.x; if(idx>=n*n) return;
  int j = idx % n;
  S[idx] /= denom[j];
}
__global__ void k_aggcol_part(const float* __restrict__ A,const float* __restrict__ aN,
                              float* agg,int n){
  int idx = blockIdx.x*256+threadIdx.x; if(idx>=n*16) return;
  int j = idx % n, c = idx / n;
  int i0 = (int)(((long long)n*c)/16), i1 = (int)(((long long)n*(c+1))/16);
  float s = 0.0f;
  for(int i=i0;i<i1;i++) if(A[(size_t)i*n + j] != 0.0f) s += aN[i];
  if(s != 0.0f) atomicAdd(&agg[j], s);
}

__global__ void k_head(const float* __restrict__ h2,const float* __restrict__ W,
                       const float* __restrict__ b,float* out){
  __shared__ float lg[10];
  int t = threadIdx.x;
  if(t < 10){
    float s = b[t];
    for(int k=0;k<64;k++) s = fmaf(h2[k], W[k*10+t], s);
    lg[t] = s;
  }
  __syncthreads();
  if(t == 0){
    float mx = lg[0];
    for(int i=1;i<10;i++) mx = fmaxf(mx, lg[i]);
    float se = 0.0f;
    for(int i=0;i<10;i++) se += expf(lg[i]-mx);
    float lse = mx + logf(se);
    for(int i=0;i<10;i++) out[i] = lg[i]-lse;
  }
}

// ---------------- host orchestration ----------------
extern "C" void kernel_launch(void* const* d_in, const int* in_sizes, int n_in,
                              void* d_out, int out_size, void* d_ws, size_t ws_size,
                              hipStream_t stream) {
  const int N0 = 1500, E = 24000;
  const float* x0   = (const float*)d_in[0];
  const int* esrc   = (const int*)d_in[1];
  const int* edst   = (const int*)d_in[2];
  const float* W1   = (const float*)d_in[3];  const float* b1   = (const float*)d_in[4];
  const float* W2   = (const float*)d_in[5];  const float* b2   = (const float*)d_in[6];
  const float* W3   = (const float*)d_in[7];  const float* b3   = (const float*)d_in[8];
  const float* Wrel = (const float*)d_in[9];  const float* brel = (const float*)d_in[10];
  const float* Wroot= (const float*)d_in[11];
  const float* pW   = (const float*)d_in[12]; const float* pb   = (const float*)d_in[13];
  const float* leW1 = (const float*)d_in[14]; const float* leb1 = (const float*)d_in[15];
  const float* leW2 = (const float*)d_in[16]; const float* leW3 = (const float*)d_in[17];
  const float* leb3 = (const float*)d_in[18];
  const float* linW1= (const float*)d_in[19]; const float* linb1= (const float*)d_in[20];
  const float* linW2= (const float*)d_in[21]; const float* linb2= (const float*)d_in[22];
  float* out = (float*)d_out;

  float* ws = (float*)d_ws;
  size_t cur = 0;
  auto allocF = [&](size_t nf)->float*{ float* p = ws + cur; cur += (nf + 15) & ~(size_t)15; return p; };
  float* Xa  = allocF(96000); float* Xb  = allocF(96000); float* Y   = allocF(96000);
  float* XQ2 = allocF(96000); float* XC  = allocF(96000); float* SEG = allocF(96000);
  float* xs  = allocF(640);
  float* mcol = allocF(1500); float* denom = allocF(1500);
  float* aN = allocF(1500); float* bN = allocF(1500); float* cN = allocF(1500);
  float* fit = allocF(1500); float* agg1 = allocF(1500); float* cntf = allocF(1500); float* cntP = allocF(1500);
  int* indeg = (int*)allocF(1500); int* outdeg = (int*)allocF(1500); int* cnti = (int*)allocF(1500);
  int* sel = (int*)allocF(1500); int* perm = (int*)allocF(1500);
  int* offS = (int*)allocF(1504); int* offD = (int*)allocF(1504);
  int* curS = (int*)allocF(1504); int* curD = (int*)allocF(1504);
  int* colS = (int*)allocF(25504); int* rowD = (int*)allocF(25504);
  unsigned* mmono = (unsigned*)allocF(1504);
  float* valS = allocF(25504); float* valD = allocF(25504);
  float* sE = allocF(25504); float* eE = allocF(25504); float* scE = allocF(25504);
  float* R   = allocF((size_t)1500*1500);
  float* TB  = allocF((size_t)1500*1350);
  float* SPD = allocF((size_t)1350*1215 + 16);
  float* SCb = allocF((size_t)1350*1350);
  float* A0  = allocF((size_t)1350*1350);
  float* A1s = allocF((size_t)1350*1350);
  // bf16x3 operand buffers: max nn*3*round32(nn) ushorts = 1350*4128
  ushort* Abf = (ushort*)allocF((size_t)1350*4128/2 + 32);
  ushort* Bbf = (ushort*)allocF((size_t)1350*4128/2 + 32);

  dim3 B256(256);
  auto G1 = [&](size_t n){ return dim3((unsigned)((n + 255) / 256)); };
  auto MS = [&](void* p, size_t bytes){ hipMemsetAsync(p, 0, bytes, stream); };
  auto kchunk_for = [&](int K, int Z){ return (int)(((K + Z*16 - 1) / (Z*16)) * 16); };

  // degrees
  MS(indeg, 1500*4); MS(outdeg, 1500*4);
  k_deg<<<G1(E),B256,0,stream>>>(esrc, edst, indeg, outdeg, E);

  // ---- FEAST x3 ----
  auto feast = [&](const float* xin,int cin,const float* W,const float* bb,int hh,float* xout){
    k_mm_small<<<G1((size_t)N0*hh),B256,0,stream>>>(xin, W, nullptr, Y, N0, cin, hh, 0);
    k_copy<<<G1((size_t)N0*hh),B256,0,stream>>>(SEG, Y, N0*hh);           // self-loop init
    k_scatter_add<<<G1((size_t)E*hh),B256,0,stream>>>(esrc, edst, Y, SEG, E, hh);
    k_feast_fin<<<G1((size_t)N0*hh),B256,0,stream>>>(SEG, indeg, bb, xout, N0, hh);
  };
  feast(x0, 16, W1, b1, 32, Xa);
  feast(Xa, 32, W2, b2, 64, Xb);
  feast(Xb, 64, W3, b3, 64, Xa);
  float* X = Xa; float* XN = Xb;
  k_mean<<<1,B256,0,stream>>>(X, N0, xs + 0);

  // ---- i=0 gconv_sparse ----
  MS(SEG, (size_t)N0*64*4);
  k_scatter_add<<<G1((size_t)E*64),B256,0,stream>>>(esrc, edst, X, SEG, E, 64);
  k_cnt_sparse<<<G1(N0),B256,0,stream>>>(indeg, cntf, N0);
  k_gconv_fin<<<G1((size_t)N0*64),B256,0,stream>>>(SEG, cntf, Wrel, brel, X, Wroot, XN, N0);
  { float* t = X; X = XN; XN = t; }
  k_mean<<<1,B256,0,stream>>>(X, N0, xs + 64);

  // ---- pool 0 (sparse ASAP), n=1500 -> k=1350 ----
  {
    const int n = 1500, kk = 1350, L = E + n;
    unsigned* xqm = (unsigned*)Y;
    k_mono_init_from<<<G1((size_t)n*64),B256,0,stream>>>(xqm, X, n*64);
    k_scatter_max<<<G1((size_t)E*64),B256,0,stream>>>(esrc, edst, X, xqm, E, 64);
    k_mono_fin<<<G1((size_t)n*64),B256,0,stream>>>(Y, xqm, n*64);
    k_mm_small<<<G1((size_t)n*64),B256,0,stream>>>(Y, pW, pb, XQ2, n, 64, 64, 0);
    k_edge_score<<<G1(L),B256,0,stream>>>(esrc, edst, XQ2, X, sE, E, n);
    k_fill_mono<<<G1(n),B256,0,stream>>>(mmono, n, -3.0e38f);
    k_segmax_edge<<<G1(L),B256,0,stream>>>(esrc, edst, sE, mmono, E, n);
    k_mono_fin<<<G1(n),B256,0,stream>>>(mcol, mmono, n);
    MS(denom, n*4);
    k_exp_edge<<<G1(L),B256,0,stream>>>(esrc, edst, sE, mcol, eE, denom, E, n);
    k_score_edge<<<G1(L),B256,0,stream>>>(esrc, edst, eE, denom, scE, E, n);
    MS(XC, (size_t)n*64*4);
    k_xc_scatter<<<G1((size_t)L*64),B256,0,stream>>>(esrc, edst, scE, X, XC, E, n);
    k_abc<<<G1(n),B256,0,stream>>>(XC, leW1, leb1, leW2, leW3, leb3, aN, bN, cN, n);
    MS(agg1, n*4);
    k_agg_edge<<<G1(L),B256,0,stream>>>(esrc, edst, aN, agg1, E, n);
    k_fit_sparse<<<G1(n),B256,0,stream>>>(agg1, indeg, bN, cN, fit, n);
    k_rank<<<G1(n),B256,0,stream>>>(fit, n, kk, sel);
    k_compact<<<G1(n),B256,0,stream>>>(sel, n, perm);
    k_xnew<<<G1((size_t)kk*64),B256,0,stream>>>(XC, fit, perm, XN, kk);
    // sparse A_new = Sp^T A Sp
    k_prefix<<<G1(n+1),B256,0,stream>>>(outdeg, offS, n);
    k_prefix<<<G1(n+1),B256,0,stream>>>(indeg, offD, n);
    k_copy_int<<<G1(n),B256,0,stream>>>(curS, offS, n);
    k_copy_int<<<G1(n),B256,0,stream>>>(curD, offD, n);
    k_csr_fill<<<G1(L),B256,0,stream>>>(esrc, edst, scE, curS, colS, valS, curD, rowD, valD, E, n);
    MS(R, (size_t)n*n*4);
    k_stage1<<<G1(L),B256,0,stream>>>(esrc, edst, offS, colS, valS, R, E, n);
    k_gather_cols<<<G1((size_t)n*kk),B256,0,stream>>>(R, n, perm, TB, kk, n);
    k_stage2<<<G1((size_t)kk*kk),B256,0,stream>>>(perm, offD, rowD, valD, TB, A0, kk);
    { float* t = X; X = XN; XN = t; }
  }

  float* Acur = A0; float* Aoth = A1s;
  int nn = 1350;

  // ---- dense gconv ----
  auto gconv_dense = [&](int layer){
    MS(cnti, nn*4);
    k_colcount_part<<<G1((size_t)nn*16),B256,0,stream>>>(Acur, nn, cnti);
    k_cnt_fin<<<G1(nn),B256,0,stream>>>(cnti, cntf, nn, 1);
    MS(SEG, (size_t)nn*64*4);
    int kc = kchunk_for(nn, 32);
    dim3 g(1, (nn+63)/64, 32);
    k_gemm<true,true,false><<<g,B256,0,stream>>>(Acur, nn, X, 64, SEG, 64, nn, 64, nn, kc, nullptr, 0, 0);
    k_gconv_fin<<<G1((size_t)nn*64),B256,0,stream>>>(SEG, cntf, Wrel + (size_t)layer*4096, brel + layer*64,
                                                    X, Wroot + (size_t)layer*4096, XN, nn);
    { float* t = X; X = XN; XN = t; }
  };

  // ---- dense ASAP pool ----
  auto asap_dense = [&](int kk, int p){
    k_diagfix<<<G1(nn),B256,0,stream>>>(Acur, nn);
    MS(cnti, nn*4);
    k_colcount_part<<<G1((size_t)nn*16),B256,0,stream>>>(Acur, nn, cnti);
    k_cnt_fin<<<G1(nn),B256,0,stream>>>(cnti, cntP, nn, 0);
    // xq = masked column-max of x, then @ pW + pb
    k_fill_mono<<<G1((size_t)nn*64),B256,0,stream>>>((unsigned*)Y, nn*64, -3.0e38f);
    {
      int kc = kchunk_for(nn, 32);
      dim3 g(1, (nn+63)/64, 32);
      k_gemm<true,true,true><<<g,B256,0,stream>>>(Acur, nn, X, 64, Y, 64, nn, 64, nn, kc, nullptr, 0, 0);
    }
    k_mono_fin<<<G1((size_t)nn*64),B256,0,stream>>>(Y, (unsigned*)Y, nn*64);
    k_mm_small<<<G1((size_t)nn*64),B256,0,stream>>>(Y, pW + (size_t)p*4096, pb + p*64, XQ2, nn, 64, 64, 0);
    // Sc = mask ? lrelu(x @ xq^T) : NEG   -- bf16x3 MFMA, K=64 -> K3=192
    k_split3<<<G1((size_t)nn*64),B256,0,stream>>>(X,   nn, 64, 64, Abf, 64, 0);
    k_split3<<<G1((size_t)nn*64),B256,0,stream>>>(XQ2, nn, 64, 64, Bbf, 64, 1);
    {
      dim3 g((nn+63)/64, (nn+63)/64);
      k_gemm_mfma<1><<<g,B256,0,stream>>>(Abf, Bbf, SCb, nn, nn, nn, 192, Acur, nn);
    }
    // column softmax (masked)
    k_fill_mono<<<G1(nn),B256,0,stream>>>(mmono, nn, -3.0e38f);
    k_colmax_part<<<G1((size_t)nn*16),B256,0,stream>>>(SCb, nn, mmono);
    k_mono_fin<<<G1(nn),B256,0,stream>>>(mcol, mmono, nn);
    MS(denom, nn*4);
    k_exp_colsum<<<G1((size_t)nn*16),B256,0,stream>>>(SCb, Acur, mcol, denom, nn);
    k_scale_cols<<<G1((size_t)nn*nn),B256,0,stream>>>(SCb, denom, nn);
    // xc = score^T @ x
    MS(XC, (size_t)nn*64*4);
    {
      int kc = kchunk_for(nn, 32);
      dim3 g(1, (nn+63)/64, 32);
      k_gemm<true,true,false><<<g,B256,0,stream>>>(SCb, nn, X, 64, XC, 64, nn, 64, nn, kc, nullptr, 0, 0);
    }
    k_abc<<<G1(nn),B256,0,stream>>>(XC, leW1 + p*64, leb1 + p, leW2 + p*64, leW3 + p*64, leb3 + p, aN, bN, cN, nn);
    MS(agg1, nn*4);
    k_aggcol_part<<<G1((size_t)nn*16),B256,0,stream>>>(Acur, aN, agg1, nn);
    k_fit_dense<<<G1(nn),B256,0,stream>>>(agg1, cntP, bN, cN, fit, nn);
    k_rank<<<G1(nn),B256,0,stream>>>(fit, nn, kk, sel);
    k_compact<<<G1(nn),B256,0,stream>>>(sel, nn, perm);
    k_xnew<<<G1((size_t)kk*64),B256,0,stream>>>(XC, fit, perm, XN, kk);
    k_gather_cols<<<G1((size_t)nn*kk),B256,0,stream>>>(SCb, nn, perm, SPD, kk, nn);
    // A_new = Sp^T @ (A' @ Sp) via bf16x3 MFMA
    const int Kp = (nn + 31) & ~31;
    const int K3 = 3*Kp;
    // TB = Acur(nn x nn) @ SPD(nn x kk)
    k_split3<<<G1((size_t)nn*Kp),B256,0,stream>>>(Acur, nn, nn, nn, Abf, Kp, 0);
    { dim3 gt((kk+31)/32, (nn+31)/32);
      k_split3_T<<<gt,B256,0,stream>>>(SPD, nn, kk, kk, Bbf, Kp, 1); }
    { dim3 g((kk+63)/64, (nn+63)/64);
      k_gemm_mfma<0><<<g,B256,0,stream>>>(Abf, Bbf, TB, kk, nn, kk, K3, nullptr, 0); }
    // Aoth = SPD^T(kk x nn) @ TB(nn x kk), diag zeroed
    { dim3 gt((kk+31)/32, (nn+31)/32);
      k_split3_T<<<gt,B256,0,stream>>>(SPD, nn, kk, kk, Abf, Kp, 0); }
    { dim3 gt((kk+31)/32, (nn+31)/32);
      k_split3_T<<<gt,B256,0,stream>>>(TB, nn, kk, kk, Bbf, Kp, 1); }
    { dim3 g((kk+63)/64, (kk+63)/64);
      k_gemm_mfma<2><<<g,B256,0,stream>>>(Abf, Bbf, Aoth, kk, kk, kk, K3, nullptr, 0); }
    { float* t = X; X = XN; XN = t; }
    { float* t = Acur; Acur = Aoth; Aoth = t; }
    nn = kk;
  };

  // i=1
  gconv_dense(1); k_mean<<<1,B256,0,stream>>>(X, nn, xs + 2*64);
  // i=2 + pool 1
  gconv_dense(2); k_mean<<<1,B256,0,stream>>>(X, nn, xs + 3*64);
  asap_dense(1215, 1);
  // i=3
  gconv_dense(3); k_mean<<<1,B256,0,stream>>>(X, nn, xs + 4*64);
  // i=4 + pool 2
  gconv_dense(4); k_mean<<<1,B256,0,stream>>>(X, nn, xs + 5*64);
  asap_dense(1094, 2);
  // i=5
  gconv_dense(5); k_mean<<<1,B256,0,stream>>>(X, nn, xs + 6*64);
  // i=6 + pool 3
  gconv_dense(6); k_mean<<<1,B256,0,stream>>>(X, nn, xs + 7*64);
  asap_dense(985, 3);
  // i=7
  gconv_dense(7); k_mean<<<1,B256,0,stream>>>(X, nn, xs + 8*64);
  // i=8
  gconv_dense(8); k_mean<<<1,B256,0,stream>>>(X, nn, xs + 9*64);

  // ---- head ----
  k_mm_small<<<G1(64),B256,0,stream>>>(xs, linW1, linb1, Y, 1, 640, 64, 1);
  k_head<<<1,64,0,stream>>>(Y, linW2, linb2, out);
}

// Round 3
// 3431.770 us; speedup vs baseline: 1.2029x; 1.0090x over previous
//
#include <hip/hip_runtime.h>
#include <math.h>

#define NEGV -1000000000.0f

typedef short short8 __attribute__((ext_vector_type(8)));
typedef float floatx4 __attribute__((ext_vector_type(4)));

__device__ __forceinline__ unsigned f2mono(float f){
  unsigned u = __float_as_uint(f);
  return (u & 0x80000000u) ? ~u : (u | 0x80000000u);
}
__device__ __forceinline__ float mono2f(unsigned u){
  return __uint_as_float((u & 0x80000000u) ? (u & 0x7fffffffu) : ~u);
}
__device__ __forceinline__ float sigm(float x){ return 1.0f/(1.0f+expf(-x)); }
__device__ __forceinline__ void edge_sd(int e,const int* src,const int* dst,int E,int& s,int& d){
  if(e<E){ s=src[e]; d=dst[e]; } else { s=e-E; d=s; }
}
__device__ __forceinline__ ushort bf16rn(float x){
  unsigned u = __float_as_uint(x);
  unsigned r = (u + 0x7fffu + ((u>>16)&1u)) >> 16;
  return (ushort)r;
}
__device__ __forceinline__ float bf16f(ushort h){ return __uint_as_float(((unsigned)h)<<16); }

// zero-fill on the compute queue (avoid SDMA memset nodes in the graph)
__global__ void k_zero(float* __restrict__ p, size_t n){
  size_t i = (size_t)blockIdx.x*256 + threadIdx.x;
  if (i < n) p[i] = 0.0f;
}

// ---------------- bf16x3 split conversions ----------------
// dst is R x 3*Cp bf16, K-innermost. bmode 0 (A role): [h,h,l]; bmode 1 (B role): [h,l,h].
__global__ void k_split3(const float* __restrict__ src,int R,int Cs,int ld,
                         ushort* __restrict__ dst,int Cp,int bmode){
  int idx = blockIdx.x*256+threadIdx.x;
  if (idx >= R*Cp) return;
  int r = idx / Cp, c = idx - r*Cp;
  float x = (c < Cs) ? src[(size_t)r*ld + c] : 0.0f;
  ushort h = bf16rn(x);
  ushort l = bf16rn(x - bf16f(h));
  size_t base = (size_t)r*(3*Cp) + c;
  dst[base]        = h;
  dst[base + Cp]   = bmode ? l : h;
  dst[base + 2*Cp] = bmode ? h : l;
}
// transpose variant: src stored Rs(K) x Cs(X) (ld), dst is Cs x 3*Kp bf16.
__global__ void k_split3_T(const float* __restrict__ src,int Rs,int Cs,int ld,
                           ushort* __restrict__ dst,int Kp,int bmode){
  __shared__ float t[32][33];
  int tx = threadIdx.x & 31, ty = threadIdx.x >> 5;
  int kb = blockIdx.y*32, xb = blockIdx.x*32;
#pragma unroll
  for (int i=0;i<4;i++){
    int k = kb + ty + i*8, x = xb + tx;
    t[ty+i*8][tx] = (k < Rs && x < Cs) ? src[(size_t)k*ld + x] : 0.0f;
  }
  __syncthreads();
  const int K3 = 3*Kp;
#pragma unroll
  for (int i=0;i<4;i++){
    int xo = xb + ty + i*8, ko = kb + tx;
    if (xo < Cs){
      float v = t[tx][ty+i*8];
      ushort h = bf16rn(v);
      ushort l = bf16rn(v - bf16f(h));
      size_t base = (size_t)xo*K3 + ko;
      dst[base]        = h;
      dst[base + Kp]   = bmode ? l : h;
      dst[base + 2*Kp] = bmode ? h : l;
    }
  }
}

// ---------------- MFMA bf16 GEMM (64x64 tile, 4 waves, 16x16x32) ----------------
template<int EPI>
__global__ __launch_bounds__(256) void k_gemm_mfma(
    const ushort* __restrict__ A, const ushort* __restrict__ B,
    float* __restrict__ C, int ldc, int M, int N, int K3,
    const float* __restrict__ mask, int ldm)
{
  __shared__ ushort As[64][40];
  __shared__ ushort Bs[64][40];
  const int tid = threadIdx.x;
  const int m0 = blockIdx.y*64, n0 = blockIdx.x*64;
  const int w = tid>>6, lane = tid&63;
  const int lo4 = lane&15, quad = lane>>4;
  const int sr = tid>>2, sseg = tid&3;

  floatx4 acc[4];
#pragma unroll
  for(int c=0;c<4;c++){ acc[c][0]=0.f; acc[c][1]=0.f; acc[c][2]=0.f; acc[c][3]=0.f; }

  const size_t arow = (size_t)(m0+sr)*K3;
  const size_t brow = (size_t)(n0+sr)*K3;
  const bool aval = (m0+sr) < M;
  const bool bval = (n0+sr) < N;

  for (int k0 = 0; k0 < K3; k0 += 32) {
    uint4 av = make_uint4(0,0,0,0), bv = make_uint4(0,0,0,0);
    if (aval) av = *(const uint4*)(A + arow + k0 + sseg*8);
    if (bval) bv = *(const uint4*)(B + brow + k0 + sseg*8);
    __syncthreads();
    *(uint4*)&As[sr][sseg*8] = av;
    *(uint4*)&Bs[sr][sseg*8] = bv;
    __syncthreads();
    short8 af = *(const short8*)&As[16*w + lo4][quad*8];
#pragma unroll
    for (int c=0;c<4;c++){
      short8 bf = *(const short8*)&Bs[16*c + lo4][quad*8];
      acc[c] = __builtin_amdgcn_mfma_f32_16x16x32_bf16(af, bf, acc[c], 0, 0, 0);
    }
  }

#pragma unroll
  for (int c=0;c<4;c++){
    const int gn = n0 + 16*c + lo4;
#pragma unroll
    for (int r=0;r<4;r++){
      const int gm = m0 + 16*w + quad*4 + r;
      if (gm < M && gn < N){
        float v = acc[c][r];
        if (EPI==1) v = (mask[(size_t)gm*ldm+gn] != 0.0f) ? (v > 0.0f ? v : 0.2f*v) : NEGV;
        if (EPI==2 && gm==gn) v = 0.0f;
        C[(size_t)gm*ldc+gn] = v;
      }
    }
  }
}

// ---------------- generic tiled fp32 GEMM (kept for skinny / masked-max) ----------------
template<bool ADIR, bool BDIR, bool MAXM>
__global__ __launch_bounds__(256) void k_gemm(
    const float* __restrict__ A, int lda,
    const float* __restrict__ B, int ldb,
    float* __restrict__ C, int ldc,
    int M, int N, int K, int kchunk,
    const float* __restrict__ mask, int ldm, int epi)
{
  __shared__ float Asm[16][68];
  __shared__ float Bsm[16][68];
  const int tid = threadIdx.x;
  const int m0 = blockIdx.y * 64, n0 = blockIdx.x * 64;
  const int tmb = (tid & 15) * 4, tnb = (tid >> 4) * 4;
  float acc[4][4];
#pragma unroll
  for (int i=0;i<4;i++)
#pragma unroll
    for (int j=0;j<4;j++) acc[i][j] = MAXM ? NEGV : 0.0f;

  int kstart = 0, kend = K;
  if (kchunk > 0) { kstart = blockIdx.z * kchunk; kend = kstart + kchunk; if (kend > K) kend = K; }

  for (int k0 = kstart; k0 < kend; k0 += 16) {
    if (ADIR) {
      const int m = m0 + (tid & 63);
      const int tb = tid >> 6;
#pragma unroll
      for (int s=0;s<4;s++) {
        const int tk = tb + s*4;
        float v = 0.0f;
        if (m < M && (k0+tk) < K) v = A[(size_t)(k0+tk)*lda + m];
        Asm[tk][tid & 63] = v;
      }
    } else {
      const int tm = tid >> 2, tb = (tid & 3) * 4;
#pragma unroll
      for (int s=0;s<4;s++) {
        const int tk = tb + s;
        float v = 0.0f;
        if ((m0+tm) < M && (k0+tk) < K) v = A[(size_t)(m0+tm)*lda + (k0+tk)];
        Asm[tk][tm] = v;
      }
    }
    if (BDIR) {
      const int nn = n0 + (tid & 63);
      const int tb = tid >> 6;
#pragma unroll
      for (int s=0;s<4;s++) {
        const int tk = tb + s*4;
        float v = 0.0f;
        if (nn < N && (k0+tk) < K) v = B[(size_t)(k0+tk)*ldb + nn];
        Bsm[tk][tid & 63] = v;
      }
    } else {
      const int tn = tid >> 2, tb = (tid & 3) * 4;
#pragma unroll
      for (int s=0;s<4;s++) {
        const int tk = tb + s;
        float v = 0.0f;
        if ((n0+tn) < N && (k0+tk) < K) v = B[(size_t)(n0+tn)*ldb + (k0+tk)];
        Bsm[tk][tn] = v;
      }
    }
    __syncthreads();
#pragma unroll
    for (int kk=0; kk<16; kk++) {
      const float4 a4 = *(const float4*)&Asm[kk][tmb];
      const float4 b4 = *(const float4*)&Bsm[kk][tnb];
      const float av[4] = {a4.x,a4.y,a4.z,a4.w};
      const float bv[4] = {b4.x,b4.y,b4.z,b4.w};
#pragma unroll
      for (int i=0;i<4;i++)
#pragma unroll
        for (int j=0;j<4;j++) {
          if (MAXM) acc[i][j] = fmaxf(acc[i][j], av[i] != 0.0f ? bv[j] : NEGV);
          else      acc[i][j] = fmaf(av[i], bv[j], acc[i][j]);
        }
    }
    __syncthreads();
  }

  const bool split = (gridDim.z > 1);
#pragma unroll
  for (int i=0;i<4;i++)
#pragma unroll
    for (int j=0;j<4;j++) {
      const int m = m0 + tmb + i, nn = n0 + tnb + j;
      if (m < M && nn < N) {
        float v = acc[i][j];
        if (split) {
          if (MAXM) atomicMax((unsigned*)&C[(size_t)m*ldc + nn], f2mono(v));
          else atomicAdd(&C[(size_t)m*ldc + nn], v);
        } else {
          if (epi == 1) { v = (mask[(size_t)m*ldm + nn] != 0.0f) ? (v > 0.0f ? v : 0.2f*v) : NEGV; }
          else if (epi == 2) { if (m == nn) v = 0.0f; }
          C[(size_t)m*ldc + nn] = v;
        }
      }
    }
}

// ---------------- small kernels ----------------
__global__ void k_deg(const int* __restrict__ src,const int* __restrict__ dst,int* indeg,int* outdeg,int E){
  int e = blockIdx.x*256+threadIdx.x; if(e>=E) return;
  atomicAdd(&indeg[dst[e]],1); atomicAdd(&outdeg[src[e]],1);
}

__global__ void k_mm_small(const float* __restrict__ A,const float* __restrict__ W,
                           const float* __restrict__ b,float* __restrict__ C,
                           int M,int K,int Np,int act){
  int idx = blockIdx.x*256+threadIdx.x; if(idx>=M*Np) return;
  int m = idx/Np, j = idx - m*Np;
  float s = b ? b[j] : 0.0f;
  const float* a = A + (size_t)m*K;
  for(int q=0;q<K;q++) s = fmaf(a[q], W[(size_t)q*Np + j], s);
  if(act==1) s = fmaxf(s, 0.0f);
  C[idx] = s;
}

__global__ void k_copy_int(int* d,const int* s,int n){ int i=blockIdx.x*256+threadIdx.x; if(i<n) d[i]=s[i]; }

__global__ void k_scatter_add(const int* __restrict__ src,const int* __restrict__ dst,
                              const float* __restrict__ Y,float* SEG,int E,int H){
  int idx = blockIdx.x*256+threadIdx.x; if(idx>=E*H) return;
  int e = idx/H, h = idx - e*H;
  atomicAdd(&SEG[(size_t)dst[e]*H + h], Y[(size_t)src[e]*H + h]);
}

// v = (SEG[i,h] + Y[i,h]) / (indeg+1) + b[h]; elu   (self-loop folded in here)
__global__ void k_feast_fin(const float* __restrict__ SEG,const float* __restrict__ Y,
                            const int* __restrict__ indeg,
                            const float* __restrict__ b,float* X,int n,int H){
  int idx = blockIdx.x*256+threadIdx.x; if(idx>=n*H) return;
  int i = idx/H, h = idx - i*H;
  float v = (SEG[idx] + Y[idx])/(float)(indeg[i]+1) + b[h];
  X[idx] = v > 0.0f ? v : (expf(v)-1.0f);
}

__global__ void k_cnt_sparse(const int* indeg,float* cntf,int n){
  int i = blockIdx.x*256+threadIdx.x; if(i>=n) return;
  cntf[i] = (float)(indeg[i] > 1 ? indeg[i] : 1);
}

__global__ void k_gconv_fin(const float* __restrict__ AGG,const float* __restrict__ cnt,
                            const float* __restrict__ Wrel,const float* __restrict__ brel,
                            const float* __restrict__ X,const float* __restrict__ Wroot,
                            float* XN,int n){
  int idx = blockIdx.x*256+threadIdx.x; if(idx>=n*64) return;
  int i = idx >> 6, j = idx & 63;
  const float* ag = AGG + (size_t)i*64;
  const float* xr = X + (size_t)i*64;
  float a = 0.0f, r = 0.0f;
  for(int q=0;q<64;q++){ a = fmaf(ag[q], Wrel[q*64+j], a); r = fmaf(xr[q], Wroot[q*64+j], r); }
  float v = a/cnt[i] + brel[j] + r;
  XN[idx] = fmaxf(v, 0.0f);
}

__global__ void k_mean(const float* __restrict__ X,int n,float* o){
  __shared__ float sh[256];
  int t = threadIdx.x; int h = t & 63, p = t >> 6;
  float s = 0.0f;
  for(int i=p;i<n;i+=4) s += X[(size_t)i*64 + h];
  sh[t] = s; __syncthreads();
  if(t < 64) o[t] = (sh[t]+sh[t+64]+sh[t+128]+sh[t+192])/(float)n;
}

__global__ void k_mono_init_from(unsigned* M,const float* X,int n){
  int i = blockIdx.x*256+threadIdx.x; if(i<n) M[i] = f2mono(X[i]);
}
__global__ void k_fill_mono(unsigned* M,int n,float v){
  int i = blockIdx.x*256+threadIdx.x; if(i<n) M[i] = f2mono(v);
}
__global__ void k_mono_fin(float* out,const unsigned* M,int n){
  int i = blockIdx.x*256+threadIdx.x; if(i<n){ unsigned u = M[i]; out[i] = mono2f(u); }
}
__global__ void k_scatter_max(const int* __restrict__ src,const int* __restrict__ dst,
                              const float* __restrict__ X,unsigned* M,int E,int H){
  int idx = blockIdx.x*256+threadIdx.x; if(idx>=E*H) return;
  int e = idx/H, h = idx - e*H;
  atomicMax(&M[(size_t)dst[e]*H + h], f2mono(X[(size_t)src[e]*H + h]));
}

__global__ void k_edge_score(const int* __restrict__ src,const int* __restrict__ dst,
                             const float* __restrict__ XQ2,const float* __restrict__ X,
                             float* sE,int E,int n){
  int e = blockIdx.x*256+threadIdx.x; if(e>=E+n) return;
  int s,d; edge_sd(e,src,dst,E,s,d);
  const float* q = XQ2 + (size_t)d*64;
  const float* x = X + (size_t)s*64;
  float acc = 0.0f;
  for(int h=0;h<64;h++) acc = fmaf(q[h], x[h], acc);
  sE[e] = acc > 0.0f ? acc : 0.2f*acc;
}
__global__ void k_segmax_edge(const int* src,const int* dst,const float* sE,unsigned* M,int E,int n){
  int e = blockIdx.x*256+threadIdx.x; if(e>=E+n) return;
  int s,d; edge_sd(e,src,dst,E,s,d);
  atomicMax(&M[d], f2mono(sE[e]));
}
__global__ void k_exp_edge(const int* src,const int* dst,const float* sE,const float* m,
                           float* eE,float* denom,int E,int n){
  int e = blockIdx.x*256+threadIdx.x; if(e>=E+n) return;
  int s,d; edge_sd(e,src,dst,E,s,d);
  float v = expf(sE[e]-m[d]); eE[e]=v; atomicAdd(&denom[d],v);
}
__global__ void k_score_edge(const int* src,const int* dst,const float* eE,const float* denom,
                             float* scE,int E,int n){
  int e = blockIdx.x*256+threadIdx.x; if(e>=E+n) return;
  int s,d; edge_sd(e,src,dst,E,s,d);
  scE[e] = eE[e]/denom[d];
}
__global__ void k_xc_scatter(const int* __restrict__ src,const int* __restrict__ dst,
                             const float* __restrict__ scE,const float* __restrict__ X,
                             float* XC,int E,int n){
  int idx = blockIdx.x*256+threadIdx.x; if(idx>=(E+n)*64) return;
  int e = idx >> 6, h = idx & 63;
  int s,d; edge_sd(e,src,dst,E,s,d);
  atomicAdd(&XC[(size_t)d*64 + h], scE[e]*X[(size_t)s*64 + h]);
}
__global__ void k_abc(const float* __restrict__ XC,const float* __restrict__ w1,const float* bb1,
                      const float* __restrict__ w2,const float* __restrict__ w3,const float* bb3,
                      float* aN,float* bN,float* cN,int n){
  int v = blockIdx.x*256+threadIdx.x; if(v>=n) return;
  const float* xc = XC + (size_t)v*64;
  float a = bb1[0], b = 0.0f, c = bb3[0];
  for(int h=0;h<64;h++){ a=fmaf(xc[h],w1[h],a); b=fmaf(xc[h],w2[h],b); c=fmaf(xc[h],w3[h],c); }
  aN[v]=a; bN[v]=b; cN[v]=c;
}
__global__ void k_agg_edge(const int* src,const int* dst,const float* aN,float* agg,int E,int n){
  int e = blockIdx.x*256+threadIdx.x; if(e>=E+n) return;
  int s,d; edge_sd(e,src,dst,E,s,d);
  atomicAdd(&agg[d], aN[s]);
}
__global__ void k_fit_sparse(const float* agg,const int* indeg,const float* bN,const float* cN,
                             float* fit,int n){
  int v = blockIdx.x*256+threadIdx.x; if(v>=n) return;
  fit[v] = sigm(agg[v] - (float)(indeg[v]+1)*bN[v] + cN[v]);
}
__global__ void k_fit_dense(const float* agg,const float* cntP,const float* bN,const float* cN,
                            float* fit,int n){
  int v = blockIdx.x*256+threadIdx.x; if(v>=n) return;
  fit[v] = sigm(agg[v] - cntP[v]*bN[v] + cN[v]);
}

__global__ void k_rank(const float* __restrict__ fit,int n,int k,int* sel){
  int v = blockIdx.x*256+threadIdx.x; if(v>=n) return;
  float fv = fit[v]; int r = 0;
  for(int u=0;u<n;u++){ float fu = fit[u]; if(fu > fv || (fu == fv && u < v)) r++; }
  sel[v] = (r < k) ? 1 : 0;
}
__global__ void k_compact(const int* __restrict__ sel,int n,int* perm){
  int v = blockIdx.x*256+threadIdx.x; if(v>=n || !sel[v]) return;
  int p = 0;
  for(int u=0;u<v;u++) p += sel[u];
  perm[p] = v;
}
__global__ void k_xnew(const float* __restrict__ XC,const float* __restrict__ fit,
                       const int* __restrict__ perm,float* XN,int k){
  int idx = blockIdx.x*256+threadIdx.x; if(idx>=k*64) return;
  int u = idx >> 6, h = idx & 63; int v = perm[u];
  XN[idx] = XC[(size_t)v*64 + h]*fit[v];
}

__global__ void k_prefix(const int* __restrict__ deg,int* off,int n){
  int t = blockIdx.x*256+threadIdx.x; if(t>n) return;
  int s = 0;
  for(int u=0;u<t;u++) s += deg[u]+1;
  off[t] = s;
}
__global__ void k_csr_fill(const int* src,const int* dst,const float* scE,
                           int* curS,int* colS,float* valS,
                           int* curD,int* rowD,float* valD,int E,int n){
  int e = blockIdx.x*256+threadIdx.x; if(e>=E+n) return;
  int s,d; edge_sd(e,src,dst,E,s,d);
  float sc = scE[e];
  int p = atomicAdd(&curS[s],1); colS[p]=d; valS[p]=sc;
  int q = atomicAdd(&curD[d],1); rowD[q]=s; valD[q]=sc;
}
__global__ void k_stage1(const int* src,const int* dst,const int* __restrict__ offS,
                         const int* __restrict__ colS,const float* __restrict__ valS,
                         float* R,int E,int n){
  int e = blockIdx.x*256+threadIdx.x; if(e>=E+n) return;
  int i,j; edge_sd(e,src,dst,E,i,j);
  int p0 = offS[j], p1 = offS[j+1];
  float* Ri = R + (size_t)i*n;
  for(int p=p0;p<p1;p++) atomicAdd(&Ri[colS[p]], valS[p]);
}
__global__ void k_gather_cols(const float* __restrict__ S,int ldS,const int* __restrict__ perm,
                              float* out,int k,int rows){
  int idx = blockIdx.x*256+threadIdx.x; if(idx>=rows*k) return;
  int i = idx/k, u = idx - i*k;
  out[idx] = S[(size_t)i*ldS + perm[u]];
}
__global__ void k_stage2(const int* __restrict__ perm,const int* __restrict__ offD,
                         const int* __restrict__ rowD,const float* __restrict__ valD,
                         const float* __restrict__ Rp,float* A,int k){
  int idx = blockIdx.x*256+threadIdx.x; if(idx>=k*k) return;
  int u = idx/k, v = idx - u*k; int d = perm[u];
  float acc = 0.0f;
  int p0 = offD[d], p1 = offD[d+1];
  for(int p=p0;p<p1;p++) acc = fmaf(valD[p], Rp[(size_t)rowD[p]*k + v], acc);
  A[idx] = (u==v) ? 0.0f : acc;
}

__global__ void k_diagfix(float* A,int n){
  int i = blockIdx.x*256+threadIdx.x; if(i>=n) return;
  size_t d = (size_t)i*n + i;
  if(A[d]==0.0f) A[d]=1.0f;
}
__global__ void k_colcount_part(const float* __restrict__ A,int n,int* cnt){
  int idx = blockIdx.x*256+threadIdx.x; if(idx>=n*16) return;
  int j = idx % n, c = idx / n;
  int i0 = (int)(((long long)n*c)/16), i1 = (int)(((long long)n*(c+1))/16);
  int s = 0;
  for(int i=i0;i<i1;i++) s += (A[(size_t)i*n + j] != 0.0f) ? 1 : 0;
  if(s) atomicAdd(&cnt[j], s);
}
__global__ void k_cnt_fin(const int* cnt,float* out,int n,int clampMin){
  int j = blockIdx.x*256+threadIdx.x; if(j>=n) return;
  int c = cnt[j]; if(c < clampMin) c = clampMin;
  out[j] = (float)c;
}
__global__ void k_colmax_part(const float* __restrict__ S,int n,unsigned* M){
  int idx = blockIdx.x*256+threadIdx.x; if(idx>=n*16) return;
  int j = idx % n, c = idx / n;
  int i0 = (int)(((long long)n*c)/16), i1 = (int)(((long long)n*(c+1))/16);
  float lm = -3.0e38f;
  for(int i=i0;i<i1;i++) lm = fmaxf(lm, S[(size_t)i*n + j]);
  atomicMax(&M[j], f2mono(lm));
}
__global__ void k_exp_colsum(float* S,const float* __restrict__ A,const float* __restrict__ m,
                             float* denom,int n){
  int idx = blockIdx.x*256+threadIdx.x; if(idx>=n*16) return;
  int j = idx % n, c = idx / n;
  int i0 = (int)(((long long)n*c)/16), i1 = (int)(((long long)n*(c+1))/16);
  float mj = m[j], ls = 0.0f;
  for(int i=i0;i<i1;i++){
    size_t o = (size_t)i*n + j;
    float v = (A[o] != 0.0f) ? expf(S[o]-mj) : 0.0f;
    S[o] = v; ls += v;
  }
  if(ls != 0.0f) atomicAdd(&denom[j], ls);
}
__global__ void k_scale_cols(float* S,const float* __restrict__ denom,int n){
  int idx = blockIdx.x*256+threadIdx.x; if(idx>=n*n) return;
  int j = idx % n;
  S[idx] /= denom[j];
}
__global__ void k_aggcol_part(const float* __restrict__ A,const float* __restrict__ aN,
                              float* agg,int n){
  int idx = blockIdx.x*256+threadIdx.x; if(idx>=n*16) return;
  int j = idx % n, c = idx / n;
  int i0 = (int)(((long long)n*c)/16), i1 = (int)(((long long)n*(c+1))/16);
  float s = 0.0f;
  for(int i=i0;i<i1;i++) if(A[(size_t)i*n + j] != 0.0f) s += aN[i];
  if(s != 0.0f) atomicAdd(&agg[j], s);
}

__global__ void k_head(const float* __restrict__ h2,const float* __restrict__ W,
                       const float* __restrict__ b,float* out){
  __shared__ float lg[10];
  int t = threadIdx.x;
  if(t < 10){
    float s = b[t];
    for(int k=0;k<64;k++) s = fmaf(h2[k], W[k*10+t], s);
    lg[t] = s;
  }
  __syncthreads();
  if(t == 0){
    float mx = lg[0];
    for(int i=1;i<10;i++) mx = fmaxf(mx, lg[i]);
    float se = 0.0f;
    for(int i=0;i<10;i++) se += expf(lg[i]-mx);
    float lse = mx + logf(se);
    for(int i=0;i<10;i++) out[i] = lg[i]-lse;
  }
}

// ---------------- host orchestration ----------------
extern "C" void kernel_launch(void* const* d_in, const int* in_sizes, int n_in,
                              void* d_out, int out_size, void* d_ws, size_t ws_size,
                              hipStream_t stream) {
  const int N0 = 1500, E = 24000;
  const float* x0   = (const float*)d_in[0];
  const int* esrc   = (const int*)d_in[1];
  const int* edst   = (const int*)d_in[2];
  const float* W1   = (const float*)d_in[3];  const float* b1   = (const float*)d_in[4];
  const float* W2   = (const float*)d_in[5];  const float* b2   = (const float*)d_in[6];
  const float* W3   = (const float*)d_in[7];  const float* b3   = (const float*)d_in[8];
  const float* Wrel = (const float*)d_in[9];  const float* brel = (const float*)d_in[10];
  const float* Wroot= (const float*)d_in[11];
  const float* pW   = (const float*)d_in[12]; const float* pb   = (const float*)d_in[13];
  const float* leW1 = (const float*)d_in[14]; const float* leb1 = (const float*)d_in[15];
  const float* leW2 = (const float*)d_in[16]; const float* leW3 = (const float*)d_in[17];
  const float* leb3 = (const float*)d_in[18];
  const float* linW1= (const float*)d_in[19]; const float* linb1= (const float*)d_in[20];
  const float* linW2= (const float*)d_in[21]; const float* linb2= (const float*)d_in[22];
  float* out = (float*)d_out;

  float* ws = (float*)d_ws;
  size_t cur = 0;
  auto allocF = [&](size_t nf)->float*{ float* p = ws + cur; cur += (nf + 15) & ~(size_t)15; return p; };
  float* Xa  = allocF(96000); float* Xb  = allocF(96000); float* Y   = allocF(96000);
  float* XQ2 = allocF(96000); float* XC  = allocF(96000); float* SEG = allocF(96000);
  float* xs  = allocF(640);
  float* mcol = allocF(1500); float* denom = allocF(1500);
  float* aN = allocF(1500); float* bN = allocF(1500); float* cN = allocF(1500);
  float* fit = allocF(1500); float* agg1 = allocF(1500); float* cntf = allocF(1500); float* cntP = allocF(1500);
  int* indeg = (int*)allocF(1500); int* outdeg = (int*)allocF(1500); int* cnti = (int*)allocF(1500);
  int* sel = (int*)allocF(1500); int* perm = (int*)allocF(1500);
  int* offS = (int*)allocF(1504); int* offD = (int*)allocF(1504);
  int* curS = (int*)allocF(1504); int* curD = (int*)allocF(1504);
  int* colS = (int*)allocF(25504); int* rowD = (int*)allocF(25504);
  unsigned* mmono = (unsigned*)allocF(1504);
  float* valS = allocF(25504); float* valD = allocF(25504);
  float* sE = allocF(25504); float* eE = allocF(25504); float* scE = allocF(25504);
  float* R   = allocF((size_t)1500*1500);
  float* TB  = allocF((size_t)1500*1350);
  float* SPD = allocF((size_t)1350*1215 + 16);
  float* SCb = allocF((size_t)1350*1350);
  float* A0  = allocF((size_t)1350*1350);
  float* A1s = allocF((size_t)1350*1350);
  ushort* Abf = (ushort*)allocF((size_t)1350*4128/2 + 32);
  ushort* Bbf = (ushort*)allocF((size_t)1350*4128/2 + 32);

  dim3 B256(256);
  auto G1 = [&](size_t n){ return dim3((unsigned)((n + 255) / 256)); };
  // zero-fill via compute kernel — NO hipMemsetAsync in the graph (SDMA engine-switch stalls)
  auto ZF = [&](void* p, size_t nfloats){ k_zero<<<G1(nfloats),B256,0,stream>>>((float*)p, nfloats); };
  auto kchunk_for = [&](int K, int Z){ return (int)(((K + Z*16 - 1) / (Z*16)) * 16); };

  // degrees
  ZF(indeg, 1500); ZF(outdeg, 1500);
  k_deg<<<G1(E),B256,0,stream>>>(esrc, edst, indeg, outdeg, E);

  // ---- FEAST x3 ----
  auto feast = [&](const float* xin,int cin,const float* W,const float* bb,int hh,float* xout){
    ZF(SEG, (size_t)N0*hh);
    k_mm_small<<<G1((size_t)N0*hh),B256,0,stream>>>(xin, W, nullptr, Y, N0, cin, hh, 0);
    k_scatter_add<<<G1((size_t)E*hh),B256,0,stream>>>(esrc, edst, Y, SEG, E, hh);
    k_feast_fin<<<G1((size_t)N0*hh),B256,0,stream>>>(SEG, Y, indeg, bb, xout, N0, hh);
  };
  feast(x0, 16, W1, b1, 32, Xa);
  feast(Xa, 32, W2, b2, 64, Xb);
  feast(Xb, 64, W3, b3, 64, Xa);
  float* X = Xa; float* XN = Xb;
  k_mean<<<1,B256,0,stream>>>(X, N0, xs + 0);

  // ---- i=0 gconv_sparse ----
  ZF(SEG, (size_t)N0*64);
  k_scatter_add<<<G1((size_t)E*64),B256,0,stream>>>(esrc, edst, X, SEG, E, 64);
  k_cnt_sparse<<<G1(N0),B256,0,stream>>>(indeg, cntf, N0);
  k_gconv_fin<<<G1((size_t)N0*64),B256,0,stream>>>(SEG, cntf, Wrel, brel, X, Wroot, XN, N0);
  { float* t = X; X = XN; XN = t; }
  k_mean<<<1,B256,0,stream>>>(X, N0, xs + 64);

  // ---- pool 0 (sparse ASAP), n=1500 -> k=1350 ----
  {
    const int n = 1500, kk = 1350, L = E + n;
    unsigned* xqm = (unsigned*)Y;
    k_mono_init_from<<<G1((size_t)n*64),B256,0,stream>>>(xqm, X, n*64);
    k_scatter_max<<<G1((size_t)E*64),B256,0,stream>>>(esrc, edst, X, xqm, E, 64);
    k_mono_fin<<<G1((size_t)n*64),B256,0,stream>>>(Y, xqm, n*64);
    k_mm_small<<<G1((size_t)n*64),B256,0,stream>>>(Y, pW, pb, XQ2, n, 64, 64, 0);
    k_edge_score<<<G1(L),B256,0,stream>>>(esrc, edst, XQ2, X, sE, E, n);
    k_fill_mono<<<G1(n),B256,0,stream>>>(mmono, n, -3.0e38f);
    k_segmax_edge<<<G1(L),B256,0,stream>>>(esrc, edst, sE, mmono, E, n);
    k_mono_fin<<<G1(n),B256,0,stream>>>(mcol, mmono, n);
    ZF(denom, n);
    k_exp_edge<<<G1(L),B256,0,stream>>>(esrc, edst, sE, mcol, eE, denom, E, n);
    k_score_edge<<<G1(L),B256,0,stream>>>(esrc, edst, eE, denom, scE, E, n);
    ZF(XC, (size_t)n*64);
    k_xc_scatter<<<G1((size_t)L*64),B256,0,stream>>>(esrc, edst, scE, X, XC, E, n);
    k_abc<<<G1(n),B256,0,stream>>>(XC, leW1, leb1, leW2, leW3, leb3, aN, bN, cN, n);
    ZF(agg1, n);
    k_agg_edge<<<G1(L),B256,0,stream>>>(esrc, edst, aN, agg1, E, n);
    k_fit_sparse<<<G1(n),B256,0,stream>>>(agg1, indeg, bN, cN, fit, n);
    k_rank<<<G1(n),B256,0,stream>>>(fit, n, kk, sel);
    k_compact<<<G1(n),B256,0,stream>>>(sel, n, perm);
    k_xnew<<<G1((size_t)kk*64),B256,0,stream>>>(XC, fit, perm, XN, kk);
    // sparse A_new = Sp^T A Sp
    k_prefix<<<G1(n+1),B256,0,stream>>>(outdeg, offS, n);
    k_prefix<<<G1(n+1),B256,0,stream>>>(indeg, offD, n);
    k_copy_int<<<G1(n),B256,0,stream>>>(curS, offS, n);
    k_copy_int<<<G1(n),B256,0,stream>>>(curD, offD, n);
    k_csr_fill<<<G1(L),B256,0,stream>>>(esrc, edst, scE, curS, colS, valS, curD, rowD, valD, E, n);
    ZF(R, (size_t)n*n);
    k_stage1<<<G1(L),B256,0,stream>>>(esrc, edst, offS, colS, valS, R, E, n);
    k_gather_cols<<<G1((size_t)n*kk),B256,0,stream>>>(R, n, perm, TB, kk, n);
    k_stage2<<<G1((size_t)kk*kk),B256,0,stream>>>(perm, offD, rowD, valD, TB, A0, kk);
    { float* t = X; X = XN; XN = t; }
  }

  float* Acur = A0; float* Aoth = A1s;
  int nn = 1350;

  // ---- dense gconv ----
  auto gconv_dense = [&](int layer){
    ZF(cnti, nn);
    k_colcount_part<<<G1((size_t)nn*16),B256,0,stream>>>(Acur, nn, cnti);
    k_cnt_fin<<<G1(nn),B256,0,stream>>>(cnti, cntf, nn, 1);
    ZF(SEG, (size_t)nn*64);
    int kc = kchunk_for(nn, 32);
    dim3 g(1, (nn+63)/64, 32);
    k_gemm<true,true,false><<<g,B256,0,stream>>>(Acur, nn, X, 64, SEG, 64, nn, 64, nn, kc, nullptr, 0, 0);
    k_gconv_fin<<<G1((size_t)nn*64),B256,0,stream>>>(SEG, cntf, Wrel + (size_t)layer*4096, brel + layer*64,
                                                    X, Wroot + (size_t)layer*4096, XN, nn);
    { float* t = X; X = XN; XN = t; }
  };

  // ---- dense ASAP pool ----
  auto asap_dense = [&](int kk, int p){
    k_diagfix<<<G1(nn),B256,0,stream>>>(Acur, nn);
    ZF(cnti, nn);
    k_colcount_part<<<G1((size_t)nn*16),B256,0,stream>>>(Acur, nn, cnti);
    k_cnt_fin<<<G1(nn),B256,0,stream>>>(cnti, cntP, nn, 0);
    // xq = masked column-max of x, then @ pW + pb
    k_fill_mono<<<G1((size_t)nn*64),B256,0,stream>>>((unsigned*)Y, nn*64, -3.0e38f);
    {
      int kc = kchunk_for(nn, 32);
      dim3 g(1, (nn+63)/64, 32);
      k_gemm<true,true,true><<<g,B256,0,stream>>>(Acur, nn, X, 64, Y, 64, nn, 64, nn, kc, nullptr, 0, 0);
    }
    k_mono_fin<<<G1((size_t)nn*64),B256,0,stream>>>(Y, (unsigned*)Y, nn*64);
    k_mm_small<<<G1((size_t)nn*64),B256,0,stream>>>(Y, pW + (size_t)p*4096, pb + p*64, XQ2, nn, 64, 64, 0);
    // Sc = mask ? lrelu(x @ xq^T) : NEG   -- bf16x3 MFMA, K=64 -> K3=192
    k_split3<<<G1((size_t)nn*64),B256,0,stream>>>(X,   nn, 64, 64, Abf, 64, 0);
    k_split3<<<G1((size_t)nn*64),B256,0,stream>>>(XQ2, nn, 64, 64, Bbf, 64, 1);
    {
      dim3 g((nn+63)/64, (nn+63)/64);
      k_gemm_mfma<1><<<g,B256,0,stream>>>(Abf, Bbf, SCb, nn, nn, nn, 192, Acur, nn);
    }
    // column softmax (masked)
    k_fill_mono<<<G1(nn),B256,0,stream>>>(mmono, nn, -3.0e38f);
    k_colmax_part<<<G1((size_t)nn*16),B256,0,stream>>>(SCb, nn, mmono);
    k_mono_fin<<<G1(nn),B256,0,stream>>>(mcol, mmono, nn);
    ZF(denom, nn);
    k_exp_colsum<<<G1((size_t)nn*16),B256,0,stream>>>(SCb, Acur, mcol, denom, nn);
    k_scale_cols<<<G1((size_t)nn*nn),B256,0,stream>>>(SCb, denom, nn);
    // xc = score^T @ x
    ZF(XC, (size_t)nn*64);
    {
      int kc = kchunk_for(nn, 32);
      dim3 g(1, (nn+63)/64, 32);
      k_gemm<true,true,false><<<g,B256,0,stream>>>(SCb, nn, X, 64, XC, 64, nn, 64, nn, kc, nullptr, 0, 0);
    }
    k_abc<<<G1(nn),B256,0,stream>>>(XC, leW1 + p*64, leb1 + p, leW2 + p*64, leW3 + p*64, leb3 + p, aN, bN, cN, nn);
    ZF(agg1, nn);
    k_aggcol_part<<<G1((size_t)nn*16),B256,0,stream>>>(Acur, aN, agg1, nn);
    k_fit_dense<<<G1(nn),B256,0,stream>>>(agg1, cntP, bN, cN, fit, nn);
    k_rank<<<G1(nn),B256,0,stream>>>(fit, nn, kk, sel);
    k_compact<<<G1(nn),B256,0,stream>>>(sel, nn, perm);
    k_xnew<<<G1((size_t)kk*64),B256,0,stream>>>(XC, fit, perm, XN, kk);
    k_gather_cols<<<G1((size_t)nn*kk),B256,0,stream>>>(SCb, nn, perm, SPD, kk, nn);
    // A_new = Sp^T @ (A' @ Sp) via bf16x3 MFMA
    const int Kp = (nn + 31) & ~31;
    const int K3 = 3*Kp;
    k_split3<<<G1((size_t)nn*Kp),B256,0,stream>>>(Acur, nn, nn, nn, Abf, Kp, 0);
    { dim3 gt((kk+31)/32, (nn+31)/32);
      k_split3_T<<<gt,B256,0,stream>>>(SPD, nn, kk, kk, Bbf, Kp, 1); }
    { dim3 g((kk+63)/64, (nn+63)/64);
      k_gemm_mfma<0><<<g,B256,0,stream>>>(Abf, Bbf, TB, kk, nn, kk, K3, nullptr, 0); }
    { dim3 gt((kk+31)/32, (nn+31)/32);
      k_split3_T<<<gt,B256,0,stream>>>(SPD, nn, kk, kk, Abf, Kp, 0); }
    { dim3 gt((kk+31)/32, (nn+31)/32);
      k_split3_T<<<gt,B256,0,stream>>>(TB, nn, kk, kk, Bbf, Kp, 1); }
    { dim3 g((kk+63)/64, (kk+63)/64);
      k_gemm_mfma<2><<<g,B256,0,stream>>>(Abf, Bbf, Aoth, kk, kk, kk, K3, nullptr, 0); }
    { float* t = X; X = XN; XN = t; }
    { float* t = Acur; Acur = Aoth; Aoth = t; }
    nn = kk;
  };

  // i=1
  gconv_dense(1); k_mean<<<1,B256,0,stream>>>(X, nn, xs + 2*64);
  // i=2 + pool 1
  gconv_dense(2); k_mean<<<1,B256,0,stream>>>(X, nn, xs + 3*64);
  asap_dense(1215, 1);
  // i=3
  gconv_dense(3); k_mean<<<1,B256,0,stream>>>(X, nn, xs + 4*64);
  // i=4 + pool 2
  gconv_dense(4); k_mean<<<1,B256,0,stream>>>(X, nn, xs + 5*64);
  asap_dense(1094, 2);
  // i=5
  gconv_dense(5); k_mean<<<1,B256,0,stream>>>(X, nn, xs + 6*64);
  // i=6 + pool 3
  gconv_dense(6); k_mean<<<1,B256,0,stream>>>(X, nn, xs + 7*64);
  asap_dense(985, 3);
  // i=7
  gconv_dense(7); k_mean<<<1,B256,0,stream>>>(X, nn, xs + 8*64);
  // i=8
  gconv_dense(8); k_mean<<<1,B256,0,stream>>>(X, nn, xs + 9*64);

  // ---- head ----
  k_mm_small<<<G1(64),B256,0,stream>>>(xs, linW1, linb1, Y, 1, 640, 64, 1);
  k_head<<<1,64,0,stream>>>(Y, linW2, linb2, out);
}

// Round 4
// 2924.522 us; speedup vs baseline: 1.4115x; 1.1734x over previous
//
#include <hip/hip_runtime.h>
#include <math.h>

#define NEGV -1000000000.0f

typedef short short8 __attribute__((ext_vector_type(8)));
typedef float floatx4 __attribute__((ext_vector_type(4)));

__device__ __forceinline__ unsigned f2mono(float f){
  unsigned u = __float_as_uint(f);
  return (u & 0x80000000u) ? ~u : (u | 0x80000000u);
}
__device__ __forceinline__ float mono2f(unsigned u){
  return __uint_as_float((u & 0x80000000u) ? (u & 0x7fffffffu) : ~u);
}
__device__ __forceinline__ float sigm(float x){ return 1.0f/(1.0f+expf(-x)); }
__device__ __forceinline__ void edge_sd(int e,const int* src,const int* dst,int E,int& s,int& d){
  if(e<E){ s=src[e]; d=dst[e]; } else { s=e-E; d=s; }
}
__device__ __forceinline__ ushort bf16rn(float x){
  unsigned u = __float_as_uint(x);
  unsigned r = (u + 0x7fffu + ((u>>16)&1u)) >> 16;
  return (ushort)r;
}
__device__ __forceinline__ float bf16f(ushort h){ return __uint_as_float(((unsigned)h)<<16); }

__global__ void k_zero(float* __restrict__ p, size_t n){
  size_t i = (size_t)blockIdx.x*256 + threadIdx.x;
  if (i < n) p[i] = 0.0f;
}

// ---------------- bf16x3 split conversions ----------------
__global__ void k_split3(const float* __restrict__ src,int R,int Cs,int ld,
                         ushort* __restrict__ dst,int Cp,int bmode){
  int idx = blockIdx.x*256+threadIdx.x;
  if (idx >= R*Cp) return;
  int r = idx / Cp, c = idx - r*Cp;
  float x = (c < Cs) ? src[(size_t)r*ld + c] : 0.0f;
  ushort h = bf16rn(x);
  ushort l = bf16rn(x - bf16f(h));
  size_t base = (size_t)r*(3*Cp) + c;
  dst[base]        = h;
  dst[base + Cp]   = bmode ? l : h;
  dst[base + 2*Cp] = bmode ? h : l;
}
// transpose variant with optional column gather (gperm) and per-src-column scale (cscale).
// src stored Rs(K) x cols (ld); output row xo corresponds to src column gperm[xo].
__global__ void k_split3_T(const float* __restrict__ src,int Rs,int Cs,int ld,
                           const int* __restrict__ gperm,const float* __restrict__ cscale,
                           ushort* __restrict__ dst,int Kp,int bmode){
  __shared__ float t[32][33];
  int tx = threadIdx.x & 31, ty = threadIdx.x >> 5;
  int kb = blockIdx.y*32, xb = blockIdx.x*32;
  int x = xb + tx;
  int gx = (x < Cs) ? (gperm ? gperm[x] : x) : 0;
#pragma unroll
  for (int i=0;i<4;i++){
    int k = kb + ty + i*8;
    t[ty+i*8][tx] = (k < Rs && x < Cs) ? src[(size_t)k*ld + gx] : 0.0f;
  }
  __syncthreads();
  const int K3 = 3*Kp;
#pragma unroll
  for (int i=0;i<4;i++){
    int xo = xb + ty + i*8, ko = kb + tx;
    if (xo < Cs){
      float v = t[tx][ty+i*8];
      if (cscale){ int g = gperm ? gperm[xo] : xo; v *= cscale[g]; }
      ushort h = bf16rn(v);
      ushort l = bf16rn(v - bf16f(h));
      size_t base = (size_t)xo*K3 + ko;
      dst[base]        = h;
      dst[base + Kp]   = bmode ? l : h;
      dst[base + 2*Kp] = bmode ? h : l;
    }
  }
}

// ---------------- MFMA bf16 GEMM (64x64 tile, 4 waves, 16x16x32) ----------------
template<int EPI>
__global__ __launch_bounds__(256) void k_gemm_mfma(
    const ushort* __restrict__ A, const ushort* __restrict__ B,
    float* __restrict__ C, int ldc, int M, int N, int K3,
    const float* __restrict__ mask, int ldm)
{
  __shared__ ushort As[64][40];
  __shared__ ushort Bs[64][40];
  const int tid = threadIdx.x;
  const int m0 = blockIdx.y*64, n0 = blockIdx.x*64;
  const int w = tid>>6, lane = tid&63;
  const int lo4 = lane&15, quad = lane>>4;
  const int sr = tid>>2, sseg = tid&3;

  floatx4 acc[4];
#pragma unroll
  for(int c=0;c<4;c++){ acc[c][0]=0.f; acc[c][1]=0.f; acc[c][2]=0.f; acc[c][3]=0.f; }

  const size_t arow = (size_t)(m0+sr)*K3;
  const size_t brow = (size_t)(n0+sr)*K3;
  const bool aval = (m0+sr) < M;
  const bool bval = (n0+sr) < N;

  for (int k0 = 0; k0 < K3; k0 += 32) {
    uint4 av = make_uint4(0,0,0,0), bv = make_uint4(0,0,0,0);
    if (aval) av = *(const uint4*)(A + arow + k0 + sseg*8);
    if (bval) bv = *(const uint4*)(B + brow + k0 + sseg*8);
    __syncthreads();
    *(uint4*)&As[sr][sseg*8] = av;
    *(uint4*)&Bs[sr][sseg*8] = bv;
    __syncthreads();
    short8 af = *(const short8*)&As[16*w + lo4][quad*8];
#pragma unroll
    for (int c=0;c<4;c++){
      short8 bf = *(const short8*)&Bs[16*c + lo4][quad*8];
      acc[c] = __builtin_amdgcn_mfma_f32_16x16x32_bf16(af, bf, acc[c], 0, 0, 0);
    }
  }

#pragma unroll
  for (int c=0;c<4;c++){
    const int gn = n0 + 16*c + lo4;
#pragma unroll
    for (int r=0;r<4;r++){
      const int gm = m0 + 16*w + quad*4 + r;
      if (gm < M && gn < N){
        float v = acc[c][r];
        if (EPI==1) v = (mask[(size_t)gm*ldm+gn] != 0.0f) ? (v > 0.0f ? v : 0.2f*v) : NEGV;
        if (EPI==2 && gm==gn) v = 0.0f;
        C[(size_t)gm*ldc+gn] = v;
      }
    }
  }
}

// ---------------- atomic-free skinny agg GEMM ----------------
// C_part[z][m][h] = (sum|max)_k in chunk z:  op(A[k][m]) with X[k][h]
// A: K x M row-major (lda). X: K x 64. P: Z x M x 64. cntp: Z x M (count A!=0 per column chunk).
// grid (1, ceil(M/64), Z), block 256.
template<bool MAXM, bool COUNT>
__global__ __launch_bounds__(256) void k_skinny(
    const float* __restrict__ A, int lda,
    const float* __restrict__ X,
    float* __restrict__ P, int* __restrict__ cntp,
    int M, int K, int kchunk)
{
  __shared__ float As[16][68];
  __shared__ float Xs[16][68];
  const int tid = threadIdx.x;
  const int m0 = blockIdx.y * 64;
  const int tmb = (tid & 15) * 4, tnb = (tid >> 4) * 4;
  float acc[4][4];
  int cacc[4] = {0,0,0,0};
#pragma unroll
  for (int i=0;i<4;i++)
#pragma unroll
    for (int j=0;j<4;j++) acc[i][j] = MAXM ? NEGV : 0.0f;

  const int kstart = blockIdx.z * kchunk;
  int kend = kstart + kchunk; if (kend > K) kend = K;
  const int ml = tid & 63, tb = tid >> 6;
  const bool mvalid = (m0 + ml) < M;

  for (int k0 = kstart; k0 < kend; k0 += 16) {
#pragma unroll
    for (int s=0;s<4;s++) {
      const int tk = tb + s*4;
      float va = 0.0f, vx = 0.0f;
      if ((k0+tk) < K) {
        if (mvalid) va = A[(size_t)(k0+tk)*lda + m0 + ml];
        vx = X[(size_t)(k0+tk)*64 + ml];
      }
      As[tk][ml] = va;
      Xs[tk][ml] = vx;
    }
    __syncthreads();
#pragma unroll
    for (int kk=0; kk<16; kk++) {
      const float4 a4 = *(const float4*)&As[kk][tmb];
      const float4 b4 = *(const float4*)&Xs[kk][tnb];
      const float av[4] = {a4.x,a4.y,a4.z,a4.w};
      const float bv[4] = {b4.x,b4.y,b4.z,b4.w};
#pragma unroll
      for (int i=0;i<4;i++){
        if (COUNT) cacc[i] += (av[i] != 0.0f) ? 1 : 0;
#pragma unroll
        for (int j=0;j<4;j++) {
          if (MAXM) acc[i][j] = fmaxf(acc[i][j], av[i] != 0.0f ? bv[j] : NEGV);
          else      acc[i][j] = fmaf(av[i], bv[j], acc[i][j]);
        }
      }
    }
    __syncthreads();
  }

  const size_t slab = (size_t)blockIdx.z * M * 64;
#pragma unroll
  for (int i=0;i<4;i++){
    const int m = m0 + tmb + i;
    if (m < M){
#pragma unroll
      for (int j=0;j<4;j++) P[slab + (size_t)m*64 + tnb + j] = acc[i][j];
    }
  }
  if (COUNT && tnb == 0){
#pragma unroll
    for (int i=0;i<4;i++){
      const int m = m0 + tmb + i;
      if (m < M) cntp[blockIdx.z*M + m] = cacc[i];
    }
  }
}

// reduce Z slabs: out[i][h] = sum_z or max_z P[z][i][h]; optional *scal[i];
// optional count reduce (h==0): cntf[i] = max(clampMin, sum_z cntp[z][i]).
__global__ void k_red8(const float* __restrict__ P,int Z,int n,float* __restrict__ out,
                       const int* __restrict__ cntp,float* cntf,int clampMin,
                       const float* __restrict__ scal,int domax){
  int idx = blockIdx.x*256+threadIdx.x; if(idx>=n*64) return;
  int i = idx>>6, h = idx&63;
  float v = domax ? NEGV : 0.0f;
  for(int z=0;z<Z;z++){
    float q = P[(size_t)z*n*64 + idx];
    v = domax ? fmaxf(v,q) : v+q;
  }
  if(scal) v *= scal[i];
  out[idx] = v;
  if(cntf && h==0){
    int c=0; for(int z=0;z<Z;z++) c += cntp[z*n+i];
    if(c<clampMin) c=clampMin;
    cntf[i] = (float)c;
  }
}

// ---------------- fused column softmax (online, 3 kernels) ----------------
// K1: per (rowchunk, col) partial max & sum-of-exp(local)
__global__ void k_smax_part(const float* __restrict__ S,int n,int R,
                            float* __restrict__ pm,float* __restrict__ ps){
  __shared__ float red[4][64];
  int jl = threadIdx.x & 63, rg = threadIdx.x >> 6;
  int j = blockIdx.x*64 + jl;
  int rc = blockIdx.y;
  int i0 = (int)(((long long)n*rc)/R), i1 = (int)(((long long)n*(rc+1))/R);
  float m = -3.0e38f;
  if(j<n) for(int i=i0+rg;i<i1;i+=4) m = fmaxf(m, S[(size_t)i*n+j]);
  red[rg][jl]=m; __syncthreads();
  float mc = fmaxf(fmaxf(red[0][jl],red[1][jl]),fmaxf(red[2][jl],red[3][jl]));
  __syncthreads();
  float s = 0.0f;
  if(j<n) for(int i=i0+rg;i<i1;i+=4) s += expf(S[(size_t)i*n+j]-mc);
  red[rg][jl]=s; __syncthreads();
  if(rg==0 && j<n){
    pm[(size_t)rc*n+j]=mc;
    ps[(size_t)rc*n+j]=red[0][jl]+red[1][jl]+red[2][jl]+red[3][jl];
  }
}
__global__ void k_smax_merge(const float* __restrict__ pm,const float* __restrict__ ps,
                             int n,int R,float* mcol,float* denom,float* invd){
  int j = blockIdx.x*256+threadIdx.x; if(j>=n) return;
  float m = -3.0e38f;
  for(int r=0;r<R;r++) m = fmaxf(m, pm[(size_t)r*n+j]);
  float d = 0.0f;
  for(int r=0;r<R;r++) d += ps[(size_t)r*n+j]*expf(pm[(size_t)r*n+j]-m);
  mcol[j]=m; denom[j]=d; invd[j]=1.0f/d;
}
__global__ void k_smax_exp(float* __restrict__ S,const float* __restrict__ mcol,int n){
  int idx = blockIdx.x*256+threadIdx.x; if(idx>=n*n) return;
  int j = idx - (idx/n)*n;
  S[idx] = expf(S[idx]-mcol[j]);
}

// ---------------- small kernels ----------------
__global__ void k_deg(const int* __restrict__ src,const int* __restrict__ dst,int* indeg,int* outdeg,int E){
  int e = blockIdx.x*256+threadIdx.x; if(e>=E) return;
  atomicAdd(&indeg[dst[e]],1); atomicAdd(&outdeg[src[e]],1);
}

__global__ void k_mm_small(const float* __restrict__ A,const float* __restrict__ W,
                           const float* __restrict__ b,float* __restrict__ C,
                           int M,int K,int Np,int act){
  int idx = blockIdx.x*256+threadIdx.x; if(idx>=M*Np) return;
  int m = idx/Np, j = idx - m*Np;
  float s = b ? b[j] : 0.0f;
  const float* a = A + (size_t)m*K;
  for(int q=0;q<K;q++) s = fmaf(a[q], W[(size_t)q*Np + j], s);
  if(act==1) s = fmaxf(s, 0.0f);
  C[idx] = s;
}

__global__ void k_copy_int(int* d,const int* s,int n){ int i=blockIdx.x*256+threadIdx.x; if(i<n) d[i]=s[i]; }

__global__ void k_scatter_add(const int* __restrict__ src,const int* __restrict__ dst,
                              const float* __restrict__ Y,float* SEG,int E,int H){
  int idx = blockIdx.x*256+threadIdx.x; if(idx>=E*H) return;
  int e = idx/H, h = idx - e*H;
  atomicAdd(&SEG[(size_t)dst[e]*H + h], Y[(size_t)src[e]*H + h]);
}

__global__ void k_feast_fin(const float* __restrict__ SEG,const float* __restrict__ Y,
                            const int* __restrict__ indeg,
                            const float* __restrict__ b,float* X,int n,int H){
  int idx = blockIdx.x*256+threadIdx.x; if(idx>=n*H) return;
  int i = idx/H, h = idx - i*H;
  float v = (SEG[idx] + Y[idx])/(float)(indeg[i]+1) + b[h];
  X[idx] = v > 0.0f ? v : (expf(v)-1.0f);
}

__global__ void k_cnt_sparse(const int* indeg,float* cntf,int n){
  int i = blockIdx.x*256+threadIdx.x; if(i>=n) return;
  cntf[i] = (float)(indeg[i] > 1 ? indeg[i] : 1);
}

__global__ void k_gconv_fin(const float* __restrict__ AGG,const float* __restrict__ cnt,
                            const float* __restrict__ Wrel,const float* __restrict__ brel,
                            const float* __restrict__ X,const float* __restrict__ Wroot,
                            float* XN,int n){
  int idx = blockIdx.x*256+threadIdx.x; if(idx>=n*64) return;
  int i = idx >> 6, j = idx & 63;
  const float* ag = AGG + (size_t)i*64;
  const float* xr = X + (size_t)i*64;
  float a = 0.0f, r = 0.0f;
  for(int q=0;q<64;q++){ a = fmaf(ag[q], Wrel[q*64+j], a); r = fmaf(xr[q], Wroot[q*64+j], r); }
  float v = a/cnt[i] + brel[j] + r;
  XN[idx] = fmaxf(v, 0.0f);
}

__global__ void k_mean(const float* __restrict__ X,int n,float* o){
  __shared__ float sh[256];
  int t = threadIdx.x; int h = t & 63, p = t >> 6;
  float s = 0.0f;
  for(int i=p;i<n;i+=4) s += X[(size_t)i*64 + h];
  sh[t] = s; __syncthreads();
  if(t < 64) o[t] = (sh[t]+sh[t+64]+sh[t+128]+sh[t+192])/(float)n;
}

__global__ void k_mono_init_from(unsigned* M,const float* X,int n){
  int i = blockIdx.x*256+threadIdx.x; if(i<n) M[i] = f2mono(X[i]);
}
__global__ void k_fill_mono(unsigned* M,int n,float v){
  int i = blockIdx.x*256+threadIdx.x; if(i<n) M[i] = f2mono(v);
}
__global__ void k_mono_fin(float* out,const unsigned* M,int n){
  int i = blockIdx.x*256+threadIdx.x; if(i<n){ unsigned u = M[i]; out[i] = mono2f(u); }
}
__global__ void k_scatter_max(const int* __restrict__ src,const int* __restrict__ dst,
                              const float* __restrict__ X,unsigned* M,int E,int H){
  int idx = blockIdx.x*256+threadIdx.x; if(idx>=E*H) return;
  int e = idx/H, h = idx - e*H;
  atomicMax(&M[(size_t)dst[e]*H + h], f2mono(X[(size_t)src[e]*H + h]));
}

__global__ void k_edge_score(const int* __restrict__ src,const int* __restrict__ dst,
                             const float* __restrict__ XQ2,const float* __restrict__ X,
                             float* sE,int E,int n){
  int e = blockIdx.x*256+threadIdx.x; if(e>=E+n) return;
  int s,d; edge_sd(e,src,dst,E,s,d);
  const float* q = XQ2 + (size_t)d*64;
  const float* x = X + (size_t)s*64;
  float acc = 0.0f;
  for(int h=0;h<64;h++) acc = fmaf(q[h], x[h], acc);
  sE[e] = acc > 0.0f ? acc : 0.2f*acc;
}
__global__ void k_segmax_edge(const int* src,const int* dst,const float* sE,unsigned* M,int E,int n){
  int e = blockIdx.x*256+threadIdx.x; if(e>=E+n) return;
  int s,d; edge_sd(e,src,dst,E,s,d);
  atomicMax(&M[d], f2mono(sE[e]));
}
__global__ void k_exp_edge(const int* src,const int* dst,const float* sE,const float* m,
                           float* eE,float* denom,int E,int n){
  int e = blockIdx.x*256+threadIdx.x; if(e>=E+n) return;
  int s,d; edge_sd(e,src,dst,E,s,d);
  float v = expf(sE[e]-m[d]); eE[e]=v; atomicAdd(&denom[d],v);
}
__global__ void k_score_edge(const int* src,const int* dst,const float* eE,const float* denom,
                             float* scE,int E,int n){
  int e = blockIdx.x*256+threadIdx.x; if(e>=E+n) return;
  int s,d; edge_sd(e,src,dst,E,s,d);
  scE[e] = eE[e]/denom[d];
}
__global__ void k_xc_scatter(const int* __restrict__ src,const int* __restrict__ dst,
                             const float* __restrict__ scE,const float* __restrict__ X,
                             float* XC,int E,int n){
  int idx = blockIdx.x*256+threadIdx.x; if(idx>=(E+n)*64) return;
  int e = idx >> 6, h = idx & 63;
  int s,d; edge_sd(e,src,dst,E,s,d);
  atomicAdd(&XC[(size_t)d*64 + h], scE[e]*X[(size_t)s*64 + h]);
}
__global__ void k_abc(const float* __restrict__ XC,const float* __restrict__ w1,const float* bb1,
                      const float* __restrict__ w2,const float* __restrict__ w3,const float* bb3,
                      float* aN,float* bN,float* cN,int n){
  int v = blockIdx.x*256+threadIdx.x; if(v>=n) return;
  const float* xc = XC + (size_t)v*64;
  float a = bb1[0], b = 0.0f, c = bb3[0];
  for(int h=0;h<64;h++){ a=fmaf(xc[h],w1[h],a); b=fmaf(xc[h],w2[h],b); c=fmaf(xc[h],w3[h],c); }
  aN[v]=a; bN[v]=b; cN[v]=c;
}
__global__ void k_agg_edge(const int* src,const int* dst,const float* aN,float* agg,int E,int n){
  int e = blockIdx.x*256+threadIdx.x; if(e>=E+n) return;
  int s,d; edge_sd(e,src,dst,E,s,d);
  atomicAdd(&agg[d], aN[s]);
}
__global__ void k_fit_sparse(const float* agg,const int* indeg,const float* bN,const float* cN,
                             float* fit,int n){
  int v = blockIdx.x*256+threadIdx.x; if(v>=n) return;
  fit[v] = sigm(agg[v] - (float)(indeg[v]+1)*bN[v] + cN[v]);
}
__global__ void k_fit_dense(const float* agg,const float* cntP,const float* bN,const float* cN,
                            float* fit,int n){
  int v = blockIdx.x*256+threadIdx.x; if(v>=n) return;
  fit[v] = sigm(agg[v] - cntP[v]*bN[v] + cN[v]);
}

__global__ void k_rank(const float* __restrict__ fit,int n,int k,int* sel){
  int v = blockIdx.x*256+threadIdx.x; if(v>=n) return;
  float fv = fit[v]; int r = 0;
  for(int u=0;u<n;u++){ float fu = fit[u]; if(fu > fv || (fu == fv && u < v)) r++; }
  sel[v] = (r < k) ? 1 : 0;
}
__global__ void k_compact(const int* __restrict__ sel,int n,int* perm){
  int v = blockIdx.x*256+threadIdx.x; if(v>=n || !sel[v]) return;
  int p = 0;
  for(int u=0;u<v;u++) p += sel[u];
  perm[p] = v;
}
__global__ void k_xnew(const float* __restrict__ XC,const float* __restrict__ fit,
                       const int* __restrict__ perm,float* XN,int k){
  int idx = blockIdx.x*256+threadIdx.x; if(idx>=k*64) return;
  int u = idx >> 6, h = idx & 63; int v = perm[u];
  XN[idx] = XC[(size_t)v*64 + h]*fit[v];
}

__global__ void k_prefix(const int* __restrict__ deg,int* off,int n){
  int t = blockIdx.x*256+threadIdx.x; if(t>n) return;
  int s = 0;
  for(int u=0;u<t;u++) s += deg[u]+1;
  off[t] = s;
}
__global__ void k_csr_fill(const int* src,const int* dst,const float* scE,
                           int* curS,int* colS,float* valS,
                           int* curD,int* rowD,float* valD,int E,int n){
  int e = blockIdx.x*256+threadIdx.x; if(e>=E+n) return;
  int s,d; edge_sd(e,src,dst,E,s,d);
  float sc = scE[e];
  int p = atomicAdd(&curS[s],1); colS[p]=d; valS[p]=sc;
  int q = atomicAdd(&curD[d],1); rowD[q]=s; valD[q]=sc;
}
__global__ void k_stage1(const int* src,const int* dst,const int* __restrict__ offS,
                         const int* __restrict__ colS,const float* __restrict__ valS,
                         float* R,int E,int n){
  int e = blockIdx.x*256+threadIdx.x; if(e>=E+n) return;
  int i,j; edge_sd(e,src,dst,E,i,j);
  int p0 = offS[j], p1 = offS[j+1];
  float* Ri = R + (size_t)i*n;
  for(int p=p0;p<p1;p++) atomicAdd(&Ri[colS[p]], valS[p]);
}
__global__ void k_gather_cols(const float* __restrict__ S,int ldS,const int* __restrict__ perm,
                              float* out,int k,int rows){
  int idx = blockIdx.x*256+threadIdx.x; if(idx>=rows*k) return;
  int i = idx/k, u = idx - i*k;
  out[idx] = S[(size_t)i*ldS + perm[u]];
}
__global__ void k_stage2(const int* __restrict__ perm,const int* __restrict__ offD,
                         const int* __restrict__ rowD,const float* __restrict__ valD,
                         const float* __restrict__ Rp,float* A,int k){
  int idx = blockIdx.x*256+threadIdx.x; if(idx>=k*k) return;
  int u = idx/k, v = idx - u*k; int d = perm[u];
  float acc = 0.0f;
  int p0 = offD[d], p1 = offD[d+1];
  for(int p=p0;p<p1;p++) acc = fmaf(valD[p], Rp[(size_t)rowD[p]*k + v], acc);
  A[idx] = (u==v) ? 0.0f : acc;
}

__global__ void k_diagfix(float* A,int n){
  int i = blockIdx.x*256+threadIdx.x; if(i>=n) return;
  size_t d = (size_t)i*n + i;
  if(A[d]==0.0f) A[d]=1.0f;
}
__global__ void k_aggcol_part(const float* __restrict__ A,const float* __restrict__ aN,
                              float* agg,int n){
  int idx = blockIdx.x*256+threadIdx.x; if(idx>=n*16) return;
  int j = idx % n, c = idx / n;
  int i0 = (int)(((long long)n*c)/16), i1 = (int)(((long long)n*(c+1))/16);
  float s = 0.0f;
  for(int i=i0;i<i1;i++) if(A[(size_t)i*n + j] != 0.0f) s += aN[i];
  if(s != 0.0f) atomicAdd(&agg[j], s);
}

__global__ void k_head(const float* __restrict__ h2,const float* __restrict__ W,
                       const float* __restrict__ b,float* out){
  __shared__ float lg[10];
  int t = threadIdx.x;
  if(t < 10){
    float s = b[t];
    for(int k=0;k<64;k++) s = fmaf(h2[k], W[k*10+t], s);
    lg[t] = s;
  }
  __syncthreads();
  if(t == 0){
    float mx = lg[0];
    for(int i=1;i<10;i++) mx = fmaxf(mx, lg[i]);
    float se = 0.0f;
    for(int i=0;i<10;i++) se += expf(lg[i]-mx);
    float lse = mx + logf(se);
    for(int i=0;i<10;i++) out[i] = lg[i]-lse;
  }
}

// ---------------- host orchestration ----------------
extern "C" void kernel_launch(void* const* d_in, const int* in_sizes, int n_in,
                              void* d_out, int out_size, void* d_ws, size_t ws_size,
                              hipStream_t stream) {
  const int N0 = 1500, E = 24000, Z = 8;
  const float* x0   = (const float*)d_in[0];
  const int* esrc   = (const int*)d_in[1];
  const int* edst   = (const int*)d_in[2];
  const float* W1   = (const float*)d_in[3];  const float* b1   = (const float*)d_in[4];
  const float* W2   = (const float*)d_in[5];  const float* b2   = (const float*)d_in[6];
  const float* W3   = (const float*)d_in[7];  const float* b3   = (const float*)d_in[8];
  const float* Wrel = (const float*)d_in[9];  const float* brel = (const float*)d_in[10];
  const float* Wroot= (const float*)d_in[11];
  const float* pW   = (const float*)d_in[12]; const float* pb   = (const float*)d_in[13];
  const float* leW1 = (const float*)d_in[14]; const float* leb1 = (const float*)d_in[15];
  const float* leW2 = (const float*)d_in[16]; const float* leW3 = (const float*)d_in[17];
  const float* leb3 = (const float*)d_in[18];
  const float* linW1= (const float*)d_in[19]; const float* linb1= (const float*)d_in[20];
  const float* linW2= (const float*)d_in[21]; const float* linb2= (const float*)d_in[22];
  float* out = (float*)d_out;

  float* ws = (float*)d_ws;
  size_t cur = 0;
  auto allocF = [&](size_t nf)->float*{ float* p = ws + cur; cur += (nf + 15) & ~(size_t)15; return p; };
  float* Xa  = allocF(96000); float* Xb  = allocF(96000); float* Y   = allocF(96000);
  float* XQ2 = allocF(96000); float* XC  = allocF(96000); float* SEG = allocF(96000);
  float* xs  = allocF(640);
  float* mcol = allocF(1504); float* denom = allocF(1504); float* invd = allocF(1504);
  float* aN = allocF(1500); float* bN = allocF(1500); float* cN = allocF(1500);
  float* fit = allocF(1500); float* agg1 = allocF(1500); float* cntf = allocF(1500); float* cntP = allocF(1500);
  int* indeg = (int*)allocF(1500); int* outdeg = (int*)allocF(1500);
  int* sel = (int*)allocF(1500); int* perm = (int*)allocF(1500);
  int* offS = (int*)allocF(1504); int* offD = (int*)allocF(1504);
  int* curS = (int*)allocF(1504); int* curD = (int*)allocF(1504);
  int* colS = (int*)allocF(25504); int* rowD = (int*)allocF(25504);
  unsigned* mmono = (unsigned*)allocF(1504);
  float* valS = allocF(25504); float* valD = allocF(25504);
  float* sE = allocF(25504); float* eE = allocF(25504); float* scE = allocF(25504);
  float* pm = allocF(8*1504); float* ps = allocF(8*1504);
  int* cntp8 = (int*)allocF(8*1504);
  float* SEGP = allocF((size_t)Z*1504*64);
  float* R   = allocF((size_t)1500*1500);
  float* TB  = allocF((size_t)1500*1350);
  float* SCb = allocF((size_t)1350*1350);
  float* A0  = allocF((size_t)1350*1350);
  float* A1s = allocF((size_t)1350*1350);
  ushort* Abf = (ushort*)allocF((size_t)1350*4128/2 + 32);
  ushort* Bbf = (ushort*)allocF((size_t)1350*4128/2 + 32);

  dim3 B256(256);
  auto G1 = [&](size_t n){ return dim3((unsigned)((n + 255) / 256)); };
  auto ZF = [&](void* p, size_t nfloats){ k_zero<<<G1(nfloats),B256,0,stream>>>((float*)p, nfloats); };
  auto kc8 = [&](int K){ return (int)(((K + Z*16 - 1) / (Z*16)) * 16); };

  // degrees
  ZF(indeg, 1500); ZF(outdeg, 1500);
  k_deg<<<G1(E),B256,0,stream>>>(esrc, edst, indeg, outdeg, E);

  // ---- FEAST x3 ----
  auto feast = [&](const float* xin,int cin,const float* W,const float* bb,int hh,float* xout){
    ZF(SEG, (size_t)N0*hh);
    k_mm_small<<<G1((size_t)N0*hh),B256,0,stream>>>(xin, W, nullptr, Y, N0, cin, hh, 0);
    k_scatter_add<<<G1((size_t)E*hh),B256,0,stream>>>(esrc, edst, Y, SEG, E, hh);
    k_feast_fin<<<G1((size_t)N0*hh),B256,0,stream>>>(SEG, Y, indeg, bb, xout, N0, hh);
  };
  feast(x0, 16, W1, b1, 32, Xa);
  feast(Xa, 32, W2, b2, 64, Xb);
  feast(Xb, 64, W3, b3, 64, Xa);
  float* X = Xa; float* XN = Xb;
  k_mean<<<1,B256,0,stream>>>(X, N0, xs + 0);

  // ---- i=0 gconv_sparse ----
  ZF(SEG, (size_t)N0*64);
  k_scatter_add<<<G1((size_t)E*64),B256,0,stream>>>(esrc, edst, X, SEG, E, 64);
  k_cnt_sparse<<<G1(N0),B256,0,stream>>>(indeg, cntf, N0);
  k_gconv_fin<<<G1((size_t)N0*64),B256,0,stream>>>(SEG, cntf, Wrel, brel, X, Wroot, XN, N0);
  { float* t = X; X = XN; XN = t; }
  k_mean<<<1,B256,0,stream>>>(X, N0, xs + 64);

  // ---- pool 0 (sparse ASAP), n=1500 -> k=1350 ----
  {
    const int n = 1500, kk = 1350, L = E + n;
    unsigned* xqm = (unsigned*)Y;
    k_mono_init_from<<<G1((size_t)n*64),B256,0,stream>>>(xqm, X, n*64);
    k_scatter_max<<<G1((size_t)E*64),B256,0,stream>>>(esrc, edst, X, xqm, E, 64);
    k_mono_fin<<<G1((size_t)n*64),B256,0,stream>>>(Y, xqm, n*64);
    k_mm_small<<<G1((size_t)n*64),B256,0,stream>>>(Y, pW, pb, XQ2, n, 64, 64, 0);
    k_edge_score<<<G1(L),B256,0,stream>>>(esrc, edst, XQ2, X, sE, E, n);
    k_fill_mono<<<G1(n),B256,0,stream>>>(mmono, n, -3.0e38f);
    k_segmax_edge<<<G1(L),B256,0,stream>>>(esrc, edst, sE, mmono, E, n);
    k_mono_fin<<<G1(n),B256,0,stream>>>(mcol, mmono, n);
    ZF(denom, n);
    k_exp_edge<<<G1(L),B256,0,stream>>>(esrc, edst, sE, mcol, eE, denom, E, n);
    k_score_edge<<<G1(L),B256,0,stream>>>(esrc, edst, eE, denom, scE, E, n);
    ZF(XC, (size_t)n*64);
    k_xc_scatter<<<G1((size_t)L*64),B256,0,stream>>>(esrc, edst, scE, X, XC, E, n);
    k_abc<<<G1(n),B256,0,stream>>>(XC, leW1, leb1, leW2, leW3, leb3, aN, bN, cN, n);
    ZF(agg1, n);
    k_agg_edge<<<G1(L),B256,0,stream>>>(esrc, edst, aN, agg1, E, n);
    k_fit_sparse<<<G1(n),B256,0,stream>>>(agg1, indeg, bN, cN, fit, n);
    k_rank<<<G1(n),B256,0,stream>>>(fit, n, kk, sel);
    k_compact<<<G1(n),B256,0,stream>>>(sel, n, perm);
    k_xnew<<<G1((size_t)kk*64),B256,0,stream>>>(XC, fit, perm, XN, kk);
    // sparse A_new = Sp^T A Sp
    k_prefix<<<G1(n+1),B256,0,stream>>>(outdeg, offS, n);
    k_prefix<<<G1(n+1),B256,0,stream>>>(indeg, offD, n);
    k_copy_int<<<G1(n),B256,0,stream>>>(curS, offS, n);
    k_copy_int<<<G1(n),B256,0,stream>>>(curD, offD, n);
    k_csr_fill<<<G1(L),B256,0,stream>>>(esrc, edst, scE, curS, colS, valS, curD, rowD, valD, E, n);
    ZF(R, (size_t)n*n);
    k_stage1<<<G1(L),B256,0,stream>>>(esrc, edst, offS, colS, valS, R, E, n);
    k_gather_cols<<<G1((size_t)n*kk),B256,0,stream>>>(R, n, perm, TB, kk, n);
    k_stage2<<<G1((size_t)kk*kk),B256,0,stream>>>(perm, offD, rowD, valD, TB, A0, kk);
    { float* t = X; X = XN; XN = t; }
  }

  float* Acur = A0; float* Aoth = A1s;
  int nn = 1350;

  // ---- dense gconv ----
  auto gconv_dense = [&](int layer){
    dim3 g(1, (nn+63)/64, Z);
    k_skinny<false,true><<<g,B256,0,stream>>>(Acur, nn, X, SEGP, cntp8, nn, nn, kc8(nn));
    k_red8<<<G1((size_t)nn*64),B256,0,stream>>>(SEGP, Z, nn, SEG, cntp8, cntf, 1, nullptr, 0);
    k_gconv_fin<<<G1((size_t)nn*64),B256,0,stream>>>(SEG, cntf, Wrel + (size_t)layer*4096, brel + layer*64,
                                                    X, Wroot + (size_t)layer*4096, XN, nn);
    { float* t = X; X = XN; XN = t; }
  };

  // ---- dense ASAP pool ----
  auto asap_dense = [&](int kk, int p){
    k_diagfix<<<G1(nn),B256,0,stream>>>(Acur, nn);
    // xq = masked column-max of x (+ column nonzero counts), then @ pW + pb
    {
      dim3 g(1, (nn+63)/64, Z);
      k_skinny<true,true><<<g,B256,0,stream>>>(Acur, nn, X, SEGP, cntp8, nn, nn, kc8(nn));
      k_red8<<<G1((size_t)nn*64),B256,0,stream>>>(SEGP, Z, nn, Y, cntp8, cntP, 0, nullptr, 1);
    }
    k_mm_small<<<G1((size_t)nn*64),B256,0,stream>>>(Y, pW + (size_t)p*4096, pb + p*64, XQ2, nn, 64, 64, 0);
    // Sc = mask ? lrelu(x @ xq^T) : NEG   -- bf16x3 MFMA, K=64 -> K3=192
    k_split3<<<G1((size_t)nn*64),B256,0,stream>>>(X,   nn, 64, 64, Abf, 64, 0);
    k_split3<<<G1((size_t)nn*64),B256,0,stream>>>(XQ2, nn, 64, 64, Bbf, 64, 1);
    {
      dim3 g((nn+63)/64, (nn+63)/64);
      k_gemm_mfma<1><<<g,B256,0,stream>>>(Abf, Bbf, SCb, nn, nn, nn, 192, Acur, nn);
    }
    // fused column softmax: SCb <- e (unnormalized); denom deferred via invd
    {
      dim3 g1((nn+63)/64, 8);
      k_smax_part<<<g1,B256,0,stream>>>(SCb, nn, 8, pm, ps);
      k_smax_merge<<<G1(nn),B256,0,stream>>>(pm, ps, nn, 8, mcol, denom, invd);
      k_smax_exp<<<G1((size_t)nn*nn),B256,0,stream>>>(SCb, mcol, nn);
    }
    // xc = score^T @ x  (scale by invd in reduce)
    {
      dim3 g(1, (nn+63)/64, Z);
      k_skinny<false,false><<<g,B256,0,stream>>>(SCb, nn, X, SEGP, nullptr, nn, nn, kc8(nn));
      k_red8<<<G1((size_t)nn*64),B256,0,stream>>>(SEGP, Z, nn, XC, nullptr, nullptr, 0, invd, 0);
    }
    k_abc<<<G1(nn),B256,0,stream>>>(XC, leW1 + p*64, leb1 + p, leW2 + p*64, leW3 + p*64, leb3 + p, aN, bN, cN, nn);
    ZF(agg1, nn);
    k_aggcol_part<<<G1((size_t)nn*16),B256,0,stream>>>(Acur, aN, agg1, nn);
    k_fit_dense<<<G1(nn),B256,0,stream>>>(agg1, cntP, bN, cN, fit, nn);
    k_rank<<<G1(nn),B256,0,stream>>>(fit, nn, kk, sel);
    k_compact<<<G1(nn),B256,0,stream>>>(sel, nn, perm);
    k_xnew<<<G1((size_t)kk*64),B256,0,stream>>>(XC, fit, perm, XN, kk);
    // A_new = Sp^T @ (A' @ Sp) via bf16x3 MFMA; Sp gathered+scaled at conversion
    const int Kp = (nn + 31) & ~31;
    const int K3 = 3*Kp;
    k_split3<<<G1((size_t)nn*Kp),B256,0,stream>>>(Acur, nn, nn, nn, Abf, Kp, 0);
    { dim3 gt((kk+31)/32, (nn+31)/32);
      k_split3_T<<<gt,B256,0,stream>>>(SCb, nn, kk, nn, perm, invd, Bbf, Kp, 1); }
    { dim3 g((kk+63)/64, (nn+63)/64);
      k_gemm_mfma<0><<<g,B256,0,stream>>>(Abf, Bbf, TB, kk, nn, kk, K3, nullptr, 0); }
    { dim3 gt((kk+31)/32, (nn+31)/32);
      k_split3_T<<<gt,B256,0,stream>>>(SCb, nn, kk, nn, perm, invd, Abf, Kp, 0); }
    { dim3 gt((kk+31)/32, (nn+31)/32);
      k_split3_T<<<gt,B256,0,stream>>>(TB, nn, kk, kk, nullptr, nullptr, Bbf, Kp, 1); }
    { dim3 g((kk+63)/64, (kk+63)/64);
      k_gemm_mfma<2><<<g,B256,0,stream>>>(Abf, Bbf, Aoth, kk, kk, kk, K3, nullptr, 0); }
    { float* t = X; X = XN; XN = t; }
    { float* t = Acur; Acur = Aoth; Aoth = t; }
    nn = kk;
  };

  // i=1
  gconv_dense(1); k_mean<<<1,B256,0,stream>>>(X, nn, xs + 2*64);
  // i=2 + pool 1
  gconv_dense(2); k_mean<<<1,B256,0,stream>>>(X, nn, xs + 3*64);
  asap_dense(1215, 1);
  // i=3
  gconv_dense(3); k_mean<<<1,B256,0,stream>>>(X, nn, xs + 4*64);
  // i=4 + pool 2
  gconv_dense(4); k_mean<<<1,B256,0,stream>>>(X, nn, xs + 5*64);
  asap_dense(1094, 2);
  // i=5
  gconv_dense(5); k_mean<<<1,B256,0,stream>>>(X, nn, xs + 6*64);
  // i=6 + pool 3
  gconv_dense(6); k_mean<<<1,B256,0,stream>>>(X, nn, xs + 7*64);
  asap_dense(985, 3);
  // i=7
  gconv_dense(7); k_mean<<<1,B256,0,stream>>>(X, nn, xs + 8*64);
  // i=8
  gconv_dense(8); k_mean<<<1,B256,0,stream>>>(X, nn, xs + 9*64);

  // ---- head ----
  k_mm_small<<<G1(64),B256,0,stream>>>(xs, linW1, linb1, Y, 1, 640, 64, 1);
  k_head<<<1,64,0,stream>>>(Y, linW2, linb2, out);
}

// Round 5
// 2102.303 us; speedup vs baseline: 1.9635x; 1.3911x over previous
//
#include <hip/hip_runtime.h>
#include <math.h>

#define NEGV -1000000000.0f

typedef short short8 __attribute__((ext_vector_type(8)));
typedef float floatx4 __attribute__((ext_vector_type(4)));

__device__ __forceinline__ unsigned f2mono(float f){
  unsigned u = __float_as_uint(f);
  return (u & 0x80000000u) ? ~u : (u | 0x80000000u);
}
__device__ __forceinline__ float mono2f(unsigned u){
  return __uint_as_float((u & 0x80000000u) ? (u & 0x7fffffffu) : ~u);
}
__device__ __forceinline__ float sigm(float x){ return 1.0f/(1.0f+expf(-x)); }
__device__ __forceinline__ void edge_sd(int e,const int* src,const int* dst,int E,int& s,int& d){
  if(e<E){ s=src[e]; d=dst[e]; } else { s=e-E; d=s; }
}
__device__ __forceinline__ ushort bf16rn(float x){
  unsigned u = __float_as_uint(x);
  unsigned r = (u + 0x7fffu + ((u>>16)&1u)) >> 16;
  return (ushort)r;
}
__device__ __forceinline__ float bf16f(ushort h){ return __uint_as_float(((unsigned)h)<<16); }

__global__ void k_zero(float* __restrict__ p, size_t n){
  size_t i = (size_t)blockIdx.x*256 + threadIdx.x;
  if (i < n) p[i] = 0.0f;
}

// ---------------- bf16x3 split conversions ----------------
__global__ void k_split3(const float* __restrict__ src,int R,int Cs,int ld,
                         ushort* __restrict__ dst,int Cp,int bmode){
  int idx = blockIdx.x*256+threadIdx.x;
  if (idx >= R*Cp) return;
  int r = idx / Cp, c = idx - r*Cp;
  float x = (c < Cs) ? src[(size_t)r*ld + c] : 0.0f;
  ushort h = bf16rn(x);
  ushort l = bf16rn(x - bf16f(h));
  size_t base = (size_t)r*(3*Cp) + c;
  dst[base]        = h;
  dst[base + Cp]   = bmode ? l : h;
  dst[base + 2*Cp] = bmode ? h : l;
}
// dual: Xsrc -> dstA (bmode0), Qsrc -> dstB (bmode1), both R x 64, Cp=64
__global__ void k_split3_dual(const float* __restrict__ Xsrc,const float* __restrict__ Qsrc,
                              int R,ushort* __restrict__ dstA,ushort* __restrict__ dstB){
  int idx = blockIdx.x*256+threadIdx.x;
  if (idx >= R*64) return;
  int r = idx >> 6, c = idx & 63;
  size_t base = (size_t)r*192 + c;
  float x = Xsrc[idx];
  ushort h = bf16rn(x), l = bf16rn(x - bf16f(h));
  dstA[base] = h; dstA[base+64] = h; dstA[base+128] = l;
  float q = Qsrc[idx];
  h = bf16rn(q); l = bf16rn(q - bf16f(h));
  dstB[base] = h; dstB[base+64] = l; dstB[base+128] = h;
}
// transpose variant: src Rs(K) x cols (ld); out row xo = src column gperm[xo].
// emax!=null: v = exp(v - emax[g]) (masked-softmax fusion); cscale: v *= cscale[g].
// Grid y must cover Kp/32; k>=Rs rows emit 0.
__global__ void k_split3_T(const float* __restrict__ src,int Rs,int Cs,int ld,
                           const int* __restrict__ gperm,const float* __restrict__ cscale,
                           const float* __restrict__ emax,
                           ushort* __restrict__ dst,int Kp,int bmode){
  __shared__ float t[32][33];
  int tx = threadIdx.x & 31, ty = threadIdx.x >> 5;
  int kb = blockIdx.y*32, xb = blockIdx.x*32;
  int x = xb + tx;
  int gx = (x < Cs) ? (gperm ? gperm[x] : x) : 0;
#pragma unroll
  for (int i=0;i<4;i++){
    int k = kb + ty + i*8;
    t[ty+i*8][tx] = (k < Rs && x < Cs) ? src[(size_t)k*ld + gx] : 0.0f;
  }
  __syncthreads();
  const int K3 = 3*Kp;
#pragma unroll
  for (int i=0;i<4;i++){
    int xo = xb + ty + i*8, ko = kb + tx;
    if (xo < Cs){
      float v = 0.0f;
      if (ko < Rs){
        v = t[tx][ty+i*8];
        int g = gperm ? gperm[xo] : xo;
        if (emax)   v = expf(v - emax[g]);
        if (cscale) v *= cscale[g];
      }
      ushort h = bf16rn(v);
      ushort l = bf16rn(v - bf16f(h));
      size_t base = (size_t)xo*K3 + ko;
      dst[base]        = h;
      dst[base + Kp]   = bmode ? l : h;
      dst[base + 2*Kp] = bmode ? h : l;
    }
  }
}

// ---------------- MFMA bf16 GEMM (64x64 tile, 4 waves, K-step 64) ----------------
// K3 must be a multiple of 64. EPI: 0 none, 1 mask+leakyrelu, 2 zero diag.
template<int EPI>
__global__ __launch_bounds__(256) void k_gemm_mfma(
    const ushort* __restrict__ A, const ushort* __restrict__ B,
    float* __restrict__ C, int ldc, int M, int N, int K3,
    const float* __restrict__ mask, int ldm)
{
  __shared__ ushort As[64][72];
  __shared__ ushort Bs[64][72];
  const int tid = threadIdx.x;
  const int m0 = blockIdx.y*64, n0 = blockIdx.x*64;
  const int w = tid>>6, lane = tid&63;
  const int lo4 = lane&15, quad = lane>>4;
  const int sr = tid>>2, sseg = tid&3;

  floatx4 acc[4];
#pragma unroll
  for(int c=0;c<4;c++){ acc[c][0]=0.f; acc[c][1]=0.f; acc[c][2]=0.f; acc[c][3]=0.f; }

  const size_t arow = (size_t)(m0+sr)*K3;
  const size_t brow = (size_t)(n0+sr)*K3;
  const bool aval = (m0+sr) < M;
  const bool bval = (n0+sr) < N;

  for (int k0 = 0; k0 < K3; k0 += 64) {
    uint4 av0 = make_uint4(0,0,0,0), av1 = make_uint4(0,0,0,0);
    uint4 bv0 = make_uint4(0,0,0,0), bv1 = make_uint4(0,0,0,0);
    if (aval){ av0 = *(const uint4*)(A + arow + k0 + sseg*8);
               av1 = *(const uint4*)(A + arow + k0 + 32 + sseg*8); }
    if (bval){ bv0 = *(const uint4*)(B + brow + k0 + sseg*8);
               bv1 = *(const uint4*)(B + brow + k0 + 32 + sseg*8); }
    __syncthreads();
    *(uint4*)&As[sr][sseg*8] = av0; *(uint4*)&As[sr][32+sseg*8] = av1;
    *(uint4*)&Bs[sr][sseg*8] = bv0; *(uint4*)&Bs[sr][32+sseg*8] = bv1;
    __syncthreads();
    short8 af0 = *(const short8*)&As[16*w + lo4][quad*8];
    short8 af1 = *(const short8*)&As[16*w + lo4][32+quad*8];
#pragma unroll
    for (int c=0;c<4;c++){
      short8 bf0 = *(const short8*)&Bs[16*c + lo4][quad*8];
      acc[c] = __builtin_amdgcn_mfma_f32_16x16x32_bf16(af0, bf0, acc[c], 0, 0, 0);
      short8 bf1 = *(const short8*)&Bs[16*c + lo4][32+quad*8];
      acc[c] = __builtin_amdgcn_mfma_f32_16x16x32_bf16(af1, bf1, acc[c], 0, 0, 0);
    }
  }

#pragma unroll
  for (int c=0;c<4;c++){
    const int gn = n0 + 16*c + lo4;
#pragma unroll
    for (int r=0;r<4;r++){
      const int gm = m0 + 16*w + quad*4 + r;
      if (gm < M && gn < N){
        float v = acc[c][r];
        if (EPI==1) v = (mask[(size_t)gm*ldm+gn] != 0.0f) ? (v > 0.0f ? v : 0.2f*v) : NEGV;
        if (EPI==2 && gm==gn) v = 0.0f;
        C[(size_t)gm*ldc+gn] = v;
      }
    }
  }
}

// ---------------- atomic-free skinny agg GEMM ----------------
// EXPM: A-element -> exp(A - mcol[m]) (masked-softmax fused; NEG -> 0).
template<bool MAXM, bool COUNT, bool EXPM>
__global__ __launch_bounds__(256) void k_skinny(
    const float* __restrict__ A, int lda,
    const float* __restrict__ X,
    const float* __restrict__ mcol,
    float* __restrict__ P, int* __restrict__ cntp,
    int M, int K, int kchunk)
{
  __shared__ float As[16][68];
  __shared__ float Xs[16][68];
  const int tid = threadIdx.x;
  const int m0 = blockIdx.y * 64;
  const int tmb = (tid & 15) * 4, tnb = (tid >> 4) * 4;
  float acc[4][4];
  int cacc[4] = {0,0,0,0};
#pragma unroll
  for (int i=0;i<4;i++)
#pragma unroll
    for (int j=0;j<4;j++) acc[i][j] = MAXM ? NEGV : 0.0f;

  const int kstart = blockIdx.z * kchunk;
  int kend = kstart + kchunk; if (kend > K) kend = K;
  const int ml = tid & 63, tb = tid >> 6;
  const bool mvalid = (m0 + ml) < M;
  float mc = 0.0f;
  if (EXPM && mvalid) mc = mcol[m0 + ml];

  for (int k0 = kstart; k0 < kend; k0 += 16) {
#pragma unroll
    for (int s=0;s<4;s++) {
      const int tk = tb + s*4;
      float va = 0.0f, vx = 0.0f;
      if ((k0+tk) < K) {
        if (mvalid){
          va = A[(size_t)(k0+tk)*lda + m0 + ml];
          if (EXPM) va = expf(va - mc);
        }
        vx = X[(size_t)(k0+tk)*64 + ml];
      }
      As[tk][ml] = va;
      Xs[tk][ml] = vx;
    }
    __syncthreads();
#pragma unroll
    for (int kk=0; kk<16; kk++) {
      const float4 a4 = *(const float4*)&As[kk][tmb];
      const float4 b4 = *(const float4*)&Xs[kk][tnb];
      const float av[4] = {a4.x,a4.y,a4.z,a4.w};
      const float bv[4] = {b4.x,b4.y,b4.z,b4.w};
#pragma unroll
      for (int i=0;i<4;i++){
        if (COUNT) cacc[i] += (av[i] != 0.0f) ? 1 : 0;
#pragma unroll
        for (int j=0;j<4;j++) {
          if (MAXM) acc[i][j] = fmaxf(acc[i][j], av[i] != 0.0f ? bv[j] : NEGV);
          else      acc[i][j] = fmaf(av[i], bv[j], acc[i][j]);
        }
      }
    }
    __syncthreads();
  }

  const size_t slab = (size_t)blockIdx.z * M * 64;
#pragma unroll
  for (int i=0;i<4;i++){
    const int m = m0 + tmb + i;
    if (m < M){
#pragma unroll
      for (int j=0;j<4;j++) P[slab + (size_t)m*64 + tnb + j] = acc[i][j];
    }
  }
  if (COUNT && tnb == 0){
#pragma unroll
    for (int i=0;i<4;i++){
      const int m = m0 + tmb + i;
      if (m < M) cntp[blockIdx.z*M + m] = cacc[i];
    }
  }
}

// reduce Z slabs: out = sum/max over z, optional scale; optional count (h==0).
__global__ void k_red8(const float* __restrict__ P,int Z,int n,float* __restrict__ out,
                       const int* __restrict__ cntp,float* cntf,int clampMin,
                       const float* __restrict__ scal,int domax){
  int idx = blockIdx.x*256+threadIdx.x; if(idx>=n*64) return;
  int i = idx>>6, h = idx&63;
  float v = domax ? NEGV : 0.0f;
  for(int z=0;z<Z;z++){
    float q = P[(size_t)z*n*64 + idx];
    v = domax ? fmaxf(v,q) : v+q;
  }
  if(scal) v *= scal[i];
  out[idx] = v;
  if(cntf && h==0){
    int c=0; for(int z=0;z<Z;z++) c += cntp[z*n+i];
    if(c<clampMin) c=clampMin;
    cntf[i] = (float)c;
  }
}

// fused dense gconv: reduce SEGP+cntp8, two 64x64 matmuls, relu, mean-accumulate.
__global__ __launch_bounds__(256) void k_gconv_fuse(
    const float* __restrict__ SEGP,const int* __restrict__ cntp8,int Z,
    const float* __restrict__ Wrel,const float* __restrict__ brel,
    const float* __restrict__ X,const float* __restrict__ Wroot,
    float* __restrict__ XN,int n,float* __restrict__ meanacc,float inv_n)
{
  __shared__ float agg_s[4][65];
  __shared__ float xrow[4][65];
  __shared__ float cnt_s[4];
  const int tid = threadIdx.x;
  const int r = tid>>6, j = tid&63;
  const int i = blockIdx.x*4 + r;
  float a = 0.0f;
  if (i < n){
    for(int z=0;z<Z;z++) a += SEGP[(size_t)z*n*64 + (size_t)i*64 + j];
    xrow[r][j] = X[(size_t)i*64 + j];
    if (j == 0){
      int c=0; for(int z=0;z<Z;z++) c += cntp8[z*n+i];
      cnt_s[r] = (float)(c>1?c:1);
    }
  }
  agg_s[r][j] = a;
  __syncthreads();
  float v = 0.0f;
  if (i < n){
    float acc=0.0f, rt=0.0f;
    for(int q=0;q<64;q++){
      acc = fmaf(agg_s[r][q], Wrel[q*64+j], acc);
      rt  = fmaf(xrow[r][q],  Wroot[q*64+j], rt);
    }
    v = fmaxf(acc/cnt_s[r] + brel[j] + rt, 0.0f);
    XN[(size_t)i*64 + j] = v;
  }
  __syncthreads();
  agg_s[r][j] = v;
  __syncthreads();
  if (r == 0) atomicAdd(&meanacc[j], (agg_s[0][j]+agg_s[1][j]+agg_s[2][j]+agg_s[3][j])*inv_n);
}

// ---------------- fused column softmax stats (2 kernels) ----------------
__global__ void k_smax_part(const float* __restrict__ S,int n,int R,
                            float* __restrict__ pm,float* __restrict__ ps){
  __shared__ float red[4][64];
  int jl = threadIdx.x & 63, rg = threadIdx.x >> 6;
  int j = blockIdx.x*64 + jl;
  int rc = blockIdx.y;
  int i0 = (int)(((long long)n*rc)/R), i1 = (int)(((long long)n*(rc+1))/R);
  float m = -3.0e38f;
  if(j<n) for(int i=i0+rg;i<i1;i+=4) m = fmaxf(m, S[(size_t)i*n+j]);
  red[rg][jl]=m; __syncthreads();
  float mc = fmaxf(fmaxf(red[0][jl],red[1][jl]),fmaxf(red[2][jl],red[3][jl]));
  __syncthreads();
  float s = 0.0f;
  if(j<n) for(int i=i0+rg;i<i1;i+=4) s += expf(S[(size_t)i*n+j]-mc);
  red[rg][jl]=s; __syncthreads();
  if(rg==0 && j<n){
    pm[(size_t)rc*n+j]=mc;
    ps[(size_t)rc*n+j]=red[0][jl]+red[1][jl]+red[2][jl]+red[3][jl];
  }
}
__global__ void k_smax_merge(const float* __restrict__ pm,const float* __restrict__ ps,
                             int n,int R,float* mcol,float* invd){
  int j = blockIdx.x*256+threadIdx.x; if(j>=n) return;
  float m = -3.0e38f;
  for(int r=0;r<R;r++) m = fmaxf(m, pm[(size_t)r*n+j]);
  float d = 0.0f;
  for(int r=0;r<R;r++) d += ps[(size_t)r*n+j]*expf(pm[(size_t)r*n+j]-m);
  mcol[j]=m; invd[j]=1.0f/d;
}

// ---------------- small kernels ----------------
__global__ void k_deg(const int* __restrict__ src,const int* __restrict__ dst,int* indeg,int* outdeg,int E){
  int e = blockIdx.x*256+threadIdx.x; if(e>=E) return;
  atomicAdd(&indeg[dst[e]],1); atomicAdd(&outdeg[src[e]],1);
}

__global__ void k_mm_small(const float* __restrict__ A,const float* __restrict__ W,
                           const float* __restrict__ b,float* __restrict__ C,
                           int M,int K,int Np,int act){
  int idx = blockIdx.x*256+threadIdx.x; if(idx>=M*Np) return;
  int m = idx/Np, j = idx - m*Np;
  float s = b ? b[j] : 0.0f;
  const float* a = A + (size_t)m*K;
  for(int q=0;q<K;q++) s = fmaf(a[q], W[(size_t)q*Np + j], s);
  if(act==1) s = fmaxf(s, 0.0f);
  C[idx] = s;
}

__global__ void k_copy_int(int* d,const int* s,int n){ int i=blockIdx.x*256+threadIdx.x; if(i<n) d[i]=s[i]; }

__global__ void k_scatter_add(const int* __restrict__ src,const int* __restrict__ dst,
                              const float* __restrict__ Y,float* SEG,int E,int H){
  int idx = blockIdx.x*256+threadIdx.x; if(idx>=E*H) return;
  int e = idx/H, h = idx - e*H;
  atomicAdd(&SEG[(size_t)dst[e]*H + h], Y[(size_t)src[e]*H + h]);
}

// v = (SEG+Y)/(indeg+1)+b; elu; optional mean accumulation (H must be 64)
__global__ void k_feast_fin(const float* __restrict__ SEG,const float* __restrict__ Y,
                            const int* __restrict__ indeg,
                            const float* __restrict__ b,float* X,int n,int H,
                            float* __restrict__ meanacc,float inv_n){
  __shared__ float ms[4][64];
  int idx = blockIdx.x*256+threadIdx.x;
  float v = 0.0f;
  if(idx<n*H){
    int i = idx/H, h = idx - i*H;
    float t = (SEG[idx] + Y[idx])/(float)(indeg[i]+1) + b[h];
    v = t > 0.0f ? t : (expf(t)-1.0f);
    X[idx] = v;
  }
  if(meanacc){
    int r = threadIdx.x>>6, j = threadIdx.x&63;
    ms[r][j] = (idx<n*H) ? v : 0.0f;
    __syncthreads();
    if(r==0) atomicAdd(&meanacc[j], (ms[0][j]+ms[1][j]+ms[2][j]+ms[3][j])*inv_n);
  }
}

__global__ void k_cnt_sparse(const int* indeg,float* cntf,int n){
  int i = blockIdx.x*256+threadIdx.x; if(i>=n) return;
  cntf[i] = (float)(indeg[i] > 1 ? indeg[i] : 1);
}

// sparse-layer gconv finish + mean accumulation
__global__ void k_gconv_fin(const float* __restrict__ AGG,const float* __restrict__ cnt,
                            const float* __restrict__ Wrel,const float* __restrict__ brel,
                            const float* __restrict__ X,const float* __restrict__ Wroot,
                            float* XN,int n,float* __restrict__ meanacc,float inv_n){
  __shared__ float ms[4][64];
  int idx = blockIdx.x*256+threadIdx.x;
  float v = 0.0f;
  if(idx<n*64){
    int i = idx >> 6, j = idx & 63;
    const float* ag = AGG + (size_t)i*64;
    const float* xr = X + (size_t)i*64;
    float a = 0.0f, r = 0.0f;
    for(int q=0;q<64;q++){ a = fmaf(ag[q], Wrel[q*64+j], a); r = fmaf(xr[q], Wroot[q*64+j], r); }
    v = fmaxf(a/cnt[i] + brel[j] + r, 0.0f);
    XN[idx] = v;
  }
  int r2 = threadIdx.x>>6, j2 = threadIdx.x&63;
  ms[r2][j2] = (idx<n*64) ? v : 0.0f;
  __syncthreads();
  if(r2==0) atomicAdd(&meanacc[j2], (ms[0][j2]+ms[1][j2]+ms[2][j2]+ms[3][j2])*inv_n);
}

__global__ void k_mono_init_from(unsigned* M,const float* X,int n){
  int i = blockIdx.x*256+threadIdx.x; if(i<n) M[i] = f2mono(X[i]);
}
__global__ void k_fill_mono(unsigned* M,int n,float v){
  int i = blockIdx.x*256+threadIdx.x; if(i<n) M[i] = f2mono(v);
}
__global__ void k_mono_fin(float* out,const unsigned* M,int n){
  int i = blockIdx.x*256+threadIdx.x; if(i<n){ unsigned u = M[i]; out[i] = mono2f(u); }
}
__global__ void k_scatter_max(const int* __restrict__ src,const int* __restrict__ dst,
                              const float* __restrict__ X,unsigned* M,int E,int H){
  int idx = blockIdx.x*256+threadIdx.x; if(idx>=E*H) return;
  int e = idx/H, h = idx - e*H;
  atomicMax(&M[(size_t)dst[e]*H + h], f2mono(X[(size_t)src[e]*H + h]));
}

__global__ void k_edge_score(const int* __restrict__ src,const int* __restrict__ dst,
                             const float* __restrict__ XQ2,const float* __restrict__ X,
                             float* sE,int E,int n){
  int e = blockIdx.x*256+threadIdx.x; if(e>=E+n) return;
  int s,d; edge_sd(e,src,dst,E,s,d);
  const float* q = XQ2 + (size_t)d*64;
  const float* x = X + (size_t)s*64;
  float acc = 0.0f;
  for(int h=0;h<64;h++) acc = fmaf(q[h], x[h], acc);
  sE[e] = acc > 0.0f ? acc : 0.2f*acc;
}
__global__ void k_segmax_edge(const int* src,const int* dst,const float* sE,unsigned* M,int E,int n){
  int e = blockIdx.x*256+threadIdx.x; if(e>=E+n) return;
  int s,d; edge_sd(e,src,dst,E,s,d);
  atomicMax(&M[d], f2mono(sE[e]));
}
__global__ void k_exp_edge(const int* src,const int* dst,const float* sE,const float* m,
                           float* eE,float* denom,int E,int n){
  int e = blockIdx.x*256+threadIdx.x; if(e>=E+n) return;
  int s,d; edge_sd(e,src,dst,E,s,d);
  float v = expf(sE[e]-m[d]); eE[e]=v; atomicAdd(&denom[d],v);
}
__global__ void k_score_edge(const int* src,const int* dst,const float* eE,const float* denom,
                             float* scE,int E,int n){
  int e = blockIdx.x*256+threadIdx.x; if(e>=E+n) return;
  int s,d; edge_sd(e,src,dst,E,s,d);
  scE[e] = eE[e]/denom[d];
}
__global__ void k_xc_scatter(const int* __restrict__ src,const int* __restrict__ dst,
                             const float* __restrict__ scE,const float* __restrict__ X,
                             float* XC,int E,int n){
  int idx = blockIdx.x*256+threadIdx.x; if(idx>=(E+n)*64) return;
  int e = idx >> 6, h = idx & 63;
  int s,d; edge_sd(e,src,dst,E,s,d);
  atomicAdd(&XC[(size_t)d*64 + h], scE[e]*X[(size_t)s*64 + h]);
}
__global__ void k_abc(const float* __restrict__ XC,const float* __restrict__ w1,const float* bb1,
                      const float* __restrict__ w2,const float* __restrict__ w3,const float* bb3,
                      float* aN,float* bN,float* cN,int n){
  int v = blockIdx.x*256+threadIdx.x; if(v>=n) return;
  const float* xc = XC + (size_t)v*64;
  float a = bb1[0], b = 0.0f, c = bb3[0];
  for(int h=0;h<64;h++){ a=fmaf(xc[h],w1[h],a); b=fmaf(xc[h],w2[h],b); c=fmaf(xc[h],w3[h],c); }
  aN[v]=a; bN[v]=b; cN[v]=c;
}
__global__ void k_agg_edge(const int* src,const int* dst,const float* aN,float* agg,int E,int n){
  int e = blockIdx.x*256+threadIdx.x; if(e>=E+n) return;
  int s,d; edge_sd(e,src,dst,E,s,d);
  atomicAdd(&agg[d], aN[s]);
}
__global__ void k_fit_sparse(const float* agg,const int* indeg,const float* bN,const float* cN,
                             float* fit,int n){
  int v = blockIdx.x*256+threadIdx.x; if(v>=n) return;
  fit[v] = sigm(agg[v] - (float)(indeg[v]+1)*bN[v] + cN[v]);
}
// agg from 16 slabs (no atomics)
__global__ void k_fit_dense(const float* __restrict__ aggp,const float* cntP,const float* bN,const float* cN,
                            float* fit,int n){
  int v = blockIdx.x*256+threadIdx.x; if(v>=n) return;
  float a = 0.0f;
  for(int c=0;c<16;c++) a += aggp[c*n+v];
  fit[v] = sigm(a - cntP[v]*bN[v] + cN[v]);
}

__global__ void k_rank(const float* __restrict__ fit,int n,int k,int* sel){
  int v = blockIdx.x*256+threadIdx.x; if(v>=n) return;
  float fv = fit[v]; int r = 0;
  for(int u=0;u<n;u++){ float fu = fit[u]; if(fu > fv || (fu == fv && u < v)) r++; }
  sel[v] = (r < k) ? 1 : 0;
}
__global__ void k_compact(const int* __restrict__ sel,int n,int* perm){
  int v = blockIdx.x*256+threadIdx.x; if(v>=n || !sel[v]) return;
  int p = 0;
  for(int u=0;u<v;u++) p += sel[u];
  perm[p] = v;
}
__global__ void k_xnew(const float* __restrict__ XC,const float* __restrict__ fit,
                       const int* __restrict__ perm,float* XN,int k){
  int idx = blockIdx.x*256+threadIdx.x; if(idx>=k*64) return;
  int u = idx >> 6, h = idx & 63; int v = perm[u];
  XN[idx] = XC[(size_t)v*64 + h]*fit[v];
}

__global__ void k_prefix(const int* __restrict__ deg,int* off,int n){
  int t = blockIdx.x*256+threadIdx.x; if(t>n) return;
  int s = 0;
  for(int u=0;u<t;u++) s += deg[u]+1;
  off[t] = s;
}
__global__ void k_csr_fill(const int* src,const int* dst,const float* scE,
                           int* curS,int* colS,float* valS,
                           int* curD,int* rowD,float* valD,int E,int n){
  int e = blockIdx.x*256+threadIdx.x; if(e>=E+n) return;
  int s,d; edge_sd(e,src,dst,E,s,d);
  float sc = scE[e];
  int p = atomicAdd(&curS[s],1); colS[p]=d; valS[p]=sc;
  int q = atomicAdd(&curD[d],1); rowD[q]=s; valD[q]=sc;
}
__global__ void k_stage1(const int* src,const int* dst,const int* __restrict__ offS,
                         const int* __restrict__ colS,const float* __restrict__ valS,
                         float* R,int E,int n){
  int e = blockIdx.x*256+threadIdx.x; if(e>=E+n) return;
  int i,j; edge_sd(e,src,dst,E,i,j);
  int p0 = offS[j], p1 = offS[j+1];
  float* Ri = R + (size_t)i*n;
  for(int p=p0;p<p1;p++) atomicAdd(&Ri[colS[p]], valS[p]);
}
__global__ void k_gather_cols(const float* __restrict__ S,int ldS,const int* __restrict__ perm,
                              float* out,int k,int rows){
  int idx = blockIdx.x*256+threadIdx.x; if(idx>=rows*k) return;
  int i = idx/k, u = idx - i*k;
  out[idx] = S[(size_t)i*ldS + perm[u]];
}
__global__ void k_stage2(const int* __restrict__ perm,const int* __restrict__ offD,
                         const int* __restrict__ rowD,const float* __restrict__ valD,
                         const float* __restrict__ Rp,float* A,int k){
  int idx = blockIdx.x*256+threadIdx.x; if(idx>=k*k) return;
  int u = idx/k, v = idx - u*k; int d = perm[u];
  float acc = 0.0f;
  int p0 = offD[d], p1 = offD[d+1];
  for(int p=p0;p<p1;p++) acc = fmaf(valD[p], Rp[(size_t)rowD[p]*k + v], acc);
  A[idx] = (u==v) ? 0.0f : acc;
}

__global__ void k_diagfix(float* A,int n){
  int i = blockIdx.x*256+threadIdx.x; if(i>=n) return;
  size_t d = (size_t)i*n + i;
  if(A[d]==0.0f) A[d]=1.0f;
}
// slab (no-atomic) masked column sum of aN over A
__global__ void k_aggcol(const float* __restrict__ A,const float* __restrict__ aN,
                         float* __restrict__ aggp,int n){
  int idx = blockIdx.x*256+threadIdx.x; if(idx>=n*16) return;
  int j = idx % n, c = idx / n;
  int i0 = (int)(((long long)n*c)/16), i1 = (int)(((long long)n*(c+1))/16);
  float s = 0.0f;
  for(int i=i0;i<i1;i++) if(A[(size_t)i*n + j] != 0.0f) s += aN[i];
  aggp[c*n + j] = s;
}

__global__ void k_head(const float* __restrict__ h2,const float* __restrict__ W,
                       const float* __restrict__ b,float* out){
  __shared__ float lg[10];
  int t = threadIdx.x;
  if(t < 10){
    float s = b[t];
    for(int k=0;k<64;k++) s = fmaf(h2[k], W[k*10+t], s);
    lg[t] = s;
  }
  __syncthreads();
  if(t == 0){
    float mx = lg[0];
    for(int i=1;i<10;i++) mx = fmaxf(mx, lg[i]);
    float se = 0.0f;
    for(int i=0;i<10;i++) se += expf(lg[i]-mx);
    float lse = mx + logf(se);
    for(int i=0;i<10;i++) out[i] = lg[i]-lse;
  }
}

// ---------------- host orchestration ----------------
extern "C" void kernel_launch(void* const* d_in, const int* in_sizes, int n_in,
                              void* d_out, int out_size, void* d_ws, size_t ws_size,
                              hipStream_t stream) {
  const int N0 = 1500, E = 24000, Z = 8;
  const float* x0   = (const float*)d_in[0];
  const int* esrc   = (const int*)d_in[1];
  const int* edst   = (const int*)d_in[2];
  const float* W1   = (const float*)d_in[3];  const float* b1   = (const float*)d_in[4];
  const float* W2   = (const float*)d_in[5];  const float* b2   = (const float*)d_in[6];
  const float* W3   = (const float*)d_in[7];  const float* b3   = (const float*)d_in[8];
  const float* Wrel = (const float*)d_in[9];  const float* brel = (const float*)d_in[10];
  const float* Wroot= (const float*)d_in[11];
  const float* pW   = (const float*)d_in[12]; const float* pb   = (const float*)d_in[13];
  const float* leW1 = (const float*)d_in[14]; const float* leb1 = (const float*)d_in[15];
  const float* leW2 = (const float*)d_in[16]; const float* leW3 = (const float*)d_in[17];
  const float* leb3 = (const float*)d_in[18];
  const float* linW1= (const float*)d_in[19]; const float* linb1= (const float*)d_in[20];
  const float* linW2= (const float*)d_in[21]; const float* linb2= (const float*)d_in[22];
  float* out = (float*)d_out;

  float* ws = (float*)d_ws;
  size_t cur = 0;
  auto allocF = [&](size_t nf)->float*{ float* p = ws + cur; cur += (nf + 15) & ~(size_t)15; return p; };
  float* Xa  = allocF(96000); float* Xb  = allocF(96000); float* Y   = allocF(96000);
  float* XQ2 = allocF(96000); float* XC  = allocF(96000); float* SEG = allocF(96000);
  float* xs  = allocF(640);
  float* mcol = allocF(1504); float* denom = allocF(1504); float* invd = allocF(1504);
  float* aN = allocF(1500); float* bN = allocF(1500); float* cN = allocF(1500);
  float* fit = allocF(1500); float* agg1 = allocF(1500); float* cntf = allocF(1500); float* cntP = allocF(1500);
  int* indeg = (int*)allocF(1500); int* outdeg = (int*)allocF(1500);
  int* sel = (int*)allocF(1500); int* perm = (int*)allocF(1500);
  int* offS = (int*)allocF(1504); int* offD = (int*)allocF(1504);
  int* curS = (int*)allocF(1504); int* curD = (int*)allocF(1504);
  int* colS = (int*)allocF(25504); int* rowD = (int*)allocF(25504);
  unsigned* mmono = (unsigned*)allocF(1504);
  float* valS = allocF(25504); float* valD = allocF(25504);
  float* sE = allocF(25504); float* eE = allocF(25504); float* scE = allocF(25504);
  float* pm = allocF(8*1504); float* ps = allocF(8*1504);
  int* cntp8 = (int*)allocF(8*1504);
  float* aggp = allocF(16*1504);
  float* SEGP = allocF((size_t)Z*1504*64);
  float* R   = allocF((size_t)1500*1500);
  float* TB  = allocF((size_t)1500*1350);
  float* SCb = allocF((size_t)1350*1350);
  float* A0  = allocF((size_t)1350*1350);
  float* A1s = allocF((size_t)1350*1350);
  // bf16x3: max nn * 3*round64(nn) = 1350*4224 ushorts
  ushort* Abf = (ushort*)allocF((size_t)1350*4224/2 + 32);
  ushort* Bbf = (ushort*)allocF((size_t)1350*4224/2 + 32);

  dim3 B256(256);
  auto G1 = [&](size_t n){ return dim3((unsigned)((n + 255) / 256)); };
  auto ZF = [&](void* p, size_t nfloats){ k_zero<<<G1(nfloats),B256,0,stream>>>((float*)p, nfloats); };
  auto kc8 = [&](int K){ return (int)(((K + Z*16 - 1) / (Z*16)) * 16); };

  // xs accumulated via atomics -> zero first
  ZF(xs, 640);
  ZF(indeg, 1500); ZF(outdeg, 1500);
  k_deg<<<G1(E),B256,0,stream>>>(esrc, edst, indeg, outdeg, E);

  // ---- FEAST x3 ----
  auto feast = [&](const float* xin,int cin,const float* W,const float* bb,int hh,float* xout,float* macc){
    ZF(SEG, (size_t)N0*hh);
    k_mm_small<<<G1((size_t)N0*hh),B256,0,stream>>>(xin, W, nullptr, Y, N0, cin, hh, 0);
    k_scatter_add<<<G1((size_t)E*hh),B256,0,stream>>>(esrc, edst, Y, SEG, E, hh);
    k_feast_fin<<<G1((size_t)N0*hh),B256,0,stream>>>(SEG, Y, indeg, bb, xout, N0, hh, macc, 1.0f/N0);
  };
  feast(x0, 16, W1, b1, 32, Xa, nullptr);
  feast(Xa, 32, W2, b2, 64, Xb, nullptr);
  feast(Xb, 64, W3, b3, 64, Xa, xs + 0);
  float* X = Xa; float* XN = Xb;

  // ---- i=0 gconv_sparse ----
  ZF(SEG, (size_t)N0*64);
  k_scatter_add<<<G1((size_t)E*64),B256,0,stream>>>(esrc, edst, X, SEG, E, 64);
  k_cnt_sparse<<<G1(N0),B256,0,stream>>>(indeg, cntf, N0);
  k_gconv_fin<<<G1((size_t)N0*64),B256,0,stream>>>(SEG, cntf, Wrel, brel, X, Wroot, XN, N0, xs + 64, 1.0f/N0);
  { float* t = X; X = XN; XN = t; }

  // ---- pool 0 (sparse ASAP), n=1500 -> k=1350 ----
  {
    const int n = 1500, kk = 1350, L = E + n;
    unsigned* xqm = (unsigned*)Y;
    k_mono_init_from<<<G1((size_t)n*64),B256,0,stream>>>(xqm, X, n*64);
    k_scatter_max<<<G1((size_t)E*64),B256,0,stream>>>(esrc, edst, X, xqm, E, 64);
    k_mono_fin<<<G1((size_t)n*64),B256,0,stream>>>(Y, xqm, n*64);
    k_mm_small<<<G1((size_t)n*64),B256,0,stream>>>(Y, pW, pb, XQ2, n, 64, 64, 0);
    k_edge_score<<<G1(L),B256,0,stream>>>(esrc, edst, XQ2, X, sE, E, n);
    k_fill_mono<<<G1(n),B256,0,stream>>>(mmono, n, -3.0e38f);
    k_segmax_edge<<<G1(L),B256,0,stream>>>(esrc, edst, sE, mmono, E, n);
    k_mono_fin<<<G1(n),B256,0,stream>>>(mcol, mmono, n);
    ZF(denom, n);
    k_exp_edge<<<G1(L),B256,0,stream>>>(esrc, edst, sE, mcol, eE, denom, E, n);
    k_score_edge<<<G1(L),B256,0,stream>>>(esrc, edst, eE, denom, scE, E, n);
    ZF(XC, (size_t)n*64);
    k_xc_scatter<<<G1((size_t)L*64),B256,0,stream>>>(esrc, edst, scE, X, XC, E, n);
    k_abc<<<G1(n),B256,0,stream>>>(XC, leW1, leb1, leW2, leW3, leb3, aN, bN, cN, n);
    ZF(agg1, n);
    k_agg_edge<<<G1(L),B256,0,stream>>>(esrc, edst, aN, agg1, E, n);
    k_fit_sparse<<<G1(n),B256,0,stream>>>(agg1, indeg, bN, cN, fit, n);
    k_rank<<<G1(n),B256,0,stream>>>(fit, n, kk, sel);
    k_compact<<<G1(n),B256,0,stream>>>(sel, n, perm);
    k_xnew<<<G1((size_t)kk*64),B256,0,stream>>>(XC, fit, perm, XN, kk);
    k_prefix<<<G1(n+1),B256,0,stream>>>(outdeg, offS, n);
    k_prefix<<<G1(n+1),B256,0,stream>>>(indeg, offD, n);
    k_copy_int<<<G1(n),B256,0,stream>>>(curS, offS, n);
    k_copy_int<<<G1(n),B256,0,stream>>>(curD, offD, n);
    k_csr_fill<<<G1(L),B256,0,stream>>>(esrc, edst, scE, curS, colS, valS, curD, rowD, valD, E, n);
    ZF(R, (size_t)n*n);
    k_stage1<<<G1(L),B256,0,stream>>>(esrc, edst, offS, colS, valS, R, E, n);
    k_gather_cols<<<G1((size_t)n*kk),B256,0,stream>>>(R, n, perm, TB, kk, n);
    k_stage2<<<G1((size_t)kk*kk),B256,0,stream>>>(perm, offD, rowD, valD, TB, A0, kk);
    { float* t = X; X = XN; XN = t; }
  }

  float* Acur = A0; float* Aoth = A1s;
  int nn = 1350;

  // ---- dense gconv (2 nodes) ----
  auto gconv_dense = [&](int layer){
    dim3 g(1, (nn+63)/64, Z);
    k_skinny<false,true,false><<<g,B256,0,stream>>>(Acur, nn, X, nullptr, SEGP, cntp8, nn, nn, kc8(nn));
    k_gconv_fuse<<<dim3((nn+3)/4),B256,0,stream>>>(SEGP, cntp8, Z,
        Wrel + (size_t)layer*4096, brel + layer*64, X, Wroot + (size_t)layer*4096,
        XN, nn, xs + (size_t)(layer+1)*64, 1.0f/nn);
    { float* t = X; X = XN; XN = t; }
  };

  // ---- dense ASAP pool ----
  auto asap_dense = [&](int kk, int p){
    k_diagfix<<<G1(nn),B256,0,stream>>>(Acur, nn);
    {
      dim3 g(1, (nn+63)/64, Z);
      k_skinny<true,true,false><<<g,B256,0,stream>>>(Acur, nn, X, nullptr, SEGP, cntp8, nn, nn, kc8(nn));
      k_red8<<<G1((size_t)nn*64),B256,0,stream>>>(SEGP, Z, nn, Y, cntp8, cntP, 0, nullptr, 1);
    }
    k_mm_small<<<G1((size_t)nn*64),B256,0,stream>>>(Y, pW + (size_t)p*4096, pb + p*64, XQ2, nn, 64, 64, 0);
    // Sc = mask ? lrelu(x @ xq^T) : NEG
    k_split3_dual<<<G1((size_t)nn*64),B256,0,stream>>>(X, XQ2, nn, Abf, Bbf);
    {
      dim3 g((nn+63)/64, (nn+63)/64);
      k_gemm_mfma<1><<<g,B256,0,stream>>>(Abf, Bbf, SCb, nn, nn, nn, 192, Acur, nn);
    }
    // column-softmax stats only; exp fused into consumers
    {
      dim3 g1((nn+63)/64, 8);
      k_smax_part<<<g1,B256,0,stream>>>(SCb, nn, 8, pm, ps);
      k_smax_merge<<<G1(nn),B256,0,stream>>>(pm, ps, nn, 8, mcol, invd);
    }
    // xc = softmax(Sc)^T @ x   (exp fused in skinny, invd in red8)
    {
      dim3 g(1, (nn+63)/64, Z);
      k_skinny<false,false,true><<<g,B256,0,stream>>>(SCb, nn, X, mcol, SEGP, nullptr, nn, nn, kc8(nn));
      k_red8<<<G1((size_t)nn*64),B256,0,stream>>>(SEGP, Z, nn, XC, nullptr, nullptr, 0, invd, 0);
    }
    k_abc<<<G1(nn),B256,0,stream>>>(XC, leW1 + p*64, leb1 + p, leW2 + p*64, leW3 + p*64, leb3 + p, aN, bN, cN, nn);
    k_aggcol<<<G1((size_t)nn*16),B256,0,stream>>>(Acur, aN, aggp, nn);
    k_fit_dense<<<G1(nn),B256,0,stream>>>(aggp, cntP, bN, cN, fit, nn);
    k_rank<<<G1(nn),B256,0,stream>>>(fit, nn, kk, sel);
    k_compact<<<G1(nn),B256,0,stream>>>(sel, nn, perm);
    k_xnew<<<G1((size_t)kk*64),B256,0,stream>>>(XC, fit, perm, XN, kk);
    // A_new = Sp^T @ (A' @ Sp); Sp = exp(SCb-mcol)*invd gathered at conversion
    const int Kp = (nn + 63) & ~63;
    const int K3 = 3*Kp;
    k_split3<<<G1((size_t)nn*Kp),B256,0,stream>>>(Acur, nn, nn, nn, Abf, Kp, 0);
    { dim3 gt((kk+31)/32, Kp/32);
      k_split3_T<<<gt,B256,0,stream>>>(SCb, nn, kk, nn, perm, invd, mcol, Bbf, Kp, 1); }
    { dim3 g((kk+63)/64, (nn+63)/64);
      k_gemm_mfma<0><<<g,B256,0,stream>>>(Abf, Bbf, TB, kk, nn, kk, K3, nullptr, 0); }
    { dim3 gt((kk+31)/32, Kp/32);
      k_split3_T<<<gt,B256,0,stream>>>(SCb, nn, kk, nn, perm, invd, mcol, Abf, Kp, 0); }
    { dim3 gt((kk+31)/32, Kp/32);
      k_split3_T<<<gt,B256,0,stream>>>(TB, nn, kk, kk, nullptr, nullptr, nullptr, Bbf, Kp, 1); }
    { dim3 g((kk+63)/64, (kk+63)/64);
      k_gemm_mfma<2><<<g,B256,0,stream>>>(Abf, Bbf, Aoth, kk, kk, kk, K3, nullptr, 0); }
    { float* t = X; X = XN; XN = t; }
    { float* t = Acur; Acur = Aoth; Aoth = t; }
    nn = kk;
  };

  gconv_dense(1);
  gconv_dense(2);
  asap_dense(1215, 1);
  gconv_dense(3);
  gconv_dense(4);
  asap_dense(1094, 2);
  gconv_dense(5);
  gconv_dense(6);
  asap_dense(985, 3);
  gconv_dense(7);
  gconv_dense(8);

  // ---- head ----
  k_mm_small<<<G1(64),B256,0,stream>>>(xs, linW1, linb1, Y, 1, 640, 64, 1);
  k_head<<<1,64,0,stream>>>(Y, linW2, linb2, out);
}

// Round 6
// 1718.606 us; speedup vs baseline: 2.4019x; 1.2233x over previous
//
#include <hip/hip_runtime.h>
#include <math.h>

#define NEGV -1000000000.0f

typedef short short8 __attribute__((ext_vector_type(8)));
typedef float floatx4 __attribute__((ext_vector_type(4)));

__device__ __forceinline__ float sigm(float x){ return 1.0f/(1.0f+expf(-x)); }
__device__ __forceinline__ void edge_sd(int e,const int* src,const int* dst,int E,int& s,int& d){
  if(e<E){ s=src[e]; d=dst[e]; } else { s=e-E; d=s; }
}
__device__ __forceinline__ ushort bf16rn(float x){
  unsigned u = __float_as_uint(x);
  unsigned r = (u + 0x7fffu + ((u>>16)&1u)) >> 16;
  return (ushort)r;
}
__device__ __forceinline__ float bf16f(ushort h){ return __uint_as_float(((unsigned)h)<<16); }

__global__ void k_zero(float* __restrict__ p, size_t n){
  size_t i = (size_t)blockIdx.x*256 + threadIdx.x;
  if (i < n) p[i] = 0.0f;
}

// ---------------- bf16x3 conversions ----------------
__global__ void k_split3(const float* __restrict__ src,int R,int Cs,int ld,
                         ushort* __restrict__ dst,int Cp,int bmode){
  int idx = blockIdx.x*256+threadIdx.x;
  if (idx >= R*Cp) return;
  int r = idx / Cp, c = idx - r*Cp;
  float x = (c < Cs) ? src[(size_t)r*ld + c] : 0.0f;
  ushort h = bf16rn(x);
  ushort l = bf16rn(x - bf16f(h));
  size_t base = (size_t)r*(3*Cp) + c;
  dst[base]        = h;
  dst[base + Cp]   = bmode ? l : h;
  dst[base + 2*Cp] = bmode ? h : l;
}
__global__ void k_split3_dual(const float* __restrict__ Xsrc,const float* __restrict__ Qsrc,
                              int R,ushort* __restrict__ dstA,ushort* __restrict__ dstB){
  int idx = blockIdx.x*256+threadIdx.x;
  if (idx >= R*64) return;
  int r = idx >> 6, c = idx & 63;
  size_t base = (size_t)r*192 + c;
  float x = Xsrc[idx];
  ushort h = bf16rn(x), l = bf16rn(x - bf16f(h));
  dstA[base] = h; dstA[base+64] = h; dstA[base+128] = l;
  float q = Qsrc[idx];
  h = bf16rn(q); l = bf16rn(q - bf16f(h));
  dstB[base] = h; dstB[base+64] = l; dstB[base+128] = h;
}
// Sp = exp(src[:,perm]-mcol[perm])*invd[perm], transposed to K-innermost; writes BOTH
// A-role (dstA) and B-role (dstB); zero-pads k>=Rs rows in dstA/dstB AND dstCpad.
__global__ void k_split3_Tdual(const float* __restrict__ src,int Rs,int Cs,int ld,
                               const int* __restrict__ gperm,const float* __restrict__ cscale,
                               const float* __restrict__ emax,
                               ushort* __restrict__ dstA,ushort* __restrict__ dstB,
                               ushort* __restrict__ dstCpad,int Kp){
  __shared__ float t[32][33];
  int tx = threadIdx.x & 31, ty = threadIdx.x >> 5;
  int kb = blockIdx.y*32, xb = blockIdx.x*32;
  int x = xb + tx;
  int gx = (x < Cs) ? gperm[x] : 0;
#pragma unroll
  for (int i=0;i<4;i++){
    int k = kb + ty + i*8;
    t[ty+i*8][tx] = (k < Rs && x < Cs) ? src[(size_t)k*ld + gx] : 0.0f;
  }
  __syncthreads();
  const int K3 = 3*Kp;
#pragma unroll
  for (int i=0;i<4;i++){
    int xo = xb + ty + i*8, ko = kb + tx;
    if (xo < Cs){
      float v = 0.0f;
      if (ko < Rs){
        int g = gperm[xo];
        v = expf(t[tx][ty+i*8] - emax[g]) * cscale[g];
      }
      ushort h = bf16rn(v);
      ushort l = bf16rn(v - bf16f(h));
      size_t base = (size_t)xo*K3 + ko;
      dstA[base] = h; dstA[base+Kp] = h; dstA[base+2*Kp] = l;
      dstB[base] = h; dstB[base+Kp] = l; dstB[base+2*Kp] = h;
      if (ko >= Rs){ dstCpad[base]=0; dstCpad[base+Kp]=0; dstCpad[base+2*Kp]=0; }
    }
  }
}

// ---------------- MFMA bf16 GEMM (64x64 tile, K-step 64) ----------------
// EPI 1: mask(A+I)+leakyrelu; EPI 2: zero diag.
template<int EPI>
__global__ __launch_bounds__(256) void k_gemm_mfma(
    const ushort* __restrict__ A, const ushort* __restrict__ B,
    float* __restrict__ C, int ldc, int M, int N, int K3,
    const float* __restrict__ mask, int ldm)
{
  __shared__ ushort As[64][72];
  __shared__ ushort Bs[64][72];
  const int tid = threadIdx.x;
  const int m0 = blockIdx.y*64, n0 = blockIdx.x*64;
  const int w = tid>>6, lane = tid&63;
  const int lo4 = lane&15, quad = lane>>4;
  const int sr = tid>>2, sseg = tid&3;

  floatx4 acc[4];
#pragma unroll
  for(int c=0;c<4;c++){ acc[c][0]=0.f; acc[c][1]=0.f; acc[c][2]=0.f; acc[c][3]=0.f; }

  const size_t arow = (size_t)(m0+sr)*K3;
  const size_t brow = (size_t)(n0+sr)*K3;
  const bool aval = (m0+sr) < M;
  const bool bval = (n0+sr) < N;

  for (int k0 = 0; k0 < K3; k0 += 64) {
    uint4 av0 = make_uint4(0,0,0,0), av1 = make_uint4(0,0,0,0);
    uint4 bv0 = make_uint4(0,0,0,0), bv1 = make_uint4(0,0,0,0);
    if (aval){ av0 = *(const uint4*)(A + arow + k0 + sseg*8);
               av1 = *(const uint4*)(A + arow + k0 + 32 + sseg*8); }
    if (bval){ bv0 = *(const uint4*)(B + brow + k0 + sseg*8);
               bv1 = *(const uint4*)(B + brow + k0 + 32 + sseg*8); }
    __syncthreads();
    *(uint4*)&As[sr][sseg*8] = av0; *(uint4*)&As[sr][32+sseg*8] = av1;
    *(uint4*)&Bs[sr][sseg*8] = bv0; *(uint4*)&Bs[sr][32+sseg*8] = bv1;
    __syncthreads();
    short8 af0 = *(const short8*)&As[16*w + lo4][quad*8];
    short8 af1 = *(const short8*)&As[16*w + lo4][32+quad*8];
#pragma unroll
    for (int c=0;c<4;c++){
      short8 bf0 = *(const short8*)&Bs[16*c + lo4][quad*8];
      acc[c] = __builtin_amdgcn_mfma_f32_16x16x32_bf16(af0, bf0, acc[c], 0, 0, 0);
      short8 bf1 = *(const short8*)&Bs[16*c + lo4][32+quad*8];
      acc[c] = __builtin_amdgcn_mfma_f32_16x16x32_bf16(af1, bf1, acc[c], 0, 0, 0);
    }
  }

#pragma unroll
  for (int c=0;c<4;c++){
    const int gn = n0 + 16*c + lo4;
#pragma unroll
    for (int r=0;r<4;r++){
      const int gm = m0 + 16*w + quad*4 + r;
      if (gm < M && gn < N){
        float v = acc[c][r];
        if (EPI==1) v = (mask[(size_t)gm*ldm+gn] != 0.0f || gm==gn) ? (v > 0.0f ? v : 0.2f*v) : NEGV;
        if (EPI==2 && gm==gn) v = 0.0f;
        C[(size_t)gm*ldc+gn] = v;
      }
    }
  }
}

// TB = A@Sp + Sp (fp32 acc), written directly as bf16x3 B-role TRANSPOSED:
// Cb[row=gn][k=gm] with [h,l,h] segments. Sp recomputed fp32 from SC in epilogue.
__global__ __launch_bounds__(256) void k_gemm_mfma_tb(
    const ushort* __restrict__ A, const ushort* __restrict__ B,
    const float* __restrict__ SC, int ldm,
    const int* __restrict__ perm, const float* __restrict__ mcol, const float* __restrict__ invd,
    ushort* __restrict__ Cb, int Kp, int M, int N, int K3)
{
  __shared__ ushort As[64][72];
  __shared__ ushort Bs[64][72];
  const int tid = threadIdx.x;
  const int m0 = blockIdx.y*64, n0 = blockIdx.x*64;
  const int w = tid>>6, lane = tid&63;
  const int lo4 = lane&15, quad = lane>>4;
  const int sr = tid>>2, sseg = tid&3;

  floatx4 acc[4];
#pragma unroll
  for(int c=0;c<4;c++){ acc[c][0]=0.f; acc[c][1]=0.f; acc[c][2]=0.f; acc[c][3]=0.f; }

  const size_t arow = (size_t)(m0+sr)*K3;
  const size_t brow = (size_t)(n0+sr)*K3;
  const bool aval = (m0+sr) < M;
  const bool bval = (n0+sr) < N;

  for (int k0 = 0; k0 < K3; k0 += 64) {
    uint4 av0 = make_uint4(0,0,0,0), av1 = make_uint4(0,0,0,0);
    uint4 bv0 = make_uint4(0,0,0,0), bv1 = make_uint4(0,0,0,0);
    if (aval){ av0 = *(const uint4*)(A + arow + k0 + sseg*8);
               av1 = *(const uint4*)(A + arow + k0 + 32 + sseg*8); }
    if (bval){ bv0 = *(const uint4*)(B + brow + k0 + sseg*8);
               bv1 = *(const uint4*)(B + brow + k0 + 32 + sseg*8); }
    __syncthreads();
    *(uint4*)&As[sr][sseg*8] = av0; *(uint4*)&As[sr][32+sseg*8] = av1;
    *(uint4*)&Bs[sr][sseg*8] = bv0; *(uint4*)&Bs[sr][32+sseg*8] = bv1;
    __syncthreads();
    short8 af0 = *(const short8*)&As[16*w + lo4][quad*8];
    short8 af1 = *(const short8*)&As[16*w + lo4][32+quad*8];
#pragma unroll
    for (int c=0;c<4;c++){
      short8 bf0 = *(const short8*)&Bs[16*c + lo4][quad*8];
      acc[c] = __builtin_amdgcn_mfma_f32_16x16x32_bf16(af0, bf0, acc[c], 0, 0, 0);
      short8 bf1 = *(const short8*)&Bs[16*c + lo4][32+quad*8];
      acc[c] = __builtin_amdgcn_mfma_f32_16x16x32_bf16(af1, bf1, acc[c], 0, 0, 0);
    }
  }

  const int K3o = 3*Kp;
#pragma unroll
  for (int c=0;c<4;c++){
    const int gn = n0 + 16*c + lo4;
    if (gn < N){
      const int pg = perm[gn];
      const float mv = mcol[pg], iv = invd[pg];
#pragma unroll
      for (int r=0;r<4;r++){
        const int gm = m0 + 16*w + quad*4 + r;
        if (gm < M){
          float v = acc[c][r] + expf(SC[(size_t)gm*ldm+pg]-mv)*iv;
          ushort h = bf16rn(v);
          ushort l = bf16rn(v - bf16f(h));
          size_t base = (size_t)gn*K3o + gm;
          Cb[base] = h; Cb[base+Kp] = l; Cb[base+2*Kp] = h;
        }
      }
    }
  }
}

// ---------------- atomic-free skinny agg GEMM ----------------
// SELF: fold +I (self row max). EXPM: exp(A - mcol[m]).
template<bool MAXM, bool COUNT, bool EXPM, bool SELF>
__global__ __launch_bounds__(256) void k_skinny(
    const float* __restrict__ A, int lda,
    const float* __restrict__ X,
    const float* __restrict__ mcol,
    float* __restrict__ P, int* __restrict__ cntp,
    int M, int K, int kchunk)
{
  __shared__ float As[16][68];
  __shared__ float Xs[16][68];
  const int tid = threadIdx.x;
  const int m0 = blockIdx.y * 64;
  const int tmb = (tid & 15) * 4, tnb = (tid >> 4) * 4;
  float acc[4][4];
  int cacc[4] = {0,0,0,0};
#pragma unroll
  for (int i=0;i<4;i++)
#pragma unroll
    for (int j=0;j<4;j++) acc[i][j] = MAXM ? NEGV : 0.0f;

  const int kstart = blockIdx.z * kchunk;
  int kend = kstart + kchunk; if (kend > K) kend = K;
  const int ml = tid & 63, tb = tid >> 6;
  const bool mvalid = (m0 + ml) < M;
  float mc = 0.0f;
  if (EXPM && mvalid) mc = mcol[m0 + ml];

  for (int k0 = kstart; k0 < kend; k0 += 16) {
#pragma unroll
    for (int s=0;s<4;s++) {
      const int tk = tb + s*4;
      float va = 0.0f, vx = 0.0f;
      if ((k0+tk) < K) {
        if (mvalid){
          va = A[(size_t)(k0+tk)*lda + m0 + ml];
          if (EXPM) va = expf(va - mc);
        }
        vx = X[(size_t)(k0+tk)*64 + ml];
      }
      As[tk][ml] = va;
      Xs[tk][ml] = vx;
    }
    __syncthreads();
#pragma unroll
    for (int kk=0; kk<16; kk++) {
      const float4 a4 = *(const float4*)&As[kk][tmb];
      const float4 b4 = *(const float4*)&Xs[kk][tnb];
      const float av[4] = {a4.x,a4.y,a4.z,a4.w};
      const float bv[4] = {b4.x,b4.y,b4.z,b4.w};
#pragma unroll
      for (int i=0;i<4;i++){
        if (COUNT) cacc[i] += (av[i] != 0.0f) ? 1 : 0;
#pragma unroll
        for (int j=0;j<4;j++) {
          if (MAXM) acc[i][j] = fmaxf(acc[i][j], av[i] != 0.0f ? bv[j] : NEGV);
          else      acc[i][j] = fmaf(av[i], bv[j], acc[i][j]);
        }
      }
    }
    __syncthreads();
  }

  const size_t slab = (size_t)blockIdx.z * M * 64;
#pragma unroll
  for (int i=0;i<4;i++){
    const int m = m0 + tmb + i;
    if (m < M){
#pragma unroll
      for (int j=0;j<4;j++){
        float v = acc[i][j];
        if (SELF) v = fmaxf(v, X[(size_t)m*64 + tnb + j]);
        P[slab + (size_t)m*64 + tnb + j] = v;
      }
    }
  }
  if (COUNT && tnb == 0){
#pragma unroll
    for (int i=0;i<4;i++){
      const int m = m0 + tmb + i;
      if (m < M) cntp[blockIdx.z*M + m] = cacc[i];
    }
  }
}

// slab max-reduce -> xq; XQ2 = xq@pW+pb; cntP = 1 + sum counts   (diag folded)
__global__ __launch_bounds__(256) void k_poolq(
    const float* __restrict__ SEGP,const int* __restrict__ cntp8,int Z,
    const float* __restrict__ pWp,const float* __restrict__ pbp,
    float* __restrict__ XQ2,float* __restrict__ cntP,int n)
{
  __shared__ float xq[4][65];
  const int tid = threadIdx.x;
  const int r = tid>>6, j = tid&63;
  const int i = blockIdx.x*4 + r;
  float v = NEGV;
  if (i < n){
    for(int z=0;z<Z;z++) v = fmaxf(v, SEGP[(size_t)z*n*64 + (size_t)i*64 + j]);
    if (j == 0){
      int c=1; for(int z=0;z<Z;z++) c += cntp8[z*n+i];
      cntP[i] = (float)c;
    }
  }
  xq[r][j] = v;
  __syncthreads();
  if (i < n){
    float s = pbp[j];
    for(int q=0;q<64;q++) s = fmaf(xq[r][q], pWp[q*64+j], s);
    XQ2[(size_t)i*64+j] = s;
  }
}

// fused dense gconv: reduce slabs, two 64x64 matmuls, relu, mean-accumulate.
__global__ __launch_bounds__(256) void k_gconv_fuse(
    const float* __restrict__ SEGP,const int* __restrict__ cntp8,int Z,
    const float* __restrict__ Wrel,const float* __restrict__ brel,
    const float* __restrict__ X,const float* __restrict__ Wroot,
    float* __restrict__ XN,int n,float* __restrict__ meanacc,float inv_n)
{
  __shared__ float agg_s[4][65];
  __shared__ float xrow[4][65];
  __shared__ float cnt_s[4];
  const int tid = threadIdx.x;
  const int r = tid>>6, j = tid&63;
  const int i = blockIdx.x*4 + r;
  float a = 0.0f;
  if (i < n){
    for(int z=0;z<Z;z++) a += SEGP[(size_t)z*n*64 + (size_t)i*64 + j];
    xrow[r][j] = X[(size_t)i*64 + j];
    if (j == 0){
      int c=0; for(int z=0;z<Z;z++) c += cntp8[z*n+i];
      cnt_s[r] = (float)(c>1?c:1);
    }
  }
  agg_s[r][j] = a;
  __syncthreads();
  float v = 0.0f;
  if (i < n){
    float acc=0.0f, rt=0.0f;
    for(int q=0;q<64;q++){
      acc = fmaf(agg_s[r][q], Wrel[q*64+j], acc);
      rt  = fmaf(xrow[r][q],  Wroot[q*64+j], rt);
    }
    v = fmaxf(acc/cnt_s[r] + brel[j] + rt, 0.0f);
    XN[(size_t)i*64 + j] = v;
  }
  __syncthreads();
  agg_s[r][j] = v;
  __syncthreads();
  if (r == 0) atomicAdd(&meanacc[j], (agg_s[0][j]+agg_s[1][j]+agg_s[2][j]+agg_s[3][j])*inv_n);
}

// ---------------- column softmax stats ----------------
__global__ void k_smax_part(const float* __restrict__ S,int n,int R,
                            float* __restrict__ pm,float* __restrict__ ps){
  __shared__ float red[4][64];
  int jl = threadIdx.x & 63, rg = threadIdx.x >> 6;
  int j = blockIdx.x*64 + jl;
  int rc = blockIdx.y;
  int i0 = (int)(((long long)n*rc)/R), i1 = (int)(((long long)n*(rc+1))/R);
  float m = -3.0e38f;
  if(j<n) for(int i=i0+rg;i<i1;i+=4) m = fmaxf(m, S[(size_t)i*n+j]);
  red[rg][jl]=m; __syncthreads();
  float mc = fmaxf(fmaxf(red[0][jl],red[1][jl]),fmaxf(red[2][jl],red[3][jl]));
  __syncthreads();
  float s = 0.0f;
  if(j<n) for(int i=i0+rg;i<i1;i+=4) s += expf(S[(size_t)i*n+j]-mc);
  red[rg][jl]=s; __syncthreads();
  if(rg==0 && j<n){
    pm[(size_t)rc*n+j]=mc;
    ps[(size_t)rc*n+j]=red[0][jl]+red[1][jl]+red[2][jl]+red[3][jl];
  }
}
__global__ void k_smax_merge(const float* __restrict__ pm,const float* __restrict__ ps,
                             int n,int R,float* mcol,float* invd){
  int j = blockIdx.x*256+threadIdx.x; if(j>=n) return;
  float m = -3.0e38f;
  for(int r=0;r<R;r++) m = fmaxf(m, pm[(size_t)r*n+j]);
  float d = 0.0f;
  for(int r=0;r<R;r++) d += ps[(size_t)r*n+j]*expf(pm[(size_t)r*n+j]-m);
  mcol[j]=m; invd[j]=1.0f/d;
}

// slab sum * invd -> XC; then aN/bN/cN per row; zeroes pcnt.
__global__ __launch_bounds__(256) void k_xcabc_dense(
    const float* __restrict__ SEGP,int Z,const float* __restrict__ invd,
    float* __restrict__ XC,
    const float* __restrict__ w1,const float* bb1,const float* __restrict__ w2,
    const float* __restrict__ w3,const float* bb3,
    float* aN,float* bN,float* cN,int* pcnt,int n)
{
  __shared__ float xc[4][65];
  const int tid = threadIdx.x;
  const int r = tid>>6, j = tid&63;
  const int i = blockIdx.x*4 + r;
  if (blockIdx.x==0 && tid==0) *pcnt = 0;
  float v = 0.0f;
  if (i < n){
    for(int z=0;z<Z;z++) v += SEGP[(size_t)z*n*64 + (size_t)i*64 + j];
    v *= invd[i];
    XC[(size_t)i*64+j] = v;
  }
  xc[r][j] = v;
  __syncthreads();
  if (i < n && j < 3){
    float s = (j==0)?bb1[0]:((j==2)?bb3[0]:0.0f);
    const float* w = (j==0)?w1:((j==1)?w2:w3);
    for(int q=0;q<64;q++) s = fmaf(xc[r][q], w[q], s);
    if(j==0) aN[i]=s; else if(j==1) bN[i]=s; else cN[i]=s;
  }
}

__global__ void k_aggcol(const float* __restrict__ A,const float* __restrict__ aN,
                         float* __restrict__ aggp,int n){
  int idx = blockIdx.x*256+threadIdx.x; if(idx>=n*16) return;
  int j = idx % n, c = idx / n;
  int i0 = (int)(((long long)n*c)/16), i1 = (int)(((long long)n*(c+1))/16);
  float s = 0.0f;
  for(int i=i0;i<i1;i++) if(A[(size_t)i*n + j] != 0.0f) s += aN[i];
  aggp[c*n + j] = s;
}
__global__ void k_fit_dense2(const float* __restrict__ aggp,const float* cntP,
                             const float* aN,const float* bN,const float* cN,
                             float* fit,int n){
  int v = blockIdx.x*256+threadIdx.x; if(v>=n) return;
  float a = aN[v];  // diag self term
  for(int c=0;c<16;c++) a += aggp[c*n+v];
  fit[v] = sigm(a - cntP[v]*bN[v] + cN[v]);
}

// rank + direct perm slot (perm order irrelevant downstream)
__global__ void k_rank_perm(const float* __restrict__ fit,int n,int k,int* pcnt,int* perm){
  int v = blockIdx.x*256+threadIdx.x; if(v>=n) return;
  float fv = fit[v]; int r = 0;
  for(int u=0;u<n;u++){ float fu = fit[u]; if(fu > fv || (fu == fv && u < v)) r++; }
  if (r < k){ int p = atomicAdd(pcnt,1); perm[p] = v; }
}
__global__ void k_xnew(const float* __restrict__ XC,const float* __restrict__ fit,
                       const int* __restrict__ perm,float* XN,int k){
  int idx = blockIdx.x*256+threadIdx.x; if(idx>=k*64) return;
  int u = idx >> 6, h = idx & 63; int v = perm[u];
  XN[idx] = XC[(size_t)v*64 + h]*fit[v];
}

// ---------------- prologue: degrees + CSR over L=E+n edges (incl self) ----------------
__global__ void k_deg(const int* __restrict__ src,const int* __restrict__ dst,int* indeg,int* outdeg,int E){
  int e = blockIdx.x*256+threadIdx.x; if(e>=E) return;
  atomicAdd(&indeg[dst[e]],1); atomicAdd(&outdeg[src[e]],1);
}
__global__ void k_prefix2(const int* __restrict__ indeg,const int* __restrict__ outdeg,
                          int* offD,int* curD,int* offS,int* curS,int n){
  int t = blockIdx.x*256+threadIdx.x;
  if (t <= n){
    int s=0; for(int u=0;u<t;u++) s += indeg[u]+1;
    offD[t]=s; if(t<n) curD[t]=s;
  } else {
    int t2 = t-(n+1);
    if (t2 <= n){
      int s=0; for(int u=0;u<t2;u++) s += outdeg[u]+1;
      offS[t2]=s; if(t2<n) curS[t2]=s;
    }
  }
}
__global__ void k_csr_fill2(const int* src,const int* dst,
                            int* curS,int* colS,int* eidS,
                            int* curD,int* rowD,int* eidD,int E,int n){
  int e = blockIdx.x*256+threadIdx.x; if(e>=E+n) return;
  int s,d; edge_sd(e,src,dst,E,s,d);
  int p = atomicAdd(&curS[s],1); colS[p]=d; eidS[p]=e;
  int q = atomicAdd(&curD[d],1); rowD[q]=s; eidD[q]=e;
}

__global__ void k_mm_small(const float* __restrict__ A,const float* __restrict__ W,
                           const float* __restrict__ b,float* __restrict__ C,
                           int M,int K,int Np,int act){
  int idx = blockIdx.x*256+threadIdx.x; if(idx>=M*Np) return;
  int m = idx/Np, j = idx - m*Np;
  float s = b ? b[j] : 0.0f;
  const float* a = A + (size_t)m*K;
  for(int q=0;q<K;q++) s = fmaf(a[q], W[(size_t)q*Np + j], s);
  if(act==1) s = fmaxf(s, 0.0f);
  C[idx] = s;
}

// feast: gather-mean over in-edges (incl self), +b, elu; optional mean (H==64)
__global__ void k_feast_gf(const float* __restrict__ Y,const int* __restrict__ offD,
                           const int* __restrict__ rowD,
                           const float* __restrict__ b,float* X,int n,int H,
                           float* __restrict__ meanacc,float inv_n){
  __shared__ float ms[4][64];
  int idx = blockIdx.x*256+threadIdx.x;
  float v = 0.0f;
  if(idx<n*H){
    int i = idx/H, h = idx - i*H;
    int p0 = offD[i], p1 = offD[i+1];
    float s = 0.0f;
    for(int p=p0;p<p1;p++) s += Y[(size_t)rowD[p]*H + h];
    float t = s/(float)(p1-p0) + b[h];
    v = t > 0.0f ? t : (expf(t)-1.0f);
    X[idx] = v;
  }
  if(meanacc){
    int r = threadIdx.x>>6, j = threadIdx.x&63;
    ms[r][j] = (idx<n*H) ? v : 0.0f;
    __syncthreads();
    if(r==0) atomicAdd(&meanacc[j], (ms[0][j]+ms[1][j]+ms[2][j]+ms[3][j])*inv_n);
  }
}

// fused sparse gconv: gather agg (real edges only), 2 matmuls, relu, mean.
__global__ __launch_bounds__(256) void k_gconv_sparse_f(
    const float* __restrict__ X,const int* __restrict__ offD,const int* __restrict__ rowD,
    const int* __restrict__ eidD,int E,
    const float* __restrict__ Wrel,const float* __restrict__ brel,
    const float* __restrict__ Wroot,
    float* __restrict__ XN,int n,float* __restrict__ meanacc,float inv_n)
{
  __shared__ float agg_s[4][65];
  __shared__ float xrow[4][65];
  __shared__ float cnt_s[4];
  const int tid = threadIdx.x;
  const int r = tid>>6, j = tid&63;
  const int i = blockIdx.x*4 + r;
  float a = 0.0f;
  if (i < n){
    int p0 = offD[i], p1 = offD[i+1], c = 0;
    for(int p=p0;p<p1;p++){
      if (eidD[p] < E){ a += X[(size_t)rowD[p]*64 + j]; c++; }
    }
    xrow[r][j] = X[(size_t)i*64 + j];
    if (j == 0) cnt_s[r] = (float)(c>1?c:1);
  }
  agg_s[r][j] = a;
  __syncthreads();
  float v = 0.0f;
  if (i < n){
    float acc=0.0f, rt=0.0f;
    for(int q=0;q<64;q++){
      acc = fmaf(agg_s[r][q], Wrel[q*64+j], acc);
      rt  = fmaf(xrow[r][q],  Wroot[q*64+j], rt);
    }
    v = fmaxf(acc/cnt_s[r] + brel[j] + rt, 0.0f);
    XN[(size_t)i*64 + j] = v;
  }
  __syncthreads();
  agg_s[r][j] = v;
  __syncthreads();
  if (r == 0) atomicAdd(&meanacc[j], (agg_s[0][j]+agg_s[1][j]+agg_s[2][j]+agg_s[3][j])*inv_n);
}

// pool0: xq = segmax gather (incl self) then @pW+pb
__global__ __launch_bounds__(256) void k_xqmaxq(
    const float* __restrict__ X,const int* __restrict__ offD,const int* __restrict__ rowD,
    const float* __restrict__ pWp,const float* __restrict__ pbp,
    float* __restrict__ XQ2,int n)
{
  __shared__ float xq[4][65];
  const int tid = threadIdx.x;
  const int r = tid>>6, j = tid&63;
  const int i = blockIdx.x*4 + r;
  float v = -3.0e38f;
  if (i < n){
    int p0 = offD[i], p1 = offD[i+1];
    for(int p=p0;p<p1;p++) v = fmaxf(v, X[(size_t)rowD[p]*64 + j]);
  }
  xq[r][j] = v;
  __syncthreads();
  if (i < n){
    float s = pbp[j];
    for(int q=0;q<64;q++) s = fmaf(xq[r][q], pWp[q*64+j], s);
    XQ2[(size_t)i*64+j] = s;
  }
}

__global__ void k_edge_score(const int* __restrict__ src,const int* __restrict__ dst,
                             const float* __restrict__ XQ2,const float* __restrict__ X,
                             float* sE,int E,int n){
  int e = blockIdx.x*256+threadIdx.x; if(e>=E+n) return;
  int s,d; edge_sd(e,src,dst,E,s,d);
  const float* q = XQ2 + (size_t)d*64;
  const float* x = X + (size_t)s*64;
  float acc = 0.0f;
  for(int h=0;h<64;h++) acc = fmaf(q[h], x[h], acc);
  sE[e] = acc > 0.0f ? acc : 0.2f*acc;
}

// per-dst softmax over in-edges -> scE
__global__ void k_dstsoft(const int* __restrict__ offD,const int* __restrict__ eidD,
                          const float* __restrict__ sE,float* __restrict__ scE,int n){
  int i = blockIdx.x*256+threadIdx.x; if(i>=n) return;
  int p0 = offD[i], p1 = offD[i+1];
  float m = -3.0e38f;
  for(int p=p0;p<p1;p++) m = fmaxf(m, sE[eidD[p]]);
  float d = 0.0f;
  for(int p=p0;p<p1;p++) d += expf(sE[eidD[p]]-m);
  float inv = 1.0f/d;
  for(int p=p0;p<p1;p++){ int e = eidD[p]; scE[e] = expf(sE[e]-m)*inv; }
}

// pool0: xc gather + aN/bN/cN; zeroes pcnt
__global__ __launch_bounds__(256) void k_xcabc0(
    const int* __restrict__ offD,const int* __restrict__ rowD,const int* __restrict__ eidD,
    const float* __restrict__ scE,const float* __restrict__ X,
    float* __restrict__ XC,
    const float* __restrict__ w1,const float* bb1,const float* __restrict__ w2,
    const float* __restrict__ w3,const float* bb3,
    float* aN,float* bN,float* cN,int* pcnt,int n)
{
  __shared__ float xc[4][65];
  const int tid = threadIdx.x;
  const int r = tid>>6, j = tid&63;
  const int i = blockIdx.x*4 + r;
  if (blockIdx.x==0 && tid==0) *pcnt = 0;
  float v = 0.0f;
  if (i < n){
    int p0 = offD[i], p1 = offD[i+1];
    for(int p=p0;p<p1;p++) v += scE[eidD[p]] * X[(size_t)rowD[p]*64 + j];
    XC[(size_t)i*64+j] = v;
  }
  xc[r][j] = v;
  __syncthreads();
  if (i < n && j < 3){
    float s = (j==0)?bb1[0]:((j==2)?bb3[0]:0.0f);
    const float* w = (j==0)?w1:((j==1)?w2:w3);
    for(int q=0;q<64;q++) s = fmaf(xc[r][q], w[q], s);
    if(j==0) aN[i]=s; else if(j==1) bN[i]=s; else cN[i]=s;
  }
}

__global__ void k_aggfit0(const int* __restrict__ offD,const int* __restrict__ rowD,
                          const float* aN,const float* bN,const float* cN,
                          float* fit,int n){
  int i = blockIdx.x*256+threadIdx.x; if(i>=n) return;
  int p0 = offD[i], p1 = offD[i+1];
  float s = 0.0f;
  for(int p=p0;p<p1;p++) s += aN[rowD[p]];
  fit[i] = sigm(s - (float)(p1-p0)*bN[i] + cN[i]);
}

__global__ void k_stage1n(const int* src,const int* dst,const int* __restrict__ offS,
                          const int* __restrict__ colS,const int* __restrict__ eidS,
                          const float* __restrict__ scE,
                          float* R,int E,int n){
  int e = blockIdx.x*256+threadIdx.x; if(e>=E+n) return;
  int i,j; edge_sd(e,src,dst,E,i,j);
  int p0 = offS[j], p1 = offS[j+1];
  float* Ri = R + (size_t)i*n;
  for(int p=p0;p<p1;p++) atomicAdd(&Ri[colS[p]], scE[eidS[p]]);
}
__global__ void k_stage2p(const int* __restrict__ perm,const int* __restrict__ offD,
                          const int* __restrict__ rowD,const int* __restrict__ eidD,
                          const float* __restrict__ scE,
                          const float* __restrict__ R,float* A,int k,int n){
  int idx = blockIdx.x*256+threadIdx.x; if(idx>=k*k) return;
  int u = idx/k, v = idx - u*k;
  int d = perm[u], pv = perm[v];
  float acc = 0.0f;
  int p0 = offD[d], p1 = offD[d+1];
  for(int p=p0;p<p1;p++) acc = fmaf(scE[eidD[p]], R[(size_t)rowD[p]*n + pv], acc);
  A[idx] = (u==v) ? 0.0f : acc;
}

__global__ void k_head2(const float* __restrict__ xs,const float* __restrict__ W1,
                        const float* __restrict__ b1,const float* __restrict__ W2,
                        const float* __restrict__ b2,float* out){
  __shared__ float h2[64];
  __shared__ float lg[10];
  int t = threadIdx.x;
  float s = b1[t];
  for(int q=0;q<640;q++) s = fmaf(xs[q], W1[q*64+t], s);
  h2[t] = fmaxf(s, 0.0f);
  __syncthreads();
  if(t < 10){
    float s2 = b2[t];
    for(int k=0;k<64;k++) s2 = fmaf(h2[k], W2[k*10+t], s2);
    lg[t] = s2;
  }
  __syncthreads();
  if(t == 0){
    float mx = lg[0];
    for(int i=1;i<10;i++) mx = fmaxf(mx, lg[i]);
    float se = 0.0f;
    for(int i=0;i<10;i++) se += expf(lg[i]-mx);
    float lse = mx + logf(se);
    for(int i=0;i<10;i++) out[i] = lg[i]-lse;
  }
}

// ---------------- host orchestration ----------------
extern "C" void kernel_launch(void* const* d_in, const int* in_sizes, int n_in,
                              void* d_out, int out_size, void* d_ws, size_t ws_size,
                              hipStream_t stream) {
  const int N0 = 1500, E = 24000, Z = 8, L = E + N0;
  const float* x0   = (const float*)d_in[0];
  const int* esrc   = (const int*)d_in[1];
  const int* edst   = (const int*)d_in[2];
  const float* W1   = (const float*)d_in[3];  const float* b1   = (const float*)d_in[4];
  const float* W2   = (const float*)d_in[5];  const float* b2   = (const float*)d_in[6];
  const float* W3   = (const float*)d_in[7];  const float* b3   = (const float*)d_in[8];
  const float* Wrel = (const float*)d_in[9];  const float* brel = (const float*)d_in[10];
  const float* Wroot= (const float*)d_in[11];
  const float* pW   = (const float*)d_in[12]; const float* pb   = (const float*)d_in[13];
  const float* leW1 = (const float*)d_in[14]; const float* leb1 = (const float*)d_in[15];
  const float* leW2 = (const float*)d_in[16]; const float* leW3 = (const float*)d_in[17];
  const float* leb3 = (const float*)d_in[18];
  const float* linW1= (const float*)d_in[19]; const float* linb1= (const float*)d_in[20];
  const float* linW2= (const float*)d_in[21]; const float* linb2= (const float*)d_in[22];
  float* out = (float*)d_out;

  float* ws = (float*)d_ws;
  size_t cur = 0;
  auto allocF = [&](size_t nf)->float*{ float* p = ws + cur; cur += (nf + 15) & ~(size_t)15; return p; };
  // contiguous zero block: xs | indeg | outdeg
  float* xs   = allocF(640);
  int* indeg  = (int*)allocF(1504);
  int* outdeg = (int*)allocF(1504);
  float* Xa  = allocF(96000); float* Xb  = allocF(96000); float* Y   = allocF(96000);
  float* XQ2 = allocF(96000); float* XC  = allocF(96000);
  float* mcol = allocF(1504); float* invd = allocF(1504);
  float* aN = allocF(1504); float* bN = allocF(1504); float* cN = allocF(1504);
  float* fit = allocF(1504); float* cntP = allocF(1504);
  int* pcnt = (int*)allocF(16);
  int* perm = (int*)allocF(1504);
  int* offD = (int*)allocF(1504); int* offS = (int*)allocF(1504);
  int* curD = (int*)allocF(1504); int* curS = (int*)allocF(1504);
  int* colS = (int*)allocF(25504); int* eidS = (int*)allocF(25504);
  int* rowD = (int*)allocF(25504); int* eidD = (int*)allocF(25504);
  float* sE = allocF(25504); float* scE = allocF(25504);
  float* pm = allocF(8*1504); float* ps = allocF(8*1504);
  int* cntp8 = (int*)allocF(8*1504);
  float* aggp = allocF(16*1504);
  float* SEGP = allocF((size_t)Z*1504*64);
  float* Rbig = allocF((size_t)1500*1500);   // pool0 R; aliased as SCb afterwards
  float* SCb  = Rbig;
  float* A0  = allocF((size_t)1350*1350);
  float* A1s = allocF((size_t)1350*1350);
  const size_t BFSZ = (size_t)1350*4224/2 + 32;
  ushort* Abf = (ushort*)allocF(BFSZ);
  ushort* Bbf = (ushort*)allocF(BFSZ);
  ushort* Cbf = (ushort*)allocF(BFSZ);
  ushort* Dbf = (ushort*)allocF(BFSZ);

  dim3 B256(256);
  auto G1 = [&](size_t n){ return dim3((unsigned)((n + 255) / 256)); };
  auto ZF = [&](void* p, size_t nfloats){ k_zero<<<G1(nfloats),B256,0,stream>>>((float*)p, nfloats); };
  auto kc8 = [&](int K){ return (int)(((K + Z*16 - 1) / (Z*16)) * 16); };

  // ---- prologue: zero (xs+indeg+outdeg contiguous), degrees, CSR ----
  ZF(xs, 640 + 1504 + 1504);
  k_deg<<<G1(E),B256,0,stream>>>(esrc, edst, indeg, outdeg, E);
  k_prefix2<<<G1(2*(N0+1)),B256,0,stream>>>(indeg, outdeg, offD, curD, offS, curS, N0);
  k_csr_fill2<<<G1(L),B256,0,stream>>>(esrc, edst, curS, colS, eidS, curD, rowD, eidD, E, N0);

  // ---- FEAST x3 (2 nodes each) ----
  auto feast = [&](const float* xin,int cin,const float* W,const float* bb,int hh,float* xout,float* macc){
    k_mm_small<<<G1((size_t)N0*hh),B256,0,stream>>>(xin, W, nullptr, Y, N0, cin, hh, 0);
    k_feast_gf<<<G1((size_t)N0*hh),B256,0,stream>>>(Y, offD, rowD, bb, xout, N0, hh, macc, 1.0f/N0);
  };
  feast(x0, 16, W1, b1, 32, Xa, nullptr);
  feast(Xa, 32, W2, b2, 64, Xb, nullptr);
  feast(Xb, 64, W3, b3, 64, Xa, xs + 0);
  float* X = Xa; float* XN = Xb;

  // ---- i=0 gconv_sparse (1 node) ----
  k_gconv_sparse_f<<<dim3((N0+3)/4),B256,0,stream>>>(X, offD, rowD, eidD, E, Wrel, brel, Wroot,
                                                     XN, N0, xs + 64, 1.0f/N0);
  { float* t = X; X = XN; XN = t; }

  // ---- pool 0 (sparse ASAP), n=1500 -> k=1350 (10 nodes) ----
  {
    const int n = 1500, kk = 1350;
    k_xqmaxq<<<dim3((n+3)/4),B256,0,stream>>>(X, offD, rowD, pW, pb, XQ2, n);
    k_edge_score<<<G1(L),B256,0,stream>>>(esrc, edst, XQ2, X, sE, E, n);
    k_dstsoft<<<G1(n),B256,0,stream>>>(offD, eidD, sE, scE, n);
    k_xcabc0<<<dim3((n+3)/4),B256,0,stream>>>(offD, rowD, eidD, scE, X, XC,
                                              leW1, leb1, leW2, leW3, leb3, aN, bN, cN, pcnt, n);
    k_aggfit0<<<G1(n),B256,0,stream>>>(offD, rowD, aN, bN, cN, fit, n);
    k_rank_perm<<<G1(n),B256,0,stream>>>(fit, n, kk, pcnt, perm);
    k_xnew<<<G1((size_t)kk*64),B256,0,stream>>>(XC, fit, perm, XN, kk);
    ZF(Rbig, (size_t)n*n);
    k_stage1n<<<G1(L),B256,0,stream>>>(esrc, edst, offS, colS, eidS, scE, Rbig, E, n);
    k_stage2p<<<G1((size_t)kk*kk),B256,0,stream>>>(perm, offD, rowD, eidD, scE, Rbig, A0, kk, n);
    { float* t = X; X = XN; XN = t; }
  }

  float* Acur = A0; float* Aoth = A1s;
  int nn = 1350;

  // ---- dense gconv (2 nodes) ----
  auto gconv_dense = [&](int layer){
    dim3 g(1, (nn+63)/64, Z);
    k_skinny<false,true,false,false><<<g,B256,0,stream>>>(Acur, nn, X, nullptr, SEGP, cntp8, nn, nn, kc8(nn));
    k_gconv_fuse<<<dim3((nn+3)/4),B256,0,stream>>>(SEGP, cntp8, Z,
        Wrel + (size_t)layer*4096, brel + layer*64, X, Wroot + (size_t)layer*4096,
        XN, nn, xs + (size_t)(layer+1)*64, 1.0f/nn);
    { float* t = X; X = XN; XN = t; }
  };

  // ---- dense ASAP pool (16 nodes; diagfix folded algebraically) ----
  auto asap_dense = [&](int kk, int p){
    {
      dim3 g(1, (nn+63)/64, Z);
      k_skinny<true,true,false,true><<<g,B256,0,stream>>>(Acur, nn, X, nullptr, SEGP, cntp8, nn, nn, kc8(nn));
    }
    k_poolq<<<dim3((nn+3)/4),B256,0,stream>>>(SEGP, cntp8, Z, pW + (size_t)p*4096, pb + p*64, XQ2, cntP, nn);
    k_split3_dual<<<G1((size_t)nn*64),B256,0,stream>>>(X, XQ2, nn, Abf, Bbf);
    {
      dim3 g((nn+63)/64, (nn+63)/64);
      k_gemm_mfma<1><<<g,B256,0,stream>>>(Abf, Bbf, SCb, nn, nn, nn, 192, Acur, nn);
    }
    {
      dim3 g1((nn+63)/64, 8);
      k_smax_part<<<g1,B256,0,stream>>>(SCb, nn, 8, pm, ps);
      k_smax_merge<<<G1(nn),B256,0,stream>>>(pm, ps, nn, 8, mcol, invd);
    }
    {
      dim3 g(1, (nn+63)/64, Z);
      k_skinny<false,false,true,false><<<g,B256,0,stream>>>(SCb, nn, X, mcol, SEGP, nullptr, nn, nn, kc8(nn));
    }
    k_xcabc_dense<<<dim3((nn+3)/4),B256,0,stream>>>(SEGP, Z, invd, XC,
        leW1 + p*64, leb1 + p, leW2 + p*64, leW3 + p*64, leb3 + p, aN, bN, cN, pcnt, nn);
    k_aggcol<<<G1((size_t)nn*16),B256,0,stream>>>(Acur, aN, aggp, nn);
    k_fit_dense2<<<G1(nn),B256,0,stream>>>(aggp, cntP, aN, bN, cN, fit, nn);
    k_rank_perm<<<G1(nn),B256,0,stream>>>(fit, nn, kk, pcnt, perm);
    k_xnew<<<G1((size_t)kk*64),B256,0,stream>>>(XC, fit, perm, XN, kk);
    const int Kp = (nn + 63) & ~63;
    const int K3 = 3*Kp;
    k_split3<<<G1((size_t)nn*Kp),B256,0,stream>>>(Acur, nn, nn, nn, Abf, Kp, 0);
    { dim3 gt((kk+31)/32, Kp/32);
      k_split3_Tdual<<<gt,B256,0,stream>>>(SCb, nn, kk, nn, perm, invd, mcol, Dbf, Bbf, Cbf, Kp); }
    { dim3 g((kk+63)/64, (nn+63)/64);
      k_gemm_mfma_tb<<<g,B256,0,stream>>>(Abf, Bbf, SCb, nn, perm, mcol, invd, Cbf, Kp, nn, kk, K3); }
    { dim3 g((kk+63)/64, (kk+63)/64);
      k_gemm_mfma<2><<<g,B256,0,stream>>>(Dbf, Cbf, Aoth, kk, kk, kk, K3, nullptr, 0); }
    { float* t = X; X = XN; XN = t; }
    { float* t = Acur; Acur = Aoth; Aoth = t; }
    nn = kk;
  };

  gconv_dense(1);
  gconv_dense(2);
  asap_dense(1215, 1);
  gconv_dense(3);
  gconv_dense(4);
  asap_dense(1094, 2);
  gconv_dense(5);
  gconv_dense(6);
  asap_dense(985, 3);
  gconv_dense(7);
  gconv_dense(8);

  // ---- head (1 node) ----
  k_head2<<<1,64,0,stream>>>(xs, linW1, linb1, linW2, linb2, out);
}

// Round 7
// 1631.517 us; speedup vs baseline: 2.5301x; 1.0534x over previous
//
#include <hip/hip_runtime.h>
#include <math.h>

#define NEGV -1000000000.0f

typedef short short8 __attribute__((ext_vector_type(8)));
typedef float floatx4 __attribute__((ext_vector_type(4)));

__device__ __forceinline__ float sigm(float x){ return 1.0f/(1.0f+expf(-x)); }
__device__ __forceinline__ void edge_sd(int e,const int* src,const int* dst,int E,int& s,int& d){
  if(e<E){ s=src[e]; d=dst[e]; } else { s=e-E; d=s; }
}
__device__ __forceinline__ ushort bf16rn(float x){
  unsigned u = __float_as_uint(x);
  unsigned r = (u + 0x7fffu + ((u>>16)&1u)) >> 16;
  return (ushort)r;
}
__device__ __forceinline__ float bf16f(ushort h){ return __uint_as_float(((unsigned)h)<<16); }

__global__ void k_zero(float* __restrict__ p, size_t n){
  size_t i = (size_t)blockIdx.x*256 + threadIdx.x;
  if (i < n) p[i] = 0.0f;
}

// ---------------- bf16x3 conversions ----------------
__global__ void k_split3(const float* __restrict__ src,int R,int Cs,int ld,
                         ushort* __restrict__ dst,int Cp,int bmode){
  int idx = blockIdx.x*256+threadIdx.x;
  if (idx >= R*Cp) return;
  int r = idx / Cp, c = idx - r*Cp;
  float x = (c < Cs) ? src[(size_t)r*ld + c] : 0.0f;
  ushort h = bf16rn(x);
  ushort l = bf16rn(x - bf16f(h));
  size_t base = (size_t)r*(3*Cp) + c;
  dst[base]        = h;
  dst[base + Cp]   = bmode ? l : h;
  dst[base + 2*Cp] = bmode ? h : l;
}
__global__ void k_split3_dual(const float* __restrict__ Xsrc,const float* __restrict__ Qsrc,
                              int R,ushort* __restrict__ dstA,ushort* __restrict__ dstB){
  int idx = blockIdx.x*256+threadIdx.x;
  if (idx >= R*64) return;
  int r = idx >> 6, c = idx & 63;
  size_t base = (size_t)r*192 + c;
  float x = Xsrc[idx];
  ushort h = bf16rn(x), l = bf16rn(x - bf16f(h));
  dstA[base] = h; dstA[base+64] = h; dstA[base+128] = l;
  float q = Qsrc[idx];
  h = bf16rn(q); l = bf16rn(q - bf16f(h));
  dstB[base] = h; dstB[base+64] = l; dstB[base+128] = h;
}
// Sp = exp(src[:,perm]-mcol[perm])*invd[perm], transposed to K-innermost; writes BOTH
// A-role (dstA) and B-role (dstB); zero-pads k>=Rs rows in dstA/dstB AND dstCpad.
__global__ void k_split3_Tdual(const float* __restrict__ src,int Rs,int Cs,int ld,
                               const int* __restrict__ gperm,const float* __restrict__ cscale,
                               const float* __restrict__ emax,
                               ushort* __restrict__ dstA,ushort* __restrict__ dstB,
                               ushort* __restrict__ dstCpad,int Kp){
  __shared__ float t[32][33];
  int tx = threadIdx.x & 31, ty = threadIdx.x >> 5;
  int kb = blockIdx.y*32, xb = blockIdx.x*32;
  int x = xb + tx;
  int gx = (x < Cs) ? gperm[x] : 0;
#pragma unroll
  for (int i=0;i<4;i++){
    int k = kb + ty + i*8;
    t[ty+i*8][tx] = (k < Rs && x < Cs) ? src[(size_t)k*ld + gx] : 0.0f;
  }
  __syncthreads();
  const int K3 = 3*Kp;
#pragma unroll
  for (int i=0;i<4;i++){
    int xo = xb + ty + i*8, ko = kb + tx;
    if (xo < Cs){
      float v = 0.0f;
      if (ko < Rs){
        int g = gperm[xo];
        v = expf(t[tx][ty+i*8] - emax[g]) * cscale[g];
      }
      ushort h = bf16rn(v);
      ushort l = bf16rn(v - bf16f(h));
      size_t base = (size_t)xo*K3 + ko;
      dstA[base] = h; dstA[base+Kp] = h; dstA[base+2*Kp] = l;
      dstB[base] = h; dstB[base+Kp] = l; dstB[base+2*Kp] = h;
      if (ko >= Rs){ dstCpad[base]=0; dstCpad[base+Kp]=0; dstCpad[base+2*Kp]=0; }
    }
  }
}

// ---------------- MFMA bf16 GEMM (64x64 tile, K-step 64) ----------------
// EPI 1: mask(A+I)+leakyrelu; EPI 2: zero diag.
template<int EPI>
__global__ __launch_bounds__(256) void k_gemm_mfma(
    const ushort* __restrict__ A, const ushort* __restrict__ B,
    float* __restrict__ C, int ldc, int M, int N, int K3,
    const float* __restrict__ mask, int ldm)
{
  __shared__ ushort As[64][72];
  __shared__ ushort Bs[64][72];
  const int tid = threadIdx.x;
  const int m0 = blockIdx.y*64, n0 = blockIdx.x*64;
  const int w = tid>>6, lane = tid&63;
  const int lo4 = lane&15, quad = lane>>4;
  const int sr = tid>>2, sseg = tid&3;

  floatx4 acc[4];
#pragma unroll
  for(int c=0;c<4;c++){ acc[c][0]=0.f; acc[c][1]=0.f; acc[c][2]=0.f; acc[c][3]=0.f; }

  const size_t arow = (size_t)(m0+sr)*K3;
  const size_t brow = (size_t)(n0+sr)*K3;
  const bool aval = (m0+sr) < M;
  const bool bval = (n0+sr) < N;

  for (int k0 = 0; k0 < K3; k0 += 64) {
    uint4 av0 = make_uint4(0,0,0,0), av1 = make_uint4(0,0,0,0);
    uint4 bv0 = make_uint4(0,0,0,0), bv1 = make_uint4(0,0,0,0);
    if (aval){ av0 = *(const uint4*)(A + arow + k0 + sseg*8);
               av1 = *(const uint4*)(A + arow + k0 + 32 + sseg*8); }
    if (bval){ bv0 = *(const uint4*)(B + brow + k0 + sseg*8);
               bv1 = *(const uint4*)(B + brow + k0 + 32 + sseg*8); }
    __syncthreads();
    *(uint4*)&As[sr][sseg*8] = av0; *(uint4*)&As[sr][32+sseg*8] = av1;
    *(uint4*)&Bs[sr][sseg*8] = bv0; *(uint4*)&Bs[sr][32+sseg*8] = bv1;
    __syncthreads();
    short8 af0 = *(const short8*)&As[16*w + lo4][quad*8];
    short8 af1 = *(const short8*)&As[16*w + lo4][32+quad*8];
#pragma unroll
    for (int c=0;c<4;c++){
      short8 bf0 = *(const short8*)&Bs[16*c + lo4][quad*8];
      acc[c] = __builtin_amdgcn_mfma_f32_16x16x32_bf16(af0, bf0, acc[c], 0, 0, 0);
      short8 bf1 = *(const short8*)&Bs[16*c + lo4][32+quad*8];
      acc[c] = __builtin_amdgcn_mfma_f32_16x16x32_bf16(af1, bf1, acc[c], 0, 0, 0);
    }
  }

#pragma unroll
  for (int c=0;c<4;c++){
    const int gn = n0 + 16*c + lo4;
#pragma unroll
    for (int r=0;r<4;r++){
      const int gm = m0 + 16*w + quad*4 + r;
      if (gm < M && gn < N){
        float v = acc[c][r];
        if (EPI==1) v = (mask[(size_t)gm*ldm+gn] != 0.0f || gm==gn) ? (v > 0.0f ? v : 0.2f*v) : NEGV;
        if (EPI==2 && gm==gn) v = 0.0f;
        C[(size_t)gm*ldc+gn] = v;
      }
    }
  }
}

// TB = A@Sp + Sp (fp32 acc), written directly as bf16x3 B-role TRANSPOSED:
// Cb[row=gn][k=gm] with [h,l,h] segments. Sp recomputed fp32 from SC in epilogue.
__global__ __launch_bounds__(256) void k_gemm_mfma_tb(
    const ushort* __restrict__ A, const ushort* __restrict__ B,
    const float* __restrict__ SC, int ldm,
    const int* __restrict__ perm, const float* __restrict__ mcol, const float* __restrict__ invd,
    ushort* __restrict__ Cb, int Kp, int M, int N, int K3)
{
  __shared__ ushort As[64][72];
  __shared__ ushort Bs[64][72];
  const int tid = threadIdx.x;
  const int m0 = blockIdx.y*64, n0 = blockIdx.x*64;
  const int w = tid>>6, lane = tid&63;
  const int lo4 = lane&15, quad = lane>>4;
  const int sr = tid>>2, sseg = tid&3;

  floatx4 acc[4];
#pragma unroll
  for(int c=0;c<4;c++){ acc[c][0]=0.f; acc[c][1]=0.f; acc[c][2]=0.f; acc[c][3]=0.f; }

  const size_t arow = (size_t)(m0+sr)*K3;
  const size_t brow = (size_t)(n0+sr)*K3;
  const bool aval = (m0+sr) < M;
  const bool bval = (n0+sr) < N;

  for (int k0 = 0; k0 < K3; k0 += 64) {
    uint4 av0 = make_uint4(0,0,0,0), av1 = make_uint4(0,0,0,0);
    uint4 bv0 = make_uint4(0,0,0,0), bv1 = make_uint4(0,0,0,0);
    if (aval){ av0 = *(const uint4*)(A + arow + k0 + sseg*8);
               av1 = *(const uint4*)(A + arow + k0 + 32 + sseg*8); }
    if (bval){ bv0 = *(const uint4*)(B + brow + k0 + sseg*8);
               bv1 = *(const uint4*)(B + brow + k0 + 32 + sseg*8); }
    __syncthreads();
    *(uint4*)&As[sr][sseg*8] = av0; *(uint4*)&As[sr][32+sseg*8] = av1;
    *(uint4*)&Bs[sr][sseg*8] = bv0; *(uint4*)&Bs[sr][32+sseg*8] = bv1;
    __syncthreads();
    short8 af0 = *(const short8*)&As[16*w + lo4][quad*8];
    short8 af1 = *(const short8*)&As[16*w + lo4][32+quad*8];
#pragma unroll
    for (int c=0;c<4;c++){
      short8 bf0 = *(const short8*)&Bs[16*c + lo4][quad*8];
      acc[c] = __builtin_amdgcn_mfma_f32_16x16x32_bf16(af0, bf0, acc[c], 0, 0, 0);
      short8 bf1 = *(const short8*)&Bs[16*c + lo4][32+quad*8];
      acc[c] = __builtin_amdgcn_mfma_f32_16x16x32_bf16(af1, bf1, acc[c], 0, 0, 0);
    }
  }

  const int K3o = 3*Kp;
#pragma unroll
  for (int c=0;c<4;c++){
    const int gn = n0 + 16*c + lo4;
    if (gn < N){
      const int pg = perm[gn];
      const float mv = mcol[pg], iv = invd[pg];
#pragma unroll
      for (int r=0;r<4;r++){
        const int gm = m0 + 16*w + quad*4 + r;
        if (gm < M){
          float v = acc[c][r] + expf(SC[(size_t)gm*ldm+pg]-mv)*iv;
          ushort h = bf16rn(v);
          ushort l = bf16rn(v - bf16f(h));
          size_t base = (size_t)gn*K3o + gm;
          Cb[base] = h; Cb[base+Kp] = l; Cb[base+2*Kp] = h;
        }
      }
    }
  }
}

// ---------------- atomic-free skinny agg GEMM ----------------
// SELF: fold +I (self row max). EXPM: exp(A - mcol[m]).
template<bool MAXM, bool COUNT, bool EXPM, bool SELF>
__global__ __launch_bounds__(256) void k_skinny(
    const float* __restrict__ A, int lda,
    const float* __restrict__ X,
    const float* __restrict__ mcol,
    float* __restrict__ P, int* __restrict__ cntp,
    int M, int K, int kchunk)
{
  __shared__ float As[16][68];
  __shared__ float Xs[16][68];
  const int tid = threadIdx.x;
  const int m0 = blockIdx.y * 64;
  const int tmb = (tid & 15) * 4, tnb = (tid >> 4) * 4;
  float acc[4][4];
  int cacc[4] = {0,0,0,0};
#pragma unroll
  for (int i=0;i<4;i++)
#pragma unroll
    for (int j=0;j<4;j++) acc[i][j] = MAXM ? NEGV : 0.0f;

  const int kstart = blockIdx.z * kchunk;
  int kend = kstart + kchunk; if (kend > K) kend = K;
  const int ml = tid & 63, tb = tid >> 6;
  const bool mvalid = (m0 + ml) < M;
  float mc = 0.0f;
  if (EXPM && mvalid) mc = mcol[m0 + ml];

  for (int k0 = kstart; k0 < kend; k0 += 16) {
#pragma unroll
    for (int s=0;s<4;s++) {
      const int tk = tb + s*4;
      float va = 0.0f, vx = 0.0f;
      if ((k0+tk) < K) {
        if (mvalid){
          va = A[(size_t)(k0+tk)*lda + m0 + ml];
          if (EXPM) va = expf(va - mc);
        }
        vx = X[(size_t)(k0+tk)*64 + ml];
      }
      As[tk][ml] = va;
      Xs[tk][ml] = vx;
    }
    __syncthreads();
#pragma unroll
    for (int kk=0; kk<16; kk++) {
      const float4 a4 = *(const float4*)&As[kk][tmb];
      const float4 b4 = *(const float4*)&Xs[kk][tnb];
      const float av[4] = {a4.x,a4.y,a4.z,a4.w};
      const float bv[4] = {b4.x,b4.y,b4.z,b4.w};
#pragma unroll
      for (int i=0;i<4;i++){
        if (COUNT) cacc[i] += (av[i] != 0.0f) ? 1 : 0;
#pragma unroll
        for (int j=0;j<4;j++) {
          if (MAXM) acc[i][j] = fmaxf(acc[i][j], av[i] != 0.0f ? bv[j] : NEGV);
          else      acc[i][j] = fmaf(av[i], bv[j], acc[i][j]);
        }
      }
    }
    __syncthreads();
  }

  const size_t slab = (size_t)blockIdx.z * M * 64;
#pragma unroll
  for (int i=0;i<4;i++){
    const int m = m0 + tmb + i;
    if (m < M){
#pragma unroll
      for (int j=0;j<4;j++){
        float v = acc[i][j];
        if (SELF) v = fmaxf(v, X[(size_t)m*64 + tnb + j]);
        P[slab + (size_t)m*64 + tnb + j] = v;
      }
    }
  }
  if (COUNT && tnb == 0){
#pragma unroll
    for (int i=0;i<4;i++){
      const int m = m0 + tmb + i;
      if (m < M) cntp[blockIdx.z*M + m] = cacc[i];
    }
  }
}

// slab max-reduce -> xq; XQ2 = xq@pW+pb; cntP = 1 + sum counts   (diag folded)
__global__ __launch_bounds__(256) void k_poolq(
    const float* __restrict__ SEGP,const int* __restrict__ cntp8,int Z,
    const float* __restrict__ pWp,const float* __restrict__ pbp,
    float* __restrict__ XQ2,float* __restrict__ cntP,int n)
{
  __shared__ float xq[4][65];
  const int tid = threadIdx.x;
  const int r = tid>>6, j = tid&63;
  const int i = blockIdx.x*4 + r;
  float v = NEGV;
  if (i < n){
    for(int z=0;z<Z;z++) v = fmaxf(v, SEGP[(size_t)z*n*64 + (size_t)i*64 + j]);
    if (j == 0){
      int c=1; for(int z=0;z<Z;z++) c += cntp8[z*n+i];
      cntP[i] = (float)c;
    }
  }
  xq[r][j] = v;
  __syncthreads();
  if (i < n){
    float s = pbp[j];
    for(int q=0;q<64;q++) s = fmaf(xq[r][q], pWp[q*64+j], s);
    XQ2[(size_t)i*64+j] = s;
  }
}

// fused dense gconv: reduce slabs, two 64x64 matmuls, relu, mean-accumulate.
__global__ __launch_bounds__(256) void k_gconv_fuse(
    const float* __restrict__ SEGP,const int* __restrict__ cntp8,int Z,
    const float* __restrict__ Wrel,const float* __restrict__ brel,
    const float* __restrict__ X,const float* __restrict__ Wroot,
    float* __restrict__ XN,int n,float* __restrict__ meanacc,float inv_n)
{
  __shared__ float agg_s[4][65];
  __shared__ float xrow[4][65];
  __shared__ float cnt_s[4];
  const int tid = threadIdx.x;
  const int r = tid>>6, j = tid&63;
  const int i = blockIdx.x*4 + r;
  float a = 0.0f;
  if (i < n){
    for(int z=0;z<Z;z++) a += SEGP[(size_t)z*n*64 + (size_t)i*64 + j];
    xrow[r][j] = X[(size_t)i*64 + j];
    if (j == 0){
      int c=0; for(int z=0;z<Z;z++) c += cntp8[z*n+i];
      cnt_s[r] = (float)(c>1?c:1);
    }
  }
  agg_s[r][j] = a;
  __syncthreads();
  float v = 0.0f;
  if (i < n){
    float acc=0.0f, rt=0.0f;
    for(int q=0;q<64;q++){
      acc = fmaf(agg_s[r][q], Wrel[q*64+j], acc);
      rt  = fmaf(xrow[r][q],  Wroot[q*64+j], rt);
    }
    v = fmaxf(acc/cnt_s[r] + brel[j] + rt, 0.0f);
    XN[(size_t)i*64 + j] = v;
  }
  __syncthreads();
  agg_s[r][j] = v;
  __syncthreads();
  if (r == 0) atomicAdd(&meanacc[j], (agg_s[0][j]+agg_s[1][j]+agg_s[2][j]+agg_s[3][j])*inv_n);
}

// ---------------- fused column softmax stats (ONE kernel) ----------------
// block = 16 columns x 16 rowgroups over all rows
__global__ __launch_bounds__(256) void k_smax_fused(const float* __restrict__ S,int n,
                                                    float* __restrict__ mcol,float* __restrict__ invd){
  __shared__ float red[16][17];
  const int jc = threadIdx.x & 15, rg = threadIdx.x >> 4;
  const int j = blockIdx.x*16 + jc;
  float m = -3.0e38f;
  if (j < n)
    for(int i=rg;i<n;i+=16) m = fmaxf(m, S[(size_t)i*n+j]);
  red[rg][jc] = m;
  __syncthreads();
  for(int s=8;s>0;s>>=1){
    if(rg<s) red[rg][jc] = fmaxf(red[rg][jc], red[rg+s][jc]);
    __syncthreads();
  }
  const float mc = red[0][jc];
  __syncthreads();
  float sum = 0.0f;
  if (j < n)
    for(int i=rg;i<n;i+=16) sum += expf(S[(size_t)i*n+j]-mc);
  red[rg][jc] = sum;
  __syncthreads();
  for(int s=8;s>0;s>>=1){
    if(rg<s) red[rg][jc] += red[rg+s][jc];
    __syncthreads();
  }
  if(rg==0 && j<n){ mcol[j]=mc; invd[j]=1.0f/red[0][jc]; }
}

// slab sum * invd -> XC; then aN/bN/cN per row; zeroes pcnt.
__global__ __launch_bounds__(256) void k_xcabc_dense(
    const float* __restrict__ SEGP,int Z,const float* __restrict__ invd,
    float* __restrict__ XC,
    const float* __restrict__ w1,const float* bb1,const float* __restrict__ w2,
    const float* __restrict__ w3,const float* bb3,
    float* aN,float* bN,float* cN,int* pcnt,int n)
{
  __shared__ float xc[4][65];
  const int tid = threadIdx.x;
  const int r = tid>>6, j = tid&63;
  const int i = blockIdx.x*4 + r;
  if (blockIdx.x==0 && tid==0) *pcnt = 0;
  float v = 0.0f;
  if (i < n){
    for(int z=0;z<Z;z++) v += SEGP[(size_t)z*n*64 + (size_t)i*64 + j];
    v *= invd[i];
    XC[(size_t)i*64+j] = v;
  }
  xc[r][j] = v;
  __syncthreads();
  if (i < n && j < 3){
    float s = (j==0)?bb1[0]:((j==2)?bb3[0]:0.0f);
    const float* w = (j==0)?w1:((j==1)?w2:w3);
    for(int q=0;q<64;q++) s = fmaf(xc[r][q], w[q], s);
    if(j==0) aN[i]=s; else if(j==1) bN[i]=s; else cN[i]=s;
  }
}

__global__ void k_aggcol(const float* __restrict__ A,const float* __restrict__ aN,
                         float* __restrict__ aggp,int n){
  int idx = blockIdx.x*256+threadIdx.x; if(idx>=n*16) return;
  int j = idx % n, c = idx / n;
  int i0 = (int)(((long long)n*c)/16), i1 = (int)(((long long)n*(c+1))/16);
  float s = 0.0f;
  for(int i=i0;i<i1;i++) if(A[(size_t)i*n + j] != 0.0f) s += aN[i];
  aggp[c*n + j] = s;
}
__global__ void k_fit_dense2(const float* __restrict__ aggp,const float* cntP,
                             const float* aN,const float* bN,const float* cN,
                             float* fit,int n){
  int v = blockIdx.x*256+threadIdx.x; if(v>=n) return;
  float a = aN[v];  // diag self term
  for(int c=0;c<16;c++) a += aggp[c*n+v];
  fit[v] = sigm(a - cntP[v]*bN[v] + cN[v]);
}

// rank + direct perm slot — fit staged in LDS (broadcast reads are free)
__global__ __launch_bounds__(256) void k_rank_perm(const float* __restrict__ fit,int n,int k,
                                                   int* pcnt,int* perm){
  __shared__ float fs[1504];
  const int tid = threadIdx.x;
  for(int u=tid; u<n; u+=256) fs[u] = fit[u];
  __syncthreads();
  const int v = blockIdx.x*256+tid; if(v>=n) return;
  const float fv = fs[v]; int r = 0;
  for(int u=0;u<n;u++){ float fu = fs[u]; r += (fu > fv || (fu == fv && u < v)) ? 1 : 0; }
  if (r < k){ int p = atomicAdd(pcnt,1); perm[p] = v; }
}
__global__ void k_xnew(const float* __restrict__ XC,const float* __restrict__ fit,
                       const int* __restrict__ perm,float* XN,int k){
  int idx = blockIdx.x*256+threadIdx.x; if(idx>=k*64) return;
  int u = idx >> 6, h = idx & 63; int v = perm[u];
  XN[idx] = XC[(size_t)v*64 + h]*fit[v];
}

// ---------------- prologue: degrees + CSR over L=E+n edges (incl self) ----------------
__global__ void k_deg(const int* __restrict__ src,const int* __restrict__ dst,int* indeg,int* outdeg,int E){
  int e = blockIdx.x*256+threadIdx.x; if(e>=E) return;
  atomicAdd(&indeg[dst[e]],1); atomicAdd(&outdeg[src[e]],1);
}
// grid (6,2): y=0 -> indeg/offD, y=1 -> outdeg/offS; deg staged in LDS.
__global__ __launch_bounds__(256) void k_prefix2(const int* __restrict__ indeg,const int* __restrict__ outdeg,
                          int* offD,int* curD,int* offS,int* curS,int n){
  __shared__ int ds[1504];
  const int* dsrc = blockIdx.y ? outdeg : indeg;
  for(int u=threadIdx.x; u<n; u+=256) ds[u] = dsrc[u];
  __syncthreads();
  int t = blockIdx.x*256+threadIdx.x; if(t>n) return;
  int s = 0;
  for(int u=0;u<t;u++) s += ds[u]+1;
  if (blockIdx.y){ offS[t]=s; if(t<n) curS[t]=s; }
  else           { offD[t]=s; if(t<n) curD[t]=s; }
}
__global__ void k_csr_fill2(const int* src,const int* dst,
                            int* curS,int* colS,int* eidS,
                            int* curD,int* rowD,int* eidD,int E,int n){
  int e = blockIdx.x*256+threadIdx.x; if(e>=E+n) return;
  int s,d; edge_sd(e,src,dst,E,s,d);
  int p = atomicAdd(&curS[s],1); colS[p]=d; eidS[p]=e;
  int q = atomicAdd(&curD[d],1); rowD[q]=s; eidD[q]=e;
}

__global__ void k_mm_small(const float* __restrict__ A,const float* __restrict__ W,
                           const float* __restrict__ b,float* __restrict__ C,
                           int M,int K,int Np,int act){
  int idx = blockIdx.x*256+threadIdx.x; if(idx>=M*Np) return;
  int m = idx/Np, j = idx - m*Np;
  float s = b ? b[j] : 0.0f;
  const float* a = A + (size_t)m*K;
  for(int q=0;q<K;q++) s = fmaf(a[q], W[(size_t)q*Np + j], s);
  if(act==1) s = fmaxf(s, 0.0f);
  C[idx] = s;
}

// feast: gather-mean over in-edges (incl self), +b, elu; optional mean (H==64)
__global__ void k_feast_gf(const float* __restrict__ Y,const int* __restrict__ offD,
                           const int* __restrict__ rowD,
                           const float* __restrict__ b,float* X,int n,int H,
                           float* __restrict__ meanacc,float inv_n){
  __shared__ float ms[4][64];
  int idx = blockIdx.x*256+threadIdx.x;
  float v = 0.0f;
  if(idx<n*H){
    int i = idx/H, h = idx - i*H;
    int p0 = offD[i], p1 = offD[i+1];
    float s = 0.0f;
    for(int p=p0;p<p1;p++) s += Y[(size_t)rowD[p]*H + h];
    float t = s/(float)(p1-p0) + b[h];
    v = t > 0.0f ? t : (expf(t)-1.0f);
    X[idx] = v;
  }
  if(meanacc){
    int r = threadIdx.x>>6, j = threadIdx.x&63;
    ms[r][j] = (idx<n*H) ? v : 0.0f;
    __syncthreads();
    if(r==0) atomicAdd(&meanacc[j], (ms[0][j]+ms[1][j]+ms[2][j]+ms[3][j])*inv_n);
  }
}

// fused sparse gconv: gather agg (real edges only), 2 matmuls, relu, mean.
__global__ __launch_bounds__(256) void k_gconv_sparse_f(
    const float* __restrict__ X,const int* __restrict__ offD,const int* __restrict__ rowD,
    const int* __restrict__ eidD,int E,
    const float* __restrict__ Wrel,const float* __restrict__ brel,
    const float* __restrict__ Wroot,
    float* __restrict__ XN,int n,float* __restrict__ meanacc,float inv_n)
{
  __shared__ float agg_s[4][65];
  __shared__ float xrow[4][65];
  __shared__ float cnt_s[4];
  const int tid = threadIdx.x;
  const int r = tid>>6, j = tid&63;
  const int i = blockIdx.x*4 + r;
  float a = 0.0f;
  if (i < n){
    int p0 = offD[i], p1 = offD[i+1], c = 0;
    for(int p=p0;p<p1;p++){
      if (eidD[p] < E){ a += X[(size_t)rowD[p]*64 + j]; c++; }
    }
    xrow[r][j] = X[(size_t)i*64 + j];
    if (j == 0) cnt_s[r] = (float)(c>1?c:1);
  }
  agg_s[r][j] = a;
  __syncthreads();
  float v = 0.0f;
  if (i < n){
    float acc=0.0f, rt=0.0f;
    for(int q=0;q<64;q++){
      acc = fmaf(agg_s[r][q], Wrel[q*64+j], acc);
      rt  = fmaf(xrow[r][q],  Wroot[q*64+j], rt);
    }
    v = fmaxf(acc/cnt_s[r] + brel[j] + rt, 0.0f);
    XN[(size_t)i*64 + j] = v;
  }
  __syncthreads();
  agg_s[r][j] = v;
  __syncthreads();
  if (r == 0) atomicAdd(&meanacc[j], (agg_s[0][j]+agg_s[1][j]+agg_s[2][j]+agg_s[3][j])*inv_n);
}

// pool0: xq = segmax gather (incl self) then @pW+pb
__global__ __launch_bounds__(256) void k_xqmaxq(
    const float* __restrict__ X,const int* __restrict__ offD,const int* __restrict__ rowD,
    const float* __restrict__ pWp,const float* __restrict__ pbp,
    float* __restrict__ XQ2,int n)
{
  __shared__ float xq[4][65];
  const int tid = threadIdx.x;
  const int r = tid>>6, j = tid&63;
  const int i = blockIdx.x*4 + r;
  float v = -3.0e38f;
  if (i < n){
    int p0 = offD[i], p1 = offD[i+1];
    for(int p=p0;p<p1;p++) v = fmaxf(v, X[(size_t)rowD[p]*64 + j]);
  }
  xq[r][j] = v;
  __syncthreads();
  if (i < n){
    float s = pbp[j];
    for(int q=0;q<64;q++) s = fmaf(xq[r][q], pWp[q*64+j], s);
    XQ2[(size_t)i*64+j] = s;
  }
}

__global__ void k_edge_score(const int* __restrict__ src,const int* __restrict__ dst,
                             const float* __restrict__ XQ2,const float* __restrict__ X,
                             float* sE,int E,int n){
  int e = blockIdx.x*256+threadIdx.x; if(e>=E+n) return;
  int s,d; edge_sd(e,src,dst,E,s,d);
  const float* q = XQ2 + (size_t)d*64;
  const float* x = X + (size_t)s*64;
  float acc = 0.0f;
  for(int h=0;h<64;h++) acc = fmaf(q[h], x[h], acc);
  sE[e] = acc > 0.0f ? acc : 0.2f*acc;
}

// per-dst softmax over in-edges -> scE
__global__ void k_dstsoft(const int* __restrict__ offD,const int* __restrict__ eidD,
                          const float* __restrict__ sE,float* __restrict__ scE,int n){
  int i = blockIdx.x*256+threadIdx.x; if(i>=n) return;
  int p0 = offD[i], p1 = offD[i+1];
  float m = -3.0e38f;
  for(int p=p0;p<p1;p++) m = fmaxf(m, sE[eidD[p]]);
  float d = 0.0f;
  for(int p=p0;p<p1;p++) d += expf(sE[eidD[p]]-m);
  float inv = 1.0f/d;
  for(int p=p0;p<p1;p++){ int e = eidD[p]; scE[e] = expf(sE[e]-m)*inv; }
}

// pool0: xc gather + aN/bN/cN; zeroes pcnt
__global__ __launch_bounds__(256) void k_xcabc0(
    const int* __restrict__ offD,const int* __restrict__ rowD,const int* __restrict__ eidD,
    const float* __restrict__ scE,const float* __restrict__ X,
    float* __restrict__ XC,
    const float* __restrict__ w1,const float* bb1,const float* __restrict__ w2,
    const float* __restrict__ w3,const float* bb3,
    float* aN,float* bN,float* cN,int* pcnt,int n)
{
  __shared__ float xc[4][65];
  const int tid = threadIdx.x;
  const int r = tid>>6, j = tid&63;
  const int i = blockIdx.x*4 + r;
  if (blockIdx.x==0 && tid==0) *pcnt = 0;
  float v = 0.0f;
  if (i < n){
    int p0 = offD[i], p1 = offD[i+1];
    for(int p=p0;p<p1;p++) v += scE[eidD[p]] * X[(size_t)rowD[p]*64 + j];
    XC[(size_t)i*64+j] = v;
  }
  xc[r][j] = v;
  __syncthreads();
  if (i < n && j < 3){
    float s = (j==0)?bb1[0]:((j==2)?bb3[0]:0.0f);
    const float* w = (j==0)?w1:((j==1)?w2:w3);
    for(int q=0;q<64;q++) s = fmaf(xc[r][q], w[q], s);
    if(j==0) aN[i]=s; else if(j==1) bN[i]=s; else cN[i]=s;
  }
}

__global__ void k_aggfit0(const int* __restrict__ offD,const int* __restrict__ rowD,
                          const float* aN,const float* bN,const float* cN,
                          float* fit,int n){
  int i = blockIdx.x*256+threadIdx.x; if(i>=n) return;
  int p0 = offD[i], p1 = offD[i+1];
  float s = 0.0f;
  for(int p=p0;p<p1;p++) s += aN[rowD[p]];
  fit[i] = sigm(s - (float)(p1-p0)*bN[i] + cN[i]);
}

__global__ void k_stage1n(const int* src,const int* dst,const int* __restrict__ offS,
                          const int* __restrict__ colS,const int* __restrict__ eidS,
                          const float* __restrict__ scE,
                          float* R,int E,int n){
  int e = blockIdx.x*256+threadIdx.x; if(e>=E+n) return;
  int i,j; edge_sd(e,src,dst,E,i,j);
  int p0 = offS[j], p1 = offS[j+1];
  float* Ri = R + (size_t)i*n;
  for(int p=p0;p<p1;p++) atomicAdd(&Ri[colS[p]], scE[eidS[p]]);
}
__global__ void k_stage2p(const int* __restrict__ perm,const int* __restrict__ offD,
                          const int* __restrict__ rowD,const int* __restrict__ eidD,
                          const float* __restrict__ scE,
                          const float* __restrict__ R,float* A,int k,int n){
  int idx = blockIdx.x*256+threadIdx.x; if(idx>=k*k) return;
  int u = idx/k, v = idx - u*k;
  int d = perm[u], pv = perm[v];
  float acc = 0.0f;
  int p0 = offD[d], p1 = offD[d+1];
  for(int p=p0;p<p1;p++) acc = fmaf(scE[eidD[p]], R[(size_t)rowD[p]*n + pv], acc);
  A[idx] = (u==v) ? 0.0f : acc;
}

__global__ void k_head2(const float* __restrict__ xs,const float* __restrict__ W1,
                        const float* __restrict__ b1,const float* __restrict__ W2,
                        const float* __restrict__ b2,float* out){
  __shared__ float h2[64];
  __shared__ float lg[10];
  int t = threadIdx.x;
  float s = b1[t];
  for(int q=0;q<640;q++) s = fmaf(xs[q], W1[q*64+t], s);
  h2[t] = fmaxf(s, 0.0f);
  __syncthreads();
  if(t < 10){
    float s2 = b2[t];
    for(int k=0;k<64;k++) s2 = fmaf(h2[k], W2[k*10+t], s2);
    lg[t] = s2;
  }
  __syncthreads();
  if(t == 0){
    float mx = lg[0];
    for(int i=1;i<10;i++) mx = fmaxf(mx, lg[i]);
    float se = 0.0f;
    for(int i=0;i<10;i++) se += expf(lg[i]-mx);
    float lse = mx + logf(se);
    for(int i=0;i<10;i++) out[i] = lg[i]-lse;
  }
}

// ---------------- host orchestration ----------------
extern "C" void kernel_launch(void* const* d_in, const int* in_sizes, int n_in,
                              void* d_out, int out_size, void* d_ws, size_t ws_size,
                              hipStream_t stream) {
  const int N0 = 1500, E = 24000, Z = 8, L = E + N0;
  const float* x0   = (const float*)d_in[0];
  const int* esrc   = (const int*)d_in[1];
  const int* edst   = (const int*)d_in[2];
  const float* W1   = (const float*)d_in[3];  const float* b1   = (const float*)d_in[4];
  const float* W2   = (const float*)d_in[5];  const float* b2   = (const float*)d_in[6];
  const float* W3   = (const float*)d_in[7];  const float* b3   = (const float*)d_in[8];
  const float* Wrel = (const float*)d_in[9];  const float* brel = (const float*)d_in[10];
  const float* Wroot= (const float*)d_in[11];
  const float* pW   = (const float*)d_in[12]; const float* pb   = (const float*)d_in[13];
  const float* leW1 = (const float*)d_in[14]; const float* leb1 = (const float*)d_in[15];
  const float* leW2 = (const float*)d_in[16]; const float* leW3 = (const float*)d_in[17];
  const float* leb3 = (const float*)d_in[18];
  const float* linW1= (const float*)d_in[19]; const float* linb1= (const float*)d_in[20];
  const float* linW2= (const float*)d_in[21]; const float* linb2= (const float*)d_in[22];
  float* out = (float*)d_out;

  float* ws = (float*)d_ws;
  size_t cur = 0;
  auto allocF = [&](size_t nf)->float*{ float* p = ws + cur; cur += (nf + 15) & ~(size_t)15; return p; };
  // contiguous zero block: xs | indeg | outdeg
  float* xs   = allocF(640);
  int* indeg  = (int*)allocF(1504);
  int* outdeg = (int*)allocF(1504);
  float* Xa  = allocF(96000); float* Xb  = allocF(96000); float* Y   = allocF(96000);
  float* XQ2 = allocF(96000); float* XC  = allocF(96000);
  float* mcol = allocF(1504); float* invd = allocF(1504);
  float* aN = allocF(1504); float* bN = allocF(1504); float* cN = allocF(1504);
  float* fit = allocF(1504); float* cntP = allocF(1504);
  int* pcnt = (int*)allocF(16);
  int* perm = (int*)allocF(1504);
  int* offD = (int*)allocF(1504); int* offS = (int*)allocF(1504);
  int* curD = (int*)allocF(1504); int* curS = (int*)allocF(1504);
  int* colS = (int*)allocF(25504); int* eidS = (int*)allocF(25504);
  int* rowD = (int*)allocF(25504); int* eidD = (int*)allocF(25504);
  float* sE = allocF(25504); float* scE = allocF(25504);
  int* cntp8 = (int*)allocF(8*1504);
  float* aggp = allocF(16*1504);
  float* SEGP = allocF((size_t)Z*1504*64);
  float* Rbig = allocF((size_t)1500*1500);   // pool0 R; aliased as SCb afterwards
  float* SCb  = Rbig;
  float* A0  = allocF((size_t)1350*1350);
  float* A1s = allocF((size_t)1350*1350);
  const size_t BFSZ = (size_t)1350*4224/2 + 32;
  ushort* Abf = (ushort*)allocF(BFSZ);
  ushort* Bbf = (ushort*)allocF(BFSZ);
  ushort* Cbf = (ushort*)allocF(BFSZ);
  ushort* Dbf = (ushort*)allocF(BFSZ);

  dim3 B256(256);
  auto G1 = [&](size_t n){ return dim3((unsigned)((n + 255) / 256)); };
  auto ZF = [&](void* p, size_t nfloats){ k_zero<<<G1(nfloats),B256,0,stream>>>((float*)p, nfloats); };
  auto kc8 = [&](int K){ return (int)(((K + Z*16 - 1) / (Z*16)) * 16); };

  // ---- prologue: zero (xs+indeg+outdeg contiguous), degrees, CSR ----
  ZF(xs, 640 + 1504 + 1504);
  k_deg<<<G1(E),B256,0,stream>>>(esrc, edst, indeg, outdeg, E);
  k_prefix2<<<dim3((N0+256)/256,2),B256,0,stream>>>(indeg, outdeg, offD, curD, offS, curS, N0);
  k_csr_fill2<<<G1(L),B256,0,stream>>>(esrc, edst, curS, colS, eidS, curD, rowD, eidD, E, N0);

  // ---- FEAST x3 (2 nodes each) ----
  auto feast = [&](const float* xin,int cin,const float* W,const float* bb,int hh,float* xout,float* macc){
    k_mm_small<<<G1((size_t)N0*hh),B256,0,stream>>>(xin, W, nullptr, Y, N0, cin, hh, 0);
    k_feast_gf<<<G1((size_t)N0*hh),B256,0,stream>>>(Y, offD, rowD, bb, xout, N0, hh, macc, 1.0f/N0);
  };
  feast(x0, 16, W1, b1, 32, Xa, nullptr);
  feast(Xa, 32, W2, b2, 64, Xb, nullptr);
  feast(Xb, 64, W3, b3, 64, Xa, xs + 0);
  float* X = Xa; float* XN = Xb;

  // ---- i=0 gconv_sparse (1 node) ----
  k_gconv_sparse_f<<<dim3((N0+3)/4),B256,0,stream>>>(X, offD, rowD, eidD, E, Wrel, brel, Wroot,
                                                     XN, N0, xs + 64, 1.0f/N0);
  { float* t = X; X = XN; XN = t; }

  // ---- pool 0 (sparse ASAP), n=1500 -> k=1350 ----
  {
    const int n = 1500, kk = 1350;
    k_xqmaxq<<<dim3((n+3)/4),B256,0,stream>>>(X, offD, rowD, pW, pb, XQ2, n);
    k_edge_score<<<G1(L),B256,0,stream>>>(esrc, edst, XQ2, X, sE, E, n);
    k_dstsoft<<<G1(n),B256,0,stream>>>(offD, eidD, sE, scE, n);
    k_xcabc0<<<dim3((n+3)/4),B256,0,stream>>>(offD, rowD, eidD, scE, X, XC,
                                              leW1, leb1, leW2, leW3, leb3, aN, bN, cN, pcnt, n);
    k_aggfit0<<<G1(n),B256,0,stream>>>(offD, rowD, aN, bN, cN, fit, n);
    k_rank_perm<<<G1(n),B256,0,stream>>>(fit, n, kk, pcnt, perm);
    k_xnew<<<G1((size_t)kk*64),B256,0,stream>>>(XC, fit, perm, XN, kk);
    ZF(Rbig, (size_t)n*n);
    k_stage1n<<<G1(L),B256,0,stream>>>(esrc, edst, offS, colS, eidS, scE, Rbig, E, n);
    k_stage2p<<<G1((size_t)kk*kk),B256,0,stream>>>(perm, offD, rowD, eidD, scE, Rbig, A0, kk, n);
    { float* t = X; X = XN; XN = t; }
  }

  float* Acur = A0; float* Aoth = A1s;
  int nn = 1350;

  // ---- dense gconv (2 nodes) ----
  auto gconv_dense = [&](int layer){
    dim3 g(1, (nn+63)/64, Z);
    k_skinny<false,true,false,false><<<g,B256,0,stream>>>(Acur, nn, X, nullptr, SEGP, cntp8, nn, nn, kc8(nn));
    k_gconv_fuse<<<dim3((nn+3)/4),B256,0,stream>>>(SEGP, cntp8, Z,
        Wrel + (size_t)layer*4096, brel + layer*64, X, Wroot + (size_t)layer*4096,
        XN, nn, xs + (size_t)(layer+1)*64, 1.0f/nn);
    { float* t = X; X = XN; XN = t; }
  };

  // ---- dense ASAP pool (15 nodes) ----
  auto asap_dense = [&](int kk, int p){
    {
      dim3 g(1, (nn+63)/64, Z);
      k_skinny<true,true,false,true><<<g,B256,0,stream>>>(Acur, nn, X, nullptr, SEGP, cntp8, nn, nn, kc8(nn));
    }
    k_poolq<<<dim3((nn+3)/4),B256,0,stream>>>(SEGP, cntp8, Z, pW + (size_t)p*4096, pb + p*64, XQ2, cntP, nn);
    k_split3_dual<<<G1((size_t)nn*64),B256,0,stream>>>(X, XQ2, nn, Abf, Bbf);
    {
      dim3 g((nn+63)/64, (nn+63)/64);
      k_gemm_mfma<1><<<g,B256,0,stream>>>(Abf, Bbf, SCb, nn, nn, nn, 192, Acur, nn);
    }
    k_smax_fused<<<dim3((nn+15)/16),B256,0,stream>>>(SCb, nn, mcol, invd);
    {
      dim3 g(1, (nn+63)/64, Z);
      k_skinny<false,false,true,false><<<g,B256,0,stream>>>(SCb, nn, X, mcol, SEGP, nullptr, nn, nn, kc8(nn));
    }
    k_xcabc_dense<<<dim3((nn+3)/4),B256,0,stream>>>(SEGP, Z, invd, XC,
        leW1 + p*64, leb1 + p, leW2 + p*64, leW3 + p*64, leb3 + p, aN, bN, cN, pcnt, nn);
    k_aggcol<<<G1((size_t)nn*16),B256,0,stream>>>(Acur, aN, aggp, nn);
    k_fit_dense2<<<G1(nn),B256,0,stream>>>(aggp, cntP, aN, bN, cN, fit, nn);
    k_rank_perm<<<G1(nn),B256,0,stream>>>(fit, nn, kk, pcnt, perm);
    k_xnew<<<G1((size_t)kk*64),B256,0,stream>>>(XC, fit, perm, XN, kk);
    const int Kp = (nn + 63) & ~63;
    const int K3 = 3*Kp;
    k_split3<<<G1((size_t)nn*Kp),B256,0,stream>>>(Acur, nn, nn, nn, Abf, Kp, 0);
    { dim3 gt((kk+31)/32, Kp/32);
      k_split3_Tdual<<<gt,B256,0,stream>>>(SCb, nn, kk, nn, perm, invd, mcol, Dbf, Bbf, Cbf, Kp); }
    { dim3 g((kk+63)/64, (nn+63)/64);
      k_gemm_mfma_tb<<<g,B256,0,stream>>>(Abf, Bbf, SCb, nn, perm, mcol, invd, Cbf, Kp, nn, kk, K3); }
    { dim3 g((kk+63)/64, (kk+63)/64);
      k_gemm_mfma<2><<<g,B256,0,stream>>>(Dbf, Cbf, Aoth, kk, kk, kk, K3, nullptr, 0); }
    { float* t = X; X = XN; XN = t; }
    { float* t = Acur; Acur = Aoth; Aoth = t; }
    nn = kk;
  };

  gconv_dense(1);
  gconv_dense(2);
  asap_dense(1215, 1);
  gconv_dense(3);
  gconv_dense(4);
  asap_dense(1094, 2);
  gconv_dense(5);
  gconv_dense(6);
  asap_dense(985, 3);
  gconv_dense(7);
  gconv_dense(8);

  // ---- head (1 node) ----
  k_head2<<<1,64,0,stream>>>(xs, linW1, linb1, linW2, linb2, out);
}